// Round 17
// baseline (555.173 us; speedup 1.0000x reference)
//
#include <hip/hip_runtime.h>
#include <hip/hip_bf16.h>

#define N_NODES 50000
#define E_EDGES 600000
#define F_IN    256
#define HC1     128   // 4 heads * 32
#define F_OUT   64
#define NBKT    196   // ceil(N_NODES/256) coarse dst-buckets
#define BMAX    6144  // per-bucket capacity (mean 3316, sigma ~58 -> 49-sigma margin)

typedef __bf16 bf16x8 __attribute__((ext_vector_type(8)));
typedef __bf16 bf16x4 __attribute__((ext_vector_type(4)));
typedef float  f32x4  __attribute__((ext_vector_type(4)));

// -------------------- CSR build: two-phase bucket sort ------------------------
// Phase A appends edges to 196 coarse buckets (dst>>8): appends to one bucket
// are temporally dense -> full-line writes (fixes the 8x write amplification
// that made the old direct scatter 42us). Phase B sorts each bucket by dst in
// LDS and writes rowp + epair fully coalesced.

__global__ void zerob_kernel(int* __restrict__ bcur) {
    if (threadIdx.x < NBKT) bcur[threadIdx.x] = 0;
}

__global__ void bappend_kernel(const int* __restrict__ ei, int* __restrict__ bcur,
                               int2* __restrict__ bstage) {
    int i = blockIdx.x * blockDim.x + threadIdx.x;
    const int total = E_EDGES + N_NODES;
    if (i >= total) return;
    int s, d;
    if (i < E_EDGES) { s = ei[i]; d = ei[E_EDGES + i]; }
    else             { s = d = i - E_EDGES; }
    int b = d >> 8;
    int pos = atomicAdd(&bcur[b], 1);
    if (pos < BMAX) bstage[(size_t)b * BMAX + pos] = make_int2(s, d);
}

// exclusive scan of the 196 bucket counts (single block, 256 threads).
__global__ void bucket_scan_kernel(const int* __restrict__ bcur, int* __restrict__ bbase,
                                   int* __restrict__ rowp) {
    __shared__ int ws4[4];
    int tid = threadIdx.x;
    int lane = tid & 63, w = tid >> 6;
    int v = (tid < NBKT) ? bcur[tid] : 0;
    int s = v;
    #pragma unroll
    for (int d = 1; d < 64; d <<= 1) {
        int t = __shfl_up(s, d);
        if (lane >= d) s += t;
    }
    if (lane == 63) ws4[w] = s;
    __syncthreads();
    if (tid == 0) {
        int r = 0;
        #pragma unroll
        for (int q = 0; q < 4; ++q) { int t = ws4[q]; ws4[q] = r; r += t; }
    }
    __syncthreads();
    if (tid < NBKT) bbase[tid] = ws4[w] + s - v;
    if (tid == 0) rowp[N_NODES] = E_EDGES + N_NODES;
}

// per-bucket counting sort in LDS; writes rowp (256 dsts) + sorted epair region.
__global__ __launch_bounds__(1024) void bsort_kernel(const int* __restrict__ bcur,
                                                     const int* __restrict__ bbase,
                                                     const int2* __restrict__ bstage,
                                                     int* __restrict__ rowp,
                                                     int2* __restrict__ epair) {
    __shared__ int cnt[256], cur[256], ws4[4];
    __shared__ int2 sorted[BMAX];
    int b = blockIdx.x, tid = threadIdx.x;
    int nb = bcur[b]; if (nb > BMAX) nb = BMAX;
    int base = bbase[b];
    int d0 = b << 8;
    if (tid < 256) cnt[tid] = 0;
    __syncthreads();
    const int2* bs = bstage + (size_t)b * BMAX;
    for (int e = tid; e < nb; e += 1024)
        atomicAdd(&cnt[bs[e].y - d0], 1);
    __syncthreads();
    int v = 0, s = 0;
    if (tid < 256) {
        int lane = tid & 63, w = tid >> 6;
        v = cnt[tid];
        s = v;
        #pragma unroll
        for (int d = 1; d < 64; d <<= 1) {
            int t = __shfl_up(s, d);
            if (lane >= d) s += t;
        }
        if (lane == 63) ws4[w] = s;
    }
    __syncthreads();
    if (tid == 0) {
        int r = 0;
        #pragma unroll
        for (int q = 0; q < 4; ++q) { int t = ws4[q]; ws4[q] = r; r += t; }
    }
    __syncthreads();
    if (tid < 256) {
        int excl = ws4[tid >> 6] + s - v;
        cur[tid] = excl;
        int d = d0 + tid;
        if (d < N_NODES) rowp[d] = base + excl;
    }
    __syncthreads();
    for (int e = tid; e < nb; e += 1024) {
        int2 ed = bs[e];
        int p = atomicAdd(&cur[ed.y - d0], 1);
        sorted[p] = ed;
    }
    __syncthreads();
    for (int e = tid; e < nb; e += 1024)
        epair[base + e] = sorted[e];   // linear, coalesced
}

// -------------------- W pre-pack into MFMA B-fragment order (bf16 hi/lo) ------

__global__ void pack_w_kernel(const float* __restrict__ W1, const float* __restrict__ W2,
                              __bf16* __restrict__ hi1, __bf16* __restrict__ lo1,
                              __bf16* __restrict__ hi2, __bf16* __restrict__ lo2) {
    int tid = blockIdx.x * blockDim.x + threadIdx.x;
    if (tid >= F_IN * HC1 + HC1 * F_OUT) return;
    if (tid < F_IN * HC1) {
        int t = tid;
        int j = t & 7, l = (t >> 3) & 63, kt = (t >> 9) & 7, ct = t >> 12;
        int k = kt * 32 + (l >> 4) * 8 + j;
        int col = ct * 16 + (l & 15);
        float v = W1[k * HC1 + col];
        __bf16 h = (__bf16)v;
        hi1[t] = h;
        lo1[t] = (__bf16)(v - (float)h);
    } else {
        int t = tid - F_IN * HC1;
        int j = t & 7, l = (t >> 3) & 63, kt = (t >> 9) & 3, ct = t >> 11;
        int k = kt * 32 + (l >> 4) * 8 + j;
        int col = ct * 16 + (l & 15);
        float v = W2[k * F_OUT + col];
        __bf16 h = (__bf16)v;
        hi2[t] = h;
        lo2[t] = (__bf16)(v - (float)h);
    }
}

// -------------------- LDS-staged split-bf16 MFMA GEMM + fused al epilogue -----

template<int KDIM, int NC, bool CBF16, int CGROUPS>
__global__ __launch_bounds__(256) void gemm_mfma_kernel(const float* __restrict__ A,
                                                        const __bf16* __restrict__ Whi,
                                                        const __bf16* __restrict__ Wlo,
                                                        const float* __restrict__ a_s,
                                                        const float* __restrict__ a_d,
                                                        void* __restrict__ Cout,
                                                        float* __restrict__ als,
                                                        float* __restrict__ ald) {
    constexpr int KT   = KDIM / 32;
    constexpr int CT   = NC / 16;          // total col tiles
    constexpr int CTW  = CT / CGROUPS;     // col tiles per wave
    constexpr int RPB  = (CGROUPS == 2) ? 32 : 64;
    constexpr int LSTR = KDIM + 8;         // bf16 row stride: 16B-aligned, 2-way banks
    constexpr int F4PR = KDIM / 4;         // float4 per row
    __shared__ __bf16 ah[RPB][LSTR];
    __shared__ __bf16 al[RPB][LSTR];

    int tid = threadIdx.x;

    // ---- cooperative stage: coalesced float4 loads, convert once, LDS write ----
    #pragma unroll
    for (int it = 0; it < (RPB * F4PR) / 256; ++it) {
        int idx = it * 256 + tid;
        int row = idx / F4PR;
        int kk  = (idx - row * F4PR) * 4;
        int grow = blockIdx.x * RPB + row;
        const float* src = A + (size_t)(grow < N_NODES ? grow : N_NODES - 1) * KDIM + kk;
        float4 v = *(const float4*)src;
        bf16x4 h, lo;
        h[0] = (__bf16)v.x; h[1] = (__bf16)v.y; h[2] = (__bf16)v.z; h[3] = (__bf16)v.w;
        lo[0] = (__bf16)(v.x - (float)h[0]);
        lo[1] = (__bf16)(v.y - (float)h[1]);
        lo[2] = (__bf16)(v.z - (float)h[2]);
        lo[3] = (__bf16)(v.w - (float)h[3]);
        *(bf16x4*)&ah[row][kk] = h;
        *(bf16x4*)&al[row][kk] = lo;
    }
    __syncthreads();

    int w = tid >> 6, l = tid & 63;
    int rw = (CGROUPS == 2) ? (w & 1) : w;
    int cg = (CGROUPS == 2) ? (w >> 1) : 0;
    int c0 = cg * CTW;
    int r0 = blockIdx.x * RPB + rw * 16;
    int rowL = rw * 16 + (l & 15);
    int koff = (l >> 4) * 8;

    // B double-buffer: prologue loads kt=0; loop prefetches kt+1 before MFMAs on kt.
    bf16x8 bh[2][CTW], bl[2][CTW];
    #pragma unroll
    for (int c = 0; c < CTW; ++c) {
        size_t bidx = ((size_t)((c0 + c) * KT + 0) * 64 + l) * 8;
        bh[0][c] = *(const bf16x8*)(Whi + bidx);
        bl[0][c] = *(const bf16x8*)(Wlo + bidx);
    }

    f32x4 acc[CTW];
    #pragma unroll
    for (int c = 0; c < CTW; ++c) acc[c] = (f32x4){0.f, 0.f, 0.f, 0.f};

    #pragma unroll
    for (int kt = 0; kt < KT; ++kt) {
        const int cur = kt & 1, nxt = cur ^ 1;
        if (kt + 1 < KT) {
            #pragma unroll
            for (int c = 0; c < CTW; ++c) {
                size_t bidx = ((size_t)((c0 + c) * KT + (kt + 1)) * 64 + l) * 8;
                bh[nxt][c] = *(const bf16x8*)(Whi + bidx);
                bl[nxt][c] = *(const bf16x8*)(Wlo + bidx);
            }
        }
        bf16x8 ahi = *(const bf16x8*)&ah[rowL][kt * 32 + koff];
        bf16x8 alo = *(const bf16x8*)&al[rowL][kt * 32 + koff];
        #pragma unroll
        for (int c = 0; c < CTW; ++c) {
            acc[c] = __builtin_amdgcn_mfma_f32_16x16x32_bf16(ahi, bh[cur][c], acc[c], 0, 0, 0);
            acc[c] = __builtin_amdgcn_mfma_f32_16x16x32_bf16(ahi, bl[cur][c], acc[c], 0, 0, 0);
            acc[c] = __builtin_amdgcn_mfma_f32_16x16x32_bf16(alo, bh[cur][c], acc[c], 0, 0, 0);
        }
    }

    int crow0 = r0 + (l >> 4) * 4;
    int ccol = l & 15;

    // C store
    #pragma unroll
    for (int c = 0; c < CTW; ++c) {
        #pragma unroll
        for (int r = 0; r < 4; ++r) {
            int row = crow0 + r;
            if (row < N_NODES) {
                if constexpr (CBF16)
                    ((__bf16*)Cout)[(size_t)row * NC + (c0 + c) * 16 + ccol] = (__bf16)acc[c][r];
                else
                    ((float*)Cout)[(size_t)row * NC + (c0 + c) * 16 + ccol] = acc[c][r];
            }
        }
    }

    // fused attention scalars: per-row dot with a_s / a_d (wave-local by construction)
    float as_c[CTW], ad_c[CTW];
    #pragma unroll
    for (int c = 0; c < CTW; ++c) {
        as_c[c] = a_s[(c0 + c) * 16 + ccol];
        ad_c[c] = a_d[(c0 + c) * 16 + ccol];
    }

    #pragma unroll
    for (int r = 0; r < 4; ++r) {
        int row = crow0 + r;
        if constexpr (NC == 128) {
            // CTW=4 here: 2 heads per wave, head spans 2 col tiles
            #pragma unroll
            for (int hl = 0; hl < 2; ++hl) {
                int h = cg * 2 + hl;
                float vs = acc[2 * hl][r] * as_c[2 * hl] + acc[2 * hl + 1][r] * as_c[2 * hl + 1];
                float vd = acc[2 * hl][r] * ad_c[2 * hl] + acc[2 * hl + 1][r] * ad_c[2 * hl + 1];
                #pragma unroll
                for (int d = 1; d < 16; d <<= 1) {
                    vs += __shfl_xor(vs, d);
                    vd += __shfl_xor(vd, d);
                }
                if (ccol == 0 && row < N_NODES) { als[row * 4 + h] = vs; ald[row * 4 + h] = vd; }
            }
        } else {
            float vs = 0.f, vd = 0.f;
            #pragma unroll
            for (int c = 0; c < CTW; ++c) { vs += acc[c][r] * as_c[c]; vd += acc[c][r] * ad_c[c]; }
            #pragma unroll
            for (int d = 1; d < 16; d <<= 1) {
                vs += __shfl_xor(vs, d);
                vd += __shfl_xor(vd, d);
            }
            if (ccol == 0 && row < N_NODES) { als[row] = vs; ald[row] = vd; }
        }
    }
}

__device__ __forceinline__ float lrelu(float x) { return x > 0.f ? x : 0.2f * x; }
__device__ __forceinline__ float bfhi(unsigned v) { return __uint_as_float(v & 0xffff0000u); }
__device__ __forceinline__ float bflo(unsigned v) { return __uint_as_float(v << 16); }

// -------------------- per-edge attention weights (unnormalized) --------------------

__global__ __launch_bounds__(256) void p1_kernel(const int2* __restrict__ epair,
                                                 const float* __restrict__ als,
                                                 const float* __restrict__ ald,
                                                 float* __restrict__ p1) {
    int j = blockIdx.x * 256 + threadIdx.x;
    if (j >= E_EDGES + N_NODES) return;
    int2 e = epair[j];
    float4 as = *(const float4*)&als[e.x * 4];
    float4 ad = *(const float4*)&ald[e.y * 4];
    float4 p;
    p.x = __expf(lrelu(as.x + ad.x));
    p.y = __expf(lrelu(as.y + ad.y));
    p.z = __expf(lrelu(as.z + ad.z));
    p.w = __expf(lrelu(as.w + ad.w));
    *(float4*)&p1[(size_t)j * 4] = p;
}

__global__ __launch_bounds__(256) void p2_kernel(const int2* __restrict__ epair,
                                                 const float* __restrict__ als,
                                                 const float* __restrict__ ald,
                                                 float* __restrict__ p2) {
    int j = blockIdx.x * 256 + threadIdx.x;
    if (j >= E_EDGES + N_NODES) return;
    int2 e = epair[j];
    p2[j] = __expf(lrelu(als[e.x] + ald[e.y]));
}

// -------------------- single-pass aggregation (streamed p) --------------------

// layer 1: 1 wave per dst. 4 groups x 16 lanes; group g handles edge j0+g;
// lane li covers cols li*8..li*8+7 (head li>>2) via one 16B load.
__global__ __launch_bounds__(256) void aggr1_kernel(const int* __restrict__ row_ptr,
                                                    const int2* __restrict__ epair,
                                                    const float* __restrict__ p1,
                                                    const __bf16* __restrict__ h1b,
                                                    const float* __restrict__ b1,
                                                    float* __restrict__ h2out) {
    int wid = blockIdx.x * 4 + (threadIdx.x >> 6);
    int lane = threadIdx.x & 63;
    int grp = lane >> 4, li = lane & 15;
    int hh = li >> 2;                       // head of this lane's 8 cols
    int beg = row_ptr[wid], end = row_ptr[wid + 1];
    float acc[8] = {0,0,0,0,0,0,0,0};
    float S = 0.f;
    for (int j0 = beg; j0 < end; j0 += 4) {
        int j = j0 + grp;
        bool valid = (j < end);
        int s = valid ? epair[j].x : 0;
        float p = valid ? p1[(size_t)j * 4 + hh] : 0.f;   // streamed, CSR-contiguous
        uint4 v = *(const uint4*)(h1b + (size_t)s * HC1 + li * 8);
        acc[0] += p * bflo(v.x); acc[1] += p * bfhi(v.x);
        acc[2] += p * bflo(v.y); acc[3] += p * bfhi(v.y);
        acc[4] += p * bflo(v.z); acc[5] += p * bfhi(v.z);
        acc[6] += p * bflo(v.w); acc[7] += p * bfhi(v.w);
        S += p;
    }
    // reduce across the 4 groups (lane bits 4,5)
    #pragma unroll
    for (int d = 16; d < 64; d <<= 1) {
        #pragma unroll
        for (int c = 0; c < 8; ++c) acc[c] += __shfl_xor(acc[c], d);
        S += __shfl_xor(S, d);
    }
    if (grp == 0) {
        float inv = 1.f / S;
        const float* bp = b1 + li * 8;
        float4 o0, o1;
        o0.x = lrelu(acc[0] * inv + bp[0]);
        o0.y = lrelu(acc[1] * inv + bp[1]);
        o0.z = lrelu(acc[2] * inv + bp[2]);
        o0.w = lrelu(acc[3] * inv + bp[3]);
        o1.x = lrelu(acc[4] * inv + bp[4]);
        o1.y = lrelu(acc[5] * inv + bp[5]);
        o1.z = lrelu(acc[6] * inv + bp[6]);
        o1.w = lrelu(acc[7] * inv + bp[7]);
        float* orow = h2out + (size_t)wid * HC1 + li * 8;
        *(float4*)orow = o0;
        *(float4*)(orow + 4) = o1;
    }
}

// layer 2: 1 wave per dst; 4 groups x 16 lanes; lane li covers cols li*4..li*4+3.
__global__ __launch_bounds__(256) void aggr2_kernel(const int* __restrict__ row_ptr,
                                                    const int2* __restrict__ epair,
                                                    const float* __restrict__ p2,
                                                    const float* __restrict__ g,
                                                    const float* __restrict__ b2,
                                                    float* __restrict__ out) {
    int wid = blockIdx.x * 4 + (threadIdx.x >> 6);
    int lane = threadIdx.x & 63;
    int grp = lane >> 4, li = lane & 15;
    int beg = row_ptr[wid], end = row_ptr[wid + 1];
    float a0 = 0.f, a1 = 0.f, a2 = 0.f, a3 = 0.f, S = 0.f;
    for (int j0 = beg; j0 < end; j0 += 4) {
        int j = j0 + grp;
        bool valid = (j < end);
        int s = valid ? epair[j].x : 0;
        float p = valid ? p2[j] : 0.f;
        float4 gv = *(const float4*)(g + (size_t)s * F_OUT + li * 4);
        a0 += p * gv.x; a1 += p * gv.y; a2 += p * gv.z; a3 += p * gv.w;
        S += p;
    }
    #pragma unroll
    for (int d = 16; d < 64; d <<= 1) {
        a0 += __shfl_xor(a0, d); a1 += __shfl_xor(a1, d);
        a2 += __shfl_xor(a2, d); a3 += __shfl_xor(a3, d);
        S += __shfl_xor(S, d);
    }
    if (grp == 0) {
        float inv = 1.f / S;
        const float* bp = b2 + li * 4;
        float4 o;
        o.x = a0 * inv + bp[0];
        o.y = a1 * inv + bp[1];
        o.z = a2 * inv + bp[2];
        o.w = a3 * inv + bp[3];
        *(float4*)(out + (size_t)wid * F_OUT + li * 4) = o;
    }
}

// -------------------- launch --------------------

extern "C" void kernel_launch(void* const* d_in, const int* in_sizes, int n_in,
                              void* d_out, int out_size, void* d_ws, size_t ws_size,
                              hipStream_t stream) {
    const float* x      = (const float*)d_in[0];
    const int*   ei     = (const int*)  d_in[1];
    const float* W1     = (const float*)d_in[2];
    const float* a_src1 = (const float*)d_in[3];
    const float* a_dst1 = (const float*)d_in[4];
    const float* b1     = (const float*)d_in[5];
    const float* W2     = (const float*)d_in[6];
    const float* a_src2 = (const float*)d_in[7];
    const float* a_dst2 = (const float*)d_in[8];
    const float* b2     = (const float*)d_in[9];
    float* out = (float*)d_out;
    char* ws = (char*)d_ws;

    // workspace layout (bytes)
    __bf16* h1b    = (__bf16*)(ws + 0);         // N*128*2 = 12,800,000
    float* h2      = (float*)(ws + 12800000);   // 25,600,000
    float* g       = (float*)(ws + 38400000);   // 12,800,000
    float* als1    = (float*)(ws + 51200000);   // 800,000
    float* ald1    = (float*)(ws + 52000000);   // 800,000
    float* als2    = (float*)(ws + 52800000);   // 200,000
    float* ald2    = (float*)(ws + 53000000);   // 200,000
    int*   rowp    = (int*)  (ws + 53200000);   // 200,004 (pad to 53,400,064)
    int*   bcur    = (int*)  (ws + 53400064);   // 784 (pad to 53,401,088)
    int*   bbase   = (int*)  (ws + 53401088);   // 784 (pad to 53,402,112)
    int2*  bstage  = (int2*) (ws + 53402112);   // NBKT*BMAX*8 = 9,633,792 -> 63,035,904
    int2*  epair   = (int2*) (ws + 63035904);   // (E+N)*8 = 5,200,000 -> 68,235,904
    __bf16* whi1   = (__bf16*)(ws + 68235904);  // 65,536
    __bf16* wlo1   = (__bf16*)(ws + 68301440);  // 65,536
    __bf16* whi2   = (__bf16*)(ws + 68366976);  // 16,384
    __bf16* wlo2   = (__bf16*)(ws + 68383360);  // 16,384 (end 68,399,744)
    // recycled regions:
    float* p1 = g;                // consumed by aggr1 before gemm2 writes g
    float* p2 = (float*)h1b;      // h1b dead after aggr1

    const int TOT = E_EDGES + N_NODES;
    const int eb = (TOT + 255) / 256;

    zerob_kernel<<<1, 256, 0, stream>>>(bcur);
    bappend_kernel<<<eb, 256, 0, stream>>>(ei, bcur, bstage);
    bucket_scan_kernel<<<1, 256, 0, stream>>>(bcur, bbase, rowp);
    bsort_kernel<<<NBKT, 1024, 0, stream>>>(bcur, bbase, bstage, rowp, epair);

    pack_w_kernel<<<(F_IN * HC1 + HC1 * F_OUT + 255) / 256, 256, 0, stream>>>(
        W1, W2, whi1, wlo1, whi2, wlo2);

    // gemm1: 32 rows/block, 4 waves (2 row-halves x 2 col-halves) -> 1563 blocks
    gemm_mfma_kernel<F_IN, HC1, true, 2><<<(N_NODES + 31) / 32, 256, 0, stream>>>(
        x, whi1, wlo1, a_src1, a_dst1, h1b, als1, ald1);
    p1_kernel<<<eb, 256, 0, stream>>>(epair, als1, ald1, p1);
    aggr1_kernel<<<N_NODES / 4, 256, 0, stream>>>(rowp, epair, p1, h1b, b1, h2);

    // gemm2: 64 rows/block, 4 waves (row-quarters), full cols -> 782 blocks
    gemm_mfma_kernel<HC1, F_OUT, false, 1><<<(N_NODES + 63) / 64, 256, 0, stream>>>(
        h2, whi2, wlo2, a_src2, a_dst2, g, als2, ald2);
    p2_kernel<<<eb, 256, 0, stream>>>(epair, als2, ald2, p2);
    aggr2_kernel<<<N_NODES / 4, 256, 0, stream>>>(rowp, epair, p2, g, b2, out);
}

// Round 18
// 153.251 us; speedup vs baseline: 3.6226x; 3.6226x over previous
//
#include <hip/hip_runtime.h>
#include <hip/hip_bf16.h>

#define N_NODES 50000
#define E_EDGES 600000
#define F_IN    256
#define HC1     128   // 4 heads * 32
#define F_OUT   64
#define NBKT    196   // ceil(N_NODES/256) coarse dst-buckets
#define BMAX    6144  // per-bucket capacity (mean 3316, sigma ~58)
#define APB     8192  // edges per bappend block
#define NAB     80    // ceil((E+N)/APB)

typedef __bf16 bf16x8 __attribute__((ext_vector_type(8)));
typedef __bf16 bf16x4 __attribute__((ext_vector_type(4)));
typedef float  f32x4  __attribute__((ext_vector_type(4)));

// -------------------- CSR build: bucket sort w/ block-aggregated reservation --
// R17 post-mortem: 650k atomics on 196 global cursors = ~3300 serialized
// round-trips/address x ~125ns = 418us. Fix: each block counts its 8192-edge
// chunk in LDS, reserves one contiguous range per bucket (ONE global atomic per
// bucket per block: 80/address), then writes via LDS cursors (dense lines).

__global__ void zerob_kernel(int* __restrict__ bcur) {
    if (threadIdx.x < NBKT) bcur[threadIdx.x] = 0;
}

__global__ __launch_bounds__(1024) void bappend_kernel(const int* __restrict__ ei,
                                                       int* __restrict__ bcur,
                                                       int2* __restrict__ bstage) {
    __shared__ int lcnt[NBKT];
    const int TOT = E_EDGES + N_NODES;
    int tid = threadIdx.x;
    int e0 = blockIdx.x * APB;
    int e1 = e0 + APB < TOT ? e0 + APB : TOT;
    if (tid < NBKT) lcnt[tid] = 0;
    __syncthreads();
    for (int i = e0 + tid; i < e1; i += 1024) {
        int d = (i < E_EDGES) ? ei[E_EDGES + i] : (i - E_EDGES);
        atomicAdd(&lcnt[d >> 8], 1);
    }
    __syncthreads();
    if (tid < NBKT) {
        int c = lcnt[tid];
        lcnt[tid] = c ? atomicAdd(&bcur[tid], c) : 0;   // reserve range; lcnt -> cursor
    }
    __syncthreads();
    for (int i = e0 + tid; i < e1; i += 1024) {
        int s, d;
        if (i < E_EDGES) { s = ei[i]; d = ei[E_EDGES + i]; }
        else             { s = d = i - E_EDGES; }
        int b = d >> 8;
        int pos = atomicAdd(&lcnt[b], 1);               // LDS cursor
        bstage[(size_t)b * BMAX + pos] = make_int2(s, d);
    }
}

// exclusive scan of the 196 bucket counts (single block, 256 threads).
__global__ void bucket_scan_kernel(const int* __restrict__ bcur, int* __restrict__ bbase,
                                   int* __restrict__ rowp) {
    __shared__ int ws4[4];
    int tid = threadIdx.x;
    int lane = tid & 63, w = tid >> 6;
    int v = (tid < NBKT) ? bcur[tid] : 0;
    int s = v;
    #pragma unroll
    for (int d = 1; d < 64; d <<= 1) {
        int t = __shfl_up(s, d);
        if (lane >= d) s += t;
    }
    if (lane == 63) ws4[w] = s;
    __syncthreads();
    if (tid == 0) {
        int r = 0;
        #pragma unroll
        for (int q = 0; q < 4; ++q) { int t = ws4[q]; ws4[q] = r; r += t; }
    }
    __syncthreads();
    if (tid < NBKT) bbase[tid] = ws4[w] + s - v;
    if (tid == 0) rowp[N_NODES] = E_EDGES + N_NODES;
}

// per-bucket counting sort in LDS; writes rowp (256 dsts) + sorted epair region.
__global__ __launch_bounds__(1024) void bsort_kernel(const int* __restrict__ bcur,
                                                     const int* __restrict__ bbase,
                                                     const int2* __restrict__ bstage,
                                                     int* __restrict__ rowp,
                                                     int2* __restrict__ epair) {
    __shared__ int cnt[256], cur[256], ws4[4];
    __shared__ int2 sorted[BMAX];
    int b = blockIdx.x, tid = threadIdx.x;
    int nb = bcur[b]; if (nb > BMAX) nb = BMAX;
    int base = bbase[b];
    int d0 = b << 8;
    if (tid < 256) cnt[tid] = 0;
    __syncthreads();
    const int2* bs = bstage + (size_t)b * BMAX;
    for (int e = tid; e < nb; e += 1024)
        atomicAdd(&cnt[bs[e].y - d0], 1);
    __syncthreads();
    int v = 0, s = 0;
    if (tid < 256) {
        int lane = tid & 63, w = tid >> 6;
        v = cnt[tid];
        s = v;
        #pragma unroll
        for (int d = 1; d < 64; d <<= 1) {
            int t = __shfl_up(s, d);
            if (lane >= d) s += t;
        }
        if (lane == 63) ws4[w] = s;
    }
    __syncthreads();
    if (tid == 0) {
        int r = 0;
        #pragma unroll
        for (int q = 0; q < 4; ++q) { int t = ws4[q]; ws4[q] = r; r += t; }
    }
    __syncthreads();
    if (tid < 256) {
        int excl = ws4[tid >> 6] + s - v;
        cur[tid] = excl;
        int d = d0 + tid;
        if (d < N_NODES) rowp[d] = base + excl;
    }
    __syncthreads();
    for (int e = tid; e < nb; e += 1024) {
        int2 ed = bs[e];
        int p = atomicAdd(&cur[ed.y - d0], 1);
        sorted[p] = ed;
    }
    __syncthreads();
    for (int e = tid; e < nb; e += 1024)
        epair[base + e] = sorted[e];   // linear, coalesced
}

// -------------------- W pre-pack into MFMA B-fragment order (bf16 hi/lo) ------

__global__ void pack_w_kernel(const float* __restrict__ W1, const float* __restrict__ W2,
                              __bf16* __restrict__ hi1, __bf16* __restrict__ lo1,
                              __bf16* __restrict__ hi2, __bf16* __restrict__ lo2) {
    int tid = blockIdx.x * blockDim.x + threadIdx.x;
    if (tid >= F_IN * HC1 + HC1 * F_OUT) return;
    if (tid < F_IN * HC1) {
        int t = tid;
        int j = t & 7, l = (t >> 3) & 63, kt = (t >> 9) & 7, ct = t >> 12;
        int k = kt * 32 + (l >> 4) * 8 + j;
        int col = ct * 16 + (l & 15);
        float v = W1[k * HC1 + col];
        __bf16 h = (__bf16)v;
        hi1[t] = h;
        lo1[t] = (__bf16)(v - (float)h);
    } else {
        int t = tid - F_IN * HC1;
        int j = t & 7, l = (t >> 3) & 63, kt = (t >> 9) & 3, ct = t >> 11;
        int k = kt * 32 + (l >> 4) * 8 + j;
        int col = ct * 16 + (l & 15);
        float v = W2[k * F_OUT + col];
        __bf16 h = (__bf16)v;
        hi2[t] = h;
        lo2[t] = (__bf16)(v - (float)h);
    }
}

// -------------------- LDS-staged split-bf16 MFMA GEMM + fused al epilogue -----

template<int KDIM, int NC, bool CBF16, int CGROUPS>
__global__ __launch_bounds__(256) void gemm_mfma_kernel(const float* __restrict__ A,
                                                        const __bf16* __restrict__ Whi,
                                                        const __bf16* __restrict__ Wlo,
                                                        const float* __restrict__ a_s,
                                                        const float* __restrict__ a_d,
                                                        void* __restrict__ Cout,
                                                        float* __restrict__ als,
                                                        float* __restrict__ ald) {
    constexpr int KT   = KDIM / 32;
    constexpr int CT   = NC / 16;          // total col tiles
    constexpr int CTW  = CT / CGROUPS;     // col tiles per wave
    constexpr int RPB  = (CGROUPS == 2) ? 32 : 64;
    constexpr int LSTR = KDIM + 8;         // bf16 row stride: 16B-aligned, 2-way banks
    constexpr int F4PR = KDIM / 4;         // float4 per row
    __shared__ __bf16 ah[RPB][LSTR];
    __shared__ __bf16 al[RPB][LSTR];

    int tid = threadIdx.x;

    // ---- cooperative stage: coalesced float4 loads, convert once, LDS write ----
    #pragma unroll
    for (int it = 0; it < (RPB * F4PR) / 256; ++it) {
        int idx = it * 256 + tid;
        int row = idx / F4PR;
        int kk  = (idx - row * F4PR) * 4;
        int grow = blockIdx.x * RPB + row;
        const float* src = A + (size_t)(grow < N_NODES ? grow : N_NODES - 1) * KDIM + kk;
        float4 v = *(const float4*)src;
        bf16x4 h, lo;
        h[0] = (__bf16)v.x; h[1] = (__bf16)v.y; h[2] = (__bf16)v.z; h[3] = (__bf16)v.w;
        lo[0] = (__bf16)(v.x - (float)h[0]);
        lo[1] = (__bf16)(v.y - (float)h[1]);
        lo[2] = (__bf16)(v.z - (float)h[2]);
        lo[3] = (__bf16)(v.w - (float)h[3]);
        *(bf16x4*)&ah[row][kk] = h;
        *(bf16x4*)&al[row][kk] = lo;
    }
    __syncthreads();

    int w = tid >> 6, l = tid & 63;
    int rw = (CGROUPS == 2) ? (w & 1) : w;
    int cg = (CGROUPS == 2) ? (w >> 1) : 0;
    int c0 = cg * CTW;
    int r0 = blockIdx.x * RPB + rw * 16;
    int rowL = rw * 16 + (l & 15);
    int koff = (l >> 4) * 8;

    // B double-buffer: prologue loads kt=0; loop prefetches kt+1 before MFMAs on kt.
    bf16x8 bh[2][CTW], bl[2][CTW];
    #pragma unroll
    for (int c = 0; c < CTW; ++c) {
        size_t bidx = ((size_t)((c0 + c) * KT + 0) * 64 + l) * 8;
        bh[0][c] = *(const bf16x8*)(Whi + bidx);
        bl[0][c] = *(const bf16x8*)(Wlo + bidx);
    }

    f32x4 acc[CTW];
    #pragma unroll
    for (int c = 0; c < CTW; ++c) acc[c] = (f32x4){0.f, 0.f, 0.f, 0.f};

    #pragma unroll
    for (int kt = 0; kt < KT; ++kt) {
        const int cur = kt & 1, nxt = cur ^ 1;
        if (kt + 1 < KT) {
            #pragma unroll
            for (int c = 0; c < CTW; ++c) {
                size_t bidx = ((size_t)((c0 + c) * KT + (kt + 1)) * 64 + l) * 8;
                bh[nxt][c] = *(const bf16x8*)(Whi + bidx);
                bl[nxt][c] = *(const bf16x8*)(Wlo + bidx);
            }
        }
        bf16x8 ahi = *(const bf16x8*)&ah[rowL][kt * 32 + koff];
        bf16x8 alo = *(const bf16x8*)&al[rowL][kt * 32 + koff];
        #pragma unroll
        for (int c = 0; c < CTW; ++c) {
            acc[c] = __builtin_amdgcn_mfma_f32_16x16x32_bf16(ahi, bh[cur][c], acc[c], 0, 0, 0);
            acc[c] = __builtin_amdgcn_mfma_f32_16x16x32_bf16(ahi, bl[cur][c], acc[c], 0, 0, 0);
            acc[c] = __builtin_amdgcn_mfma_f32_16x16x32_bf16(alo, bh[cur][c], acc[c], 0, 0, 0);
        }
    }

    int crow0 = r0 + (l >> 4) * 4;
    int ccol = l & 15;

    // C store
    #pragma unroll
    for (int c = 0; c < CTW; ++c) {
        #pragma unroll
        for (int r = 0; r < 4; ++r) {
            int row = crow0 + r;
            if (row < N_NODES) {
                if constexpr (CBF16)
                    ((__bf16*)Cout)[(size_t)row * NC + (c0 + c) * 16 + ccol] = (__bf16)acc[c][r];
                else
                    ((float*)Cout)[(size_t)row * NC + (c0 + c) * 16 + ccol] = acc[c][r];
            }
        }
    }

    // fused attention scalars: per-row dot with a_s / a_d (wave-local by construction)
    float as_c[CTW], ad_c[CTW];
    #pragma unroll
    for (int c = 0; c < CTW; ++c) {
        as_c[c] = a_s[(c0 + c) * 16 + ccol];
        ad_c[c] = a_d[(c0 + c) * 16 + ccol];
    }

    #pragma unroll
    for (int r = 0; r < 4; ++r) {
        int row = crow0 + r;
        if constexpr (NC == 128) {
            // CTW=4 here: 2 heads per wave, head spans 2 col tiles
            #pragma unroll
            for (int hl = 0; hl < 2; ++hl) {
                int h = cg * 2 + hl;
                float vs = acc[2 * hl][r] * as_c[2 * hl] + acc[2 * hl + 1][r] * as_c[2 * hl + 1];
                float vd = acc[2 * hl][r] * ad_c[2 * hl] + acc[2 * hl + 1][r] * ad_c[2 * hl + 1];
                #pragma unroll
                for (int d = 1; d < 16; d <<= 1) {
                    vs += __shfl_xor(vs, d);
                    vd += __shfl_xor(vd, d);
                }
                if (ccol == 0 && row < N_NODES) { als[row * 4 + h] = vs; ald[row * 4 + h] = vd; }
            }
        } else {
            float vs = 0.f, vd = 0.f;
            #pragma unroll
            for (int c = 0; c < CTW; ++c) { vs += acc[c][r] * as_c[c]; vd += acc[c][r] * ad_c[c]; }
            #pragma unroll
            for (int d = 1; d < 16; d <<= 1) {
                vs += __shfl_xor(vs, d);
                vd += __shfl_xor(vd, d);
            }
            if (ccol == 0 && row < N_NODES) { als[row] = vs; ald[row] = vd; }
        }
    }
}

__device__ __forceinline__ float lrelu(float x) { return x > 0.f ? x : 0.2f * x; }
__device__ __forceinline__ float bfhi(unsigned v) { return __uint_as_float(v & 0xffff0000u); }
__device__ __forceinline__ float bflo(unsigned v) { return __uint_as_float(v << 16); }

// -------------------- per-edge attention weights (unnormalized) --------------------

__global__ __launch_bounds__(256) void p1_kernel(const int2* __restrict__ epair,
                                                 const float* __restrict__ als,
                                                 const float* __restrict__ ald,
                                                 float* __restrict__ p1) {
    int j = blockIdx.x * 256 + threadIdx.x;
    if (j >= E_EDGES + N_NODES) return;
    int2 e = epair[j];
    float4 as = *(const float4*)&als[e.x * 4];
    float4 ad = *(const float4*)&ald[e.y * 4];
    float4 p;
    p.x = __expf(lrelu(as.x + ad.x));
    p.y = __expf(lrelu(as.y + ad.y));
    p.z = __expf(lrelu(as.z + ad.z));
    p.w = __expf(lrelu(as.w + ad.w));
    *(float4*)&p1[(size_t)j * 4] = p;
}

__global__ __launch_bounds__(256) void p2_kernel(const int2* __restrict__ epair,
                                                 const float* __restrict__ als,
                                                 const float* __restrict__ ald,
                                                 float* __restrict__ p2) {
    int j = blockIdx.x * 256 + threadIdx.x;
    if (j >= E_EDGES + N_NODES) return;
    int2 e = epair[j];
    p2[j] = __expf(lrelu(als[e.x] + ald[e.y]));
}

// -------------------- single-pass aggregation (streamed p) --------------------

// layer 1: 1 wave per dst. 4 groups x 16 lanes; group g handles edge j0+g;
// lane li covers cols li*8..li*8+7 (head li>>2) via one 16B load.
__global__ __launch_bounds__(256) void aggr1_kernel(const int* __restrict__ row_ptr,
                                                    const int2* __restrict__ epair,
                                                    const float* __restrict__ p1,
                                                    const __bf16* __restrict__ h1b,
                                                    const float* __restrict__ b1,
                                                    float* __restrict__ h2out) {
    int wid = blockIdx.x * 4 + (threadIdx.x >> 6);
    int lane = threadIdx.x & 63;
    int grp = lane >> 4, li = lane & 15;
    int hh = li >> 2;                       // head of this lane's 8 cols
    int beg = row_ptr[wid], end = row_ptr[wid + 1];
    float acc[8] = {0,0,0,0,0,0,0,0};
    float S = 0.f;
    for (int j0 = beg; j0 < end; j0 += 4) {
        int j = j0 + grp;
        bool valid = (j < end);
        int s = valid ? epair[j].x : 0;
        float p = valid ? p1[(size_t)j * 4 + hh] : 0.f;   // streamed, CSR-contiguous
        uint4 v = *(const uint4*)(h1b + (size_t)s * HC1 + li * 8);
        acc[0] += p * bflo(v.x); acc[1] += p * bfhi(v.x);
        acc[2] += p * bflo(v.y); acc[3] += p * bfhi(v.y);
        acc[4] += p * bflo(v.z); acc[5] += p * bfhi(v.z);
        acc[6] += p * bflo(v.w); acc[7] += p * bfhi(v.w);
        S += p;
    }
    // reduce across the 4 groups (lane bits 4,5)
    #pragma unroll
    for (int d = 16; d < 64; d <<= 1) {
        #pragma unroll
        for (int c = 0; c < 8; ++c) acc[c] += __shfl_xor(acc[c], d);
        S += __shfl_xor(S, d);
    }
    if (grp == 0) {
        float inv = 1.f / S;
        const float* bp = b1 + li * 8;
        float4 o0, o1;
        o0.x = lrelu(acc[0] * inv + bp[0]);
        o0.y = lrelu(acc[1] * inv + bp[1]);
        o0.z = lrelu(acc[2] * inv + bp[2]);
        o0.w = lrelu(acc[3] * inv + bp[3]);
        o1.x = lrelu(acc[4] * inv + bp[4]);
        o1.y = lrelu(acc[5] * inv + bp[5]);
        o1.z = lrelu(acc[6] * inv + bp[6]);
        o1.w = lrelu(acc[7] * inv + bp[7]);
        float* orow = h2out + (size_t)wid * HC1 + li * 8;
        *(float4*)orow = o0;
        *(float4*)(orow + 4) = o1;
    }
}

// layer 2: 1 wave per dst; 4 groups x 16 lanes; lane li covers cols li*4..li*4+3.
__global__ __launch_bounds__(256) void aggr2_kernel(const int* __restrict__ row_ptr,
                                                    const int2* __restrict__ epair,
                                                    const float* __restrict__ p2,
                                                    const float* __restrict__ g,
                                                    const float* __restrict__ b2,
                                                    float* __restrict__ out) {
    int wid = blockIdx.x * 4 + (threadIdx.x >> 6);
    int lane = threadIdx.x & 63;
    int grp = lane >> 4, li = lane & 15;
    int beg = row_ptr[wid], end = row_ptr[wid + 1];
    float a0 = 0.f, a1 = 0.f, a2 = 0.f, a3 = 0.f, S = 0.f;
    for (int j0 = beg; j0 < end; j0 += 4) {
        int j = j0 + grp;
        bool valid = (j < end);
        int s = valid ? epair[j].x : 0;
        float p = valid ? p2[j] : 0.f;
        float4 gv = *(const float4*)(g + (size_t)s * F_OUT + li * 4);
        a0 += p * gv.x; a1 += p * gv.y; a2 += p * gv.z; a3 += p * gv.w;
        S += p;
    }
    #pragma unroll
    for (int d = 16; d < 64; d <<= 1) {
        a0 += __shfl_xor(a0, d); a1 += __shfl_xor(a1, d);
        a2 += __shfl_xor(a2, d); a3 += __shfl_xor(a3, d);
        S += __shfl_xor(S, d);
    }
    if (grp == 0) {
        float inv = 1.f / S;
        const float* bp = b2 + li * 4;
        float4 o;
        o.x = a0 * inv + bp[0];
        o.y = a1 * inv + bp[1];
        o.z = a2 * inv + bp[2];
        o.w = a3 * inv + bp[3];
        *(float4*)(out + (size_t)wid * F_OUT + li * 4) = o;
    }
}

// -------------------- launch --------------------

extern "C" void kernel_launch(void* const* d_in, const int* in_sizes, int n_in,
                              void* d_out, int out_size, void* d_ws, size_t ws_size,
                              hipStream_t stream) {
    const float* x      = (const float*)d_in[0];
    const int*   ei     = (const int*)  d_in[1];
    const float* W1     = (const float*)d_in[2];
    const float* a_src1 = (const float*)d_in[3];
    const float* a_dst1 = (const float*)d_in[4];
    const float* b1     = (const float*)d_in[5];
    const float* W2     = (const float*)d_in[6];
    const float* a_src2 = (const float*)d_in[7];
    const float* a_dst2 = (const float*)d_in[8];
    const float* b2     = (const float*)d_in[9];
    float* out = (float*)d_out;
    char* ws = (char*)d_ws;

    // workspace layout (bytes)
    __bf16* h1b    = (__bf16*)(ws + 0);         // N*128*2 = 12,800,000
    float* h2      = (float*)(ws + 12800000);   // 25,600,000
    float* g       = (float*)(ws + 38400000);   // 12,800,000
    float* als1    = (float*)(ws + 51200000);   // 800,000
    float* ald1    = (float*)(ws + 52000000);   // 800,000
    float* als2    = (float*)(ws + 52800000);   // 200,000
    float* ald2    = (float*)(ws + 53000000);   // 200,000
    int*   rowp    = (int*)  (ws + 53200000);   // 200,004 (pad to 53,400,064)
    int*   bcur    = (int*)  (ws + 53400064);   // 784 (pad to 53,401,088)
    int*   bbase   = (int*)  (ws + 53401088);   // 784 (pad to 53,402,112)
    int2*  bstage  = (int2*) (ws + 53402112);   // NBKT*BMAX*8 = 9,633,792 -> 63,035,904
    int2*  epair   = (int2*) (ws + 63035904);   // (E+N)*8 = 5,200,000 -> 68,235,904
    __bf16* whi1   = (__bf16*)(ws + 68235904);  // 65,536
    __bf16* wlo1   = (__bf16*)(ws + 68301440);  // 65,536
    __bf16* whi2   = (__bf16*)(ws + 68366976);  // 16,384
    __bf16* wlo2   = (__bf16*)(ws + 68383360);  // 16,384 (end 68,399,744)
    // recycled regions:
    float* p1 = g;                // consumed by aggr1 before gemm2 writes g
    float* p2 = (float*)h1b;      // h1b dead after aggr1

    const int TOT = E_EDGES + N_NODES;
    const int eb = (TOT + 255) / 256;

    zerob_kernel<<<1, 256, 0, stream>>>(bcur);
    bappend_kernel<<<NAB, 1024, 0, stream>>>(ei, bcur, bstage);
    bucket_scan_kernel<<<1, 256, 0, stream>>>(bcur, bbase, rowp);
    bsort_kernel<<<NBKT, 1024, 0, stream>>>(bcur, bbase, bstage, rowp, epair);

    pack_w_kernel<<<(F_IN * HC1 + HC1 * F_OUT + 255) / 256, 256, 0, stream>>>(
        W1, W2, whi1, wlo1, whi2, wlo2);

    // gemm1: 32 rows/block, 4 waves (2 row-halves x 2 col-halves) -> 1563 blocks
    gemm_mfma_kernel<F_IN, HC1, true, 2><<<(N_NODES + 31) / 32, 256, 0, stream>>>(
        x, whi1, wlo1, a_src1, a_dst1, h1b, als1, ald1);
    p1_kernel<<<eb, 256, 0, stream>>>(epair, als1, ald1, p1);
    aggr1_kernel<<<N_NODES / 4, 256, 0, stream>>>(rowp, epair, p1, h1b, b1, h2);

    // gemm2: 64 rows/block, 4 waves (row-quarters), full cols -> 782 blocks
    gemm_mfma_kernel<HC1, F_OUT, false, 1><<<(N_NODES + 63) / 64, 256, 0, stream>>>(
        h2, whi2, wlo2, a_src2, a_dst2, g, als2, ald2);
    p2_kernel<<<eb, 256, 0, stream>>>(epair, als2, ald2, p2);
    aggr2_kernel<<<N_NODES / 4, 256, 0, stream>>>(rowp, epair, p2, g, b2, out);
}

// Round 19
// 152.634 us; speedup vs baseline: 3.6373x; 1.0040x over previous
//
#include <hip/hip_runtime.h>
#include <hip/hip_bf16.h>

#define N_NODES 50000
#define E_EDGES 600000
#define F_IN    256
#define HC1     128   // 4 heads * 32
#define F_OUT   64
#define NBKT    196   // ceil(N_NODES/256) coarse dst-buckets
#define BMAX    6144  // per-bucket capacity (mean 3316, sigma ~58)
#define APB     8192  // edges per bappend block
#define NAB     80    // ceil((E+N)/APB)

typedef __bf16 bf16x8 __attribute__((ext_vector_type(8)));
typedef __bf16 bf16x4 __attribute__((ext_vector_type(4)));
typedef float  f32x4  __attribute__((ext_vector_type(4)));

// -------------------- CSR build: bucket sort w/ block-aggregated reservation --

__global__ void zerob_kernel(int* __restrict__ bcur) {
    if (threadIdx.x < NBKT) bcur[threadIdx.x] = 0;
}

__global__ __launch_bounds__(1024) void bappend_kernel(const int* __restrict__ ei,
                                                       int* __restrict__ bcur,
                                                       int2* __restrict__ bstage) {
    __shared__ int lcnt[NBKT];
    const int TOT = E_EDGES + N_NODES;
    int tid = threadIdx.x;
    int e0 = blockIdx.x * APB;
    int e1 = e0 + APB < TOT ? e0 + APB : TOT;
    if (tid < NBKT) lcnt[tid] = 0;
    __syncthreads();
    for (int i = e0 + tid; i < e1; i += 1024) {
        int d = (i < E_EDGES) ? ei[E_EDGES + i] : (i - E_EDGES);
        atomicAdd(&lcnt[d >> 8], 1);
    }
    __syncthreads();
    if (tid < NBKT) {
        int c = lcnt[tid];
        lcnt[tid] = c ? atomicAdd(&bcur[tid], c) : 0;   // reserve range; lcnt -> cursor
    }
    __syncthreads();
    for (int i = e0 + tid; i < e1; i += 1024) {
        int s, d;
        if (i < E_EDGES) { s = ei[i]; d = ei[E_EDGES + i]; }
        else             { s = d = i - E_EDGES; }
        int b = d >> 8;
        int pos = atomicAdd(&lcnt[b], 1);               // LDS cursor
        bstage[(size_t)b * BMAX + pos] = make_int2(s, d);
    }
}

// per-bucket counting sort in LDS; computes its own bucket base (redundant
// 196-element scan per block -- cheap, saves a kernel launch); writes rowp
// (256 dsts) + sorted epair region, all coalesced.
__global__ __launch_bounds__(1024) void bsort_kernel(const int* __restrict__ bcur,
                                                     const int2* __restrict__ bstage,
                                                     int* __restrict__ rowp,
                                                     int2* __restrict__ epair) {
    __shared__ int cnt[256], cur[256], ws4[4];
    __shared__ int bbase_s;
    __shared__ int2 sorted[BMAX];
    int b = blockIdx.x, tid = threadIdx.x;
    int nb = bcur[b]; if (nb > BMAX) nb = BMAX;
    int d0 = b << 8;

    // redundant per-block exclusive scan of the 196 bucket counts
    if (tid < 256) {
        int lane = tid & 63, w = tid >> 6;
        int v = (tid < NBKT) ? bcur[tid] : 0;
        int s = v;
        #pragma unroll
        for (int d = 1; d < 64; d <<= 1) {
            int t = __shfl_up(s, d);
            if (lane >= d) s += t;
        }
        if (lane == 63) ws4[w] = s;
        __syncthreads();
        if (tid == 0) {
            int r = 0;
            #pragma unroll
            for (int q = 0; q < 4; ++q) { int t = ws4[q]; ws4[q] = r; r += t; }
        }
        __syncthreads();
        if (tid == b) bbase_s = ws4[w] + s - v;
        if (b == 0 && tid == 0) rowp[N_NODES] = E_EDGES + N_NODES;
    } else {
        __syncthreads();
        __syncthreads();
    }
    if (tid < 256) cnt[tid] = 0;
    __syncthreads();
    int base = bbase_s;

    const int2* bs = bstage + (size_t)b * BMAX;
    for (int e = tid; e < nb; e += 1024)
        atomicAdd(&cnt[bs[e].y - d0], 1);
    __syncthreads();
    int v = 0, s = 0;
    if (tid < 256) {
        int lane = tid & 63, w = tid >> 6;
        v = cnt[tid];
        s = v;
        #pragma unroll
        for (int d = 1; d < 64; d <<= 1) {
            int t = __shfl_up(s, d);
            if (lane >= d) s += t;
        }
        if (lane == 63) ws4[w] = s;
    }
    __syncthreads();
    if (tid == 0) {
        int r = 0;
        #pragma unroll
        for (int q = 0; q < 4; ++q) { int t = ws4[q]; ws4[q] = r; r += t; }
    }
    __syncthreads();
    if (tid < 256) {
        int excl = ws4[tid >> 6] + s - v;
        cur[tid] = excl;
        int d = d0 + tid;
        if (d < N_NODES) rowp[d] = base + excl;
    }
    __syncthreads();
    for (int e = tid; e < nb; e += 1024) {
        int2 ed = bs[e];
        int p = atomicAdd(&cur[ed.y - d0], 1);
        sorted[p] = ed;
    }
    __syncthreads();
    for (int e = tid; e < nb; e += 1024)
        epair[base + e] = sorted[e];   // linear, coalesced
}

// -------------------- W pre-pack into MFMA B-fragment order (bf16 hi/lo) ------

__global__ void pack_w_kernel(const float* __restrict__ W1, const float* __restrict__ W2,
                              __bf16* __restrict__ hi1, __bf16* __restrict__ lo1,
                              __bf16* __restrict__ hi2, __bf16* __restrict__ lo2) {
    int tid = blockIdx.x * blockDim.x + threadIdx.x;
    if (tid >= F_IN * HC1 + HC1 * F_OUT) return;
    if (tid < F_IN * HC1) {
        int t = tid;
        int j = t & 7, l = (t >> 3) & 63, kt = (t >> 9) & 7, ct = t >> 12;
        int k = kt * 32 + (l >> 4) * 8 + j;
        int col = ct * 16 + (l & 15);
        float v = W1[k * HC1 + col];
        __bf16 h = (__bf16)v;
        hi1[t] = h;
        lo1[t] = (__bf16)(v - (float)h);
    } else {
        int t = tid - F_IN * HC1;
        int j = t & 7, l = (t >> 3) & 63, kt = (t >> 9) & 3, ct = t >> 11;
        int k = kt * 32 + (l >> 4) * 8 + j;
        int col = ct * 16 + (l & 15);
        float v = W2[k * F_OUT + col];
        __bf16 h = (__bf16)v;
        hi2[t] = h;
        lo2[t] = (__bf16)(v - (float)h);
    }
}

// -------------------- LDS-staged split-bf16 MFMA GEMM + fused al epilogue -----
// launch_bounds(256,1): LDS (33KB) already caps occupancy at 4 blocks/CU =
// 4 waves/SIMD, so relaxing the VGPR cap to 512 costs nothing -- it frees the
// allocator to keep all 8 staging float4s in flight (load-all/convert-all),
// breaking the serialized load->convert chain (R18: VGPR=52 forced it).

template<int KDIM, int NC, bool CBF16, int CGROUPS>
__global__ __launch_bounds__(256, 1) void gemm_mfma_kernel(const float* __restrict__ A,
                                                           const __bf16* __restrict__ Whi,
                                                           const __bf16* __restrict__ Wlo,
                                                           const float* __restrict__ a_s,
                                                           const float* __restrict__ a_d,
                                                           void* __restrict__ Cout,
                                                           float* __restrict__ als,
                                                           float* __restrict__ ald) {
    constexpr int KT   = KDIM / 32;
    constexpr int CT   = NC / 16;          // total col tiles
    constexpr int CTW  = CT / CGROUPS;     // col tiles per wave
    constexpr int RPB  = (CGROUPS == 2) ? 32 : 64;
    constexpr int LSTR = KDIM + 8;         // bf16 row stride: 16B-aligned, 2-way banks
    constexpr int F4PR = KDIM / 4;         // float4 per row
    constexpr int NIT  = (RPB * F4PR) / 256;   // 8 staging float4 per thread
    __shared__ __bf16 ah[RPB][LSTR];
    __shared__ __bf16 al[RPB][LSTR];

    int tid = threadIdx.x;

    // ---- stage: issue ALL loads first (independent, stay in flight), then
    // convert+write. Requires relaxed VGPR cap (launch_bounds min-waves=1).
    float4 rv[NIT];
    int rrow[NIT], rkk[NIT];
    #pragma unroll
    for (int it = 0; it < NIT; ++it) {
        int idx = it * 256 + tid;
        int row = idx / F4PR;
        int kk  = (idx - row * F4PR) * 4;
        int grow = blockIdx.x * RPB + row;
        rv[it] = *(const float4*)(A + (size_t)(grow < N_NODES ? grow : N_NODES - 1) * KDIM + kk);
        rrow[it] = row;
        rkk[it] = kk;
    }
    #pragma unroll
    for (int it = 0; it < NIT; ++it) {
        float4 v = rv[it];
        bf16x4 h, lo;
        h[0] = (__bf16)v.x; h[1] = (__bf16)v.y; h[2] = (__bf16)v.z; h[3] = (__bf16)v.w;
        lo[0] = (__bf16)(v.x - (float)h[0]);
        lo[1] = (__bf16)(v.y - (float)h[1]);
        lo[2] = (__bf16)(v.z - (float)h[2]);
        lo[3] = (__bf16)(v.w - (float)h[3]);
        *(bf16x4*)&ah[rrow[it]][rkk[it]] = h;
        *(bf16x4*)&al[rrow[it]][rkk[it]] = lo;
    }
    __syncthreads();

    int w = tid >> 6, l = tid & 63;
    int rw = (CGROUPS == 2) ? (w & 1) : w;
    int cg = (CGROUPS == 2) ? (w >> 1) : 0;
    int c0 = cg * CTW;
    int r0 = blockIdx.x * RPB + rw * 16;
    int rowL = rw * 16 + (l & 15);
    int koff = (l >> 4) * 8;

    // B double-buffer: prologue loads kt=0; loop prefetches kt+1 before MFMAs on kt.
    bf16x8 bh[2][CTW], bl[2][CTW];
    #pragma unroll
    for (int c = 0; c < CTW; ++c) {
        size_t bidx = ((size_t)((c0 + c) * KT + 0) * 64 + l) * 8;
        bh[0][c] = *(const bf16x8*)(Whi + bidx);
        bl[0][c] = *(const bf16x8*)(Wlo + bidx);
    }

    f32x4 acc[CTW];
    #pragma unroll
    for (int c = 0; c < CTW; ++c) acc[c] = (f32x4){0.f, 0.f, 0.f, 0.f};

    #pragma unroll
    for (int kt = 0; kt < KT; ++kt) {
        const int cur = kt & 1, nxt = cur ^ 1;
        if (kt + 1 < KT) {
            #pragma unroll
            for (int c = 0; c < CTW; ++c) {
                size_t bidx = ((size_t)((c0 + c) * KT + (kt + 1)) * 64 + l) * 8;
                bh[nxt][c] = *(const bf16x8*)(Whi + bidx);
                bl[nxt][c] = *(const bf16x8*)(Wlo + bidx);
            }
        }
        bf16x8 ahi = *(const bf16x8*)&ah[rowL][kt * 32 + koff];
        bf16x8 alo = *(const bf16x8*)&al[rowL][kt * 32 + koff];
        #pragma unroll
        for (int c = 0; c < CTW; ++c) {
            acc[c] = __builtin_amdgcn_mfma_f32_16x16x32_bf16(ahi, bh[cur][c], acc[c], 0, 0, 0);
            acc[c] = __builtin_amdgcn_mfma_f32_16x16x32_bf16(ahi, bl[cur][c], acc[c], 0, 0, 0);
            acc[c] = __builtin_amdgcn_mfma_f32_16x16x32_bf16(alo, bh[cur][c], acc[c], 0, 0, 0);
        }
    }

    int crow0 = r0 + (l >> 4) * 4;
    int ccol = l & 15;

    // C store
    #pragma unroll
    for (int c = 0; c < CTW; ++c) {
        #pragma unroll
        for (int r = 0; r < 4; ++r) {
            int row = crow0 + r;
            if (row < N_NODES) {
                if constexpr (CBF16)
                    ((__bf16*)Cout)[(size_t)row * NC + (c0 + c) * 16 + ccol] = (__bf16)acc[c][r];
                else
                    ((float*)Cout)[(size_t)row * NC + (c0 + c) * 16 + ccol] = acc[c][r];
            }
        }
    }

    // fused attention scalars: per-row dot with a_s / a_d (wave-local by construction)
    float as_c[CTW], ad_c[CTW];
    #pragma unroll
    for (int c = 0; c < CTW; ++c) {
        as_c[c] = a_s[(c0 + c) * 16 + ccol];
        ad_c[c] = a_d[(c0 + c) * 16 + ccol];
    }

    #pragma unroll
    for (int r = 0; r < 4; ++r) {
        int row = crow0 + r;
        if constexpr (NC == 128) {
            // CTW=4 here: 2 heads per wave, head spans 2 col tiles
            #pragma unroll
            for (int hl = 0; hl < 2; ++hl) {
                int h = cg * 2 + hl;
                float vs = acc[2 * hl][r] * as_c[2 * hl] + acc[2 * hl + 1][r] * as_c[2 * hl + 1];
                float vd = acc[2 * hl][r] * ad_c[2 * hl] + acc[2 * hl + 1][r] * ad_c[2 * hl + 1];
                #pragma unroll
                for (int d = 1; d < 16; d <<= 1) {
                    vs += __shfl_xor(vs, d);
                    vd += __shfl_xor(vd, d);
                }
                if (ccol == 0 && row < N_NODES) { als[row * 4 + h] = vs; ald[row * 4 + h] = vd; }
            }
        } else {
            float vs = 0.f, vd = 0.f;
            #pragma unroll
            for (int c = 0; c < CTW; ++c) { vs += acc[c][r] * as_c[c]; vd += acc[c][r] * ad_c[c]; }
            #pragma unroll
            for (int d = 1; d < 16; d <<= 1) {
                vs += __shfl_xor(vs, d);
                vd += __shfl_xor(vd, d);
            }
            if (ccol == 0 && row < N_NODES) { als[row] = vs; ald[row] = vd; }
        }
    }
}

__device__ __forceinline__ float lrelu(float x) { return x > 0.f ? x : 0.2f * x; }
__device__ __forceinline__ float bfhi(unsigned v) { return __uint_as_float(v & 0xffff0000u); }
__device__ __forceinline__ float bflo(unsigned v) { return __uint_as_float(v << 16); }

// -------------------- per-edge attention weights (unnormalized) --------------------

__global__ __launch_bounds__(256) void p1_kernel(const int2* __restrict__ epair,
                                                 const float* __restrict__ als,
                                                 const float* __restrict__ ald,
                                                 float* __restrict__ p1) {
    int j = blockIdx.x * 256 + threadIdx.x;
    if (j >= E_EDGES + N_NODES) return;
    int2 e = epair[j];
    float4 as = *(const float4*)&als[e.x * 4];
    float4 ad = *(const float4*)&ald[e.y * 4];
    float4 p;
    p.x = __expf(lrelu(as.x + ad.x));
    p.y = __expf(lrelu(as.y + ad.y));
    p.z = __expf(lrelu(as.z + ad.z));
    p.w = __expf(lrelu(as.w + ad.w));
    *(float4*)&p1[(size_t)j * 4] = p;
}

__global__ __launch_bounds__(256) void p2_kernel(const int2* __restrict__ epair,
                                                 const float* __restrict__ als,
                                                 const float* __restrict__ ald,
                                                 float* __restrict__ p2) {
    int j = blockIdx.x * 256 + threadIdx.x;
    if (j >= E_EDGES + N_NODES) return;
    int2 e = epair[j];
    p2[j] = __expf(lrelu(als[e.x] + ald[e.y]));
}

// -------------------- single-pass aggregation (streamed p) --------------------

__global__ __launch_bounds__(256) void aggr1_kernel(const int* __restrict__ row_ptr,
                                                    const int2* __restrict__ epair,
                                                    const float* __restrict__ p1,
                                                    const __bf16* __restrict__ h1b,
                                                    const float* __restrict__ b1,
                                                    float* __restrict__ h2out) {
    int wid = blockIdx.x * 4 + (threadIdx.x >> 6);
    int lane = threadIdx.x & 63;
    int grp = lane >> 4, li = lane & 15;
    int hh = li >> 2;                       // head of this lane's 8 cols
    int beg = row_ptr[wid], end = row_ptr[wid + 1];
    float acc[8] = {0,0,0,0,0,0,0,0};
    float S = 0.f;
    for (int j0 = beg; j0 < end; j0 += 4) {
        int j = j0 + grp;
        bool valid = (j < end);
        int s = valid ? epair[j].x : 0;
        float p = valid ? p1[(size_t)j * 4 + hh] : 0.f;   // streamed, CSR-contiguous
        uint4 v = *(const uint4*)(h1b + (size_t)s * HC1 + li * 8);
        acc[0] += p * bflo(v.x); acc[1] += p * bfhi(v.x);
        acc[2] += p * bflo(v.y); acc[3] += p * bfhi(v.y);
        acc[4] += p * bflo(v.z); acc[5] += p * bfhi(v.z);
        acc[6] += p * bflo(v.w); acc[7] += p * bfhi(v.w);
        S += p;
    }
    // reduce across the 4 groups (lane bits 4,5)
    #pragma unroll
    for (int d = 16; d < 64; d <<= 1) {
        #pragma unroll
        for (int c = 0; c < 8; ++c) acc[c] += __shfl_xor(acc[c], d);
        S += __shfl_xor(S, d);
    }
    if (grp == 0) {
        float inv = 1.f / S;
        const float* bp = b1 + li * 8;
        float4 o0, o1;
        o0.x = lrelu(acc[0] * inv + bp[0]);
        o0.y = lrelu(acc[1] * inv + bp[1]);
        o0.z = lrelu(acc[2] * inv + bp[2]);
        o0.w = lrelu(acc[3] * inv + bp[3]);
        o1.x = lrelu(acc[4] * inv + bp[4]);
        o1.y = lrelu(acc[5] * inv + bp[5]);
        o1.z = lrelu(acc[6] * inv + bp[6]);
        o1.w = lrelu(acc[7] * inv + bp[7]);
        float* orow = h2out + (size_t)wid * HC1 + li * 8;
        *(float4*)orow = o0;
        *(float4*)(orow + 4) = o1;
    }
}

__global__ __launch_bounds__(256) void aggr2_kernel(const int* __restrict__ row_ptr,
                                                    const int2* __restrict__ epair,
                                                    const float* __restrict__ p2,
                                                    const float* __restrict__ g,
                                                    const float* __restrict__ b2,
                                                    float* __restrict__ out) {
    int wid = blockIdx.x * 4 + (threadIdx.x >> 6);
    int lane = threadIdx.x & 63;
    int grp = lane >> 4, li = lane & 15;
    int beg = row_ptr[wid], end = row_ptr[wid + 1];
    float a0 = 0.f, a1 = 0.f, a2 = 0.f, a3 = 0.f, S = 0.f;
    for (int j0 = beg; j0 < end; j0 += 4) {
        int j = j0 + grp;
        bool valid = (j < end);
        int s = valid ? epair[j].x : 0;
        float p = valid ? p2[j] : 0.f;
        float4 gv = *(const float4*)(g + (size_t)s * F_OUT + li * 4);
        a0 += p * gv.x; a1 += p * gv.y; a2 += p * gv.z; a3 += p * gv.w;
        S += p;
    }
    #pragma unroll
    for (int d = 16; d < 64; d <<= 1) {
        a0 += __shfl_xor(a0, d); a1 += __shfl_xor(a1, d);
        a2 += __shfl_xor(a2, d); a3 += __shfl_xor(a3, d);
        S += __shfl_xor(S, d);
    }
    if (grp == 0) {
        float inv = 1.f / S;
        const float* bp = b2 + li * 4;
        float4 o;
        o.x = a0 * inv + bp[0];
        o.y = a1 * inv + bp[1];
        o.z = a2 * inv + bp[2];
        o.w = a3 * inv + bp[3];
        *(float4*)(out + (size_t)wid * F_OUT + li * 4) = o;
    }
}

// -------------------- launch --------------------

extern "C" void kernel_launch(void* const* d_in, const int* in_sizes, int n_in,
                              void* d_out, int out_size, void* d_ws, size_t ws_size,
                              hipStream_t stream) {
    const float* x      = (const float*)d_in[0];
    const int*   ei     = (const int*)  d_in[1];
    const float* W1     = (const float*)d_in[2];
    const float* a_src1 = (const float*)d_in[3];
    const float* a_dst1 = (const float*)d_in[4];
    const float* b1     = (const float*)d_in[5];
    const float* W2     = (const float*)d_in[6];
    const float* a_src2 = (const float*)d_in[7];
    const float* a_dst2 = (const float*)d_in[8];
    const float* b2     = (const float*)d_in[9];
    float* out = (float*)d_out;
    char* ws = (char*)d_ws;

    // workspace layout (bytes)
    __bf16* h1b    = (__bf16*)(ws + 0);         // N*128*2 = 12,800,000
    float* h2      = (float*)(ws + 12800000);   // 25,600,000
    float* g       = (float*)(ws + 38400000);   // 12,800,000
    float* als1    = (float*)(ws + 51200000);   // 800,000
    float* ald1    = (float*)(ws + 52000000);   // 800,000
    float* als2    = (float*)(ws + 52800000);   // 200,000
    float* ald2    = (float*)(ws + 53000000);   // 200,000
    int*   rowp    = (int*)  (ws + 53200000);   // 200,004 (pad to 53,400,064)
    int*   bcur    = (int*)  (ws + 53400064);   // 784 (pad to 53,401,088)
    int2*  bstage  = (int2*) (ws + 53402112);   // NBKT*BMAX*8 = 9,633,792 -> 63,035,904
    int2*  epair   = (int2*) (ws + 63035904);   // (E+N)*8 = 5,200,000 -> 68,235,904
    __bf16* whi1   = (__bf16*)(ws + 68235904);  // 65,536
    __bf16* wlo1   = (__bf16*)(ws + 68301440);  // 65,536
    __bf16* whi2   = (__bf16*)(ws + 68366976);  // 16,384
    __bf16* wlo2   = (__bf16*)(ws + 68383360);  // 16,384 (end 68,399,744)
    // recycled regions:
    float* p1 = g;                // consumed by aggr1 before gemm2 writes g
    float* p2 = (float*)h1b;      // h1b dead after aggr1

    const int TOT = E_EDGES + N_NODES;
    const int eb = (TOT + 255) / 256;

    zerob_kernel<<<1, 256, 0, stream>>>(bcur);
    bappend_kernel<<<NAB, 1024, 0, stream>>>(ei, bcur, bstage);
    bsort_kernel<<<NBKT, 1024, 0, stream>>>(bcur, bstage, rowp, epair);

    pack_w_kernel<<<(F_IN * HC1 + HC1 * F_OUT + 255) / 256, 256, 0, stream>>>(
        W1, W2, whi1, wlo1, whi2, wlo2);

    // gemm1: 32 rows/block, 4 waves (2 row-halves x 2 col-halves) -> 1563 blocks
    gemm_mfma_kernel<F_IN, HC1, true, 2><<<(N_NODES + 31) / 32, 256, 0, stream>>>(
        x, whi1, wlo1, a_src1, a_dst1, h1b, als1, ald1);
    p1_kernel<<<eb, 256, 0, stream>>>(epair, als1, ald1, p1);
    aggr1_kernel<<<N_NODES / 4, 256, 0, stream>>>(rowp, epair, p1, h1b, b1, h2);

    // gemm2: 64 rows/block, 4 waves (row-quarters), full cols -> 782 blocks
    gemm_mfma_kernel<HC1, F_OUT, false, 1><<<(N_NODES + 63) / 64, 256, 0, stream>>>(
        h2, whi2, wlo2, a_src2, a_dst2, g, als2, ald2);
    p2_kernel<<<eb, 256, 0, stream>>>(epair, als2, ald2, p2);
    aggr2_kernel<<<N_NODES / 4, 256, 0, stream>>>(rowp, epair, p2, g, b2, out);
}

// Round 20
// 149.206 us; speedup vs baseline: 3.7208x; 1.0230x over previous
//
#include <hip/hip_runtime.h>
#include <hip/hip_bf16.h>

#define N_NODES 50000
#define E_EDGES 600000
#define F_IN    256
#define HC1     128   // 4 heads * 32
#define F_OUT   64
#define NBKT    196   // ceil(N_NODES/256) coarse dst-buckets
#define BMAX    6144  // per-bucket capacity (mean 3316, sigma ~58)
#define APB     8192  // edges per bappend chunk
#define NAB     80    // ceil((E+N)/APB)
#define GB1     1563  // gemm1 tile blocks = ceil(N/32)
#define NPACK   (F_IN * HC1 + HC1 * F_OUT)   // 40960

typedef __bf16 bf16x8 __attribute__((ext_vector_type(8)));
typedef __bf16 bf16x4 __attribute__((ext_vector_type(4)));
typedef float  f32x4  __attribute__((ext_vector_type(4)));

__device__ __forceinline__ float lrelu(float x) { return x > 0.f ? x : 0.2f * x; }
__device__ __forceinline__ float bfhi(unsigned v) { return __uint_as_float(v & 0xffff0000u); }
__device__ __forceinline__ float bflo(unsigned v) { return __uint_as_float(v << 16); }

// -------------------- init: zero bucket cursors + pack W (fused) --------------
// block 0: zero bcur; blocks >=1: pack one 256-elem slice of W1/W2 into MFMA
// B-fragment order as bf16 hi/lo.

__global__ __launch_bounds__(256) void init_kernel(const float* __restrict__ W1,
                                                   const float* __restrict__ W2,
                                                   __bf16* __restrict__ hi1, __bf16* __restrict__ lo1,
                                                   __bf16* __restrict__ hi2, __bf16* __restrict__ lo2,
                                                   int* __restrict__ bcur) {
    if (blockIdx.x == 0) {
        if (threadIdx.x < NBKT) bcur[threadIdx.x] = 0;
        return;
    }
    int tid = (blockIdx.x - 1) * 256 + threadIdx.x;
    if (tid >= NPACK) return;
    if (tid < F_IN * HC1) {
        int t = tid;
        int j = t & 7, l = (t >> 3) & 63, kt = (t >> 9) & 7, ct = t >> 12;
        int k = kt * 32 + (l >> 4) * 8 + j;
        int col = ct * 16 + (l & 15);
        float v = W1[k * HC1 + col];
        __bf16 h = (__bf16)v;
        hi1[t] = h;
        lo1[t] = (__bf16)(v - (float)h);
    } else {
        int t = tid - F_IN * HC1;
        int j = t & 7, l = (t >> 3) & 63, kt = (t >> 9) & 3, ct = t >> 11;
        int k = kt * 32 + (l >> 4) * 8 + j;
        int col = ct * 16 + (l & 15);
        float v = W2[k * F_OUT + col];
        __bf16 h = (__bf16)v;
        hi2[t] = h;
        lo2[t] = (__bf16)(v - (float)h);
    }
}

// -------------------- fused gemm1 + bappend -----------------------------------
// Blocks [0,GB1): 32-row gemm1 tile (proven R15 structure: LDS-staged bf16
// hi/lo A, B reg-double-buffered, fused al epilogue). Blocks [GB1,GB1+NAB):
// CSR bucket-append chunks (independent of gemm1 -> ride under its 40us of
// idle bandwidth; block-aggregated reservation keeps global atomics at
// 80/address).

__global__ __launch_bounds__(256) void gemm1_bappend_kernel(
        const float* __restrict__ A,
        const __bf16* __restrict__ Whi, const __bf16* __restrict__ Wlo,
        const float* __restrict__ a_s, const float* __restrict__ a_d,
        __bf16* __restrict__ Cout, float* __restrict__ als, float* __restrict__ ald,
        const int* __restrict__ ei, int* __restrict__ bcur, int2* __restrict__ bstage) {
    __shared__ __bf16 ah[32][F_IN + 8];
    __shared__ __bf16 al[32][F_IN + 8];
    __shared__ int lcnt[NBKT];
    int tid = threadIdx.x;

    if (blockIdx.x >= GB1) {
        // ---------------- bappend chunk ----------------
        const int TOT = E_EDGES + N_NODES;
        int bb = (int)blockIdx.x - GB1;
        int e0 = bb * APB;
        int e1 = e0 + APB < TOT ? e0 + APB : TOT;
        if (tid < NBKT) lcnt[tid] = 0;
        __syncthreads();
        for (int i = e0 + tid; i < e1; i += 256) {
            int d = (i < E_EDGES) ? ei[E_EDGES + i] : (i - E_EDGES);
            atomicAdd(&lcnt[d >> 8], 1);
        }
        __syncthreads();
        if (tid < NBKT) {
            int c = lcnt[tid];
            lcnt[tid] = c ? atomicAdd(&bcur[tid], c) : 0;
        }
        __syncthreads();
        for (int i = e0 + tid; i < e1; i += 256) {
            int s, d;
            if (i < E_EDGES) { s = ei[i]; d = ei[E_EDGES + i]; }
            else             { s = d = i - E_EDGES; }
            int b = d >> 8;
            int pos = atomicAdd(&lcnt[b], 1);
            bstage[(size_t)b * BMAX + pos] = make_int2(s, d);
        }
        return;
    }

    // ---------------- gemm1 tile (KDIM=256, NC=128, CGROUPS=2) ----------------
    constexpr int KT = 8, CTW = 4, F4PR = 64;
    #pragma unroll
    for (int it = 0; it < 8; ++it) {
        int idx = it * 256 + tid;
        int row = idx / F4PR;
        int kk  = (idx - row * F4PR) * 4;
        int grow = blockIdx.x * 32 + row;
        const float* src = A + (size_t)(grow < N_NODES ? grow : N_NODES - 1) * F_IN + kk;
        float4 v = *(const float4*)src;
        bf16x4 h, lo;
        h[0] = (__bf16)v.x; h[1] = (__bf16)v.y; h[2] = (__bf16)v.z; h[3] = (__bf16)v.w;
        lo[0] = (__bf16)(v.x - (float)h[0]);
        lo[1] = (__bf16)(v.y - (float)h[1]);
        lo[2] = (__bf16)(v.z - (float)h[2]);
        lo[3] = (__bf16)(v.w - (float)h[3]);
        *(bf16x4*)&ah[row][kk] = h;
        *(bf16x4*)&al[row][kk] = lo;
    }
    __syncthreads();

    int w = tid >> 6, l = tid & 63;
    int rw = w & 1, cg = w >> 1;
    int c0 = cg * CTW;
    int r0 = blockIdx.x * 32 + rw * 16;
    int rowL = rw * 16 + (l & 15);
    int koff = (l >> 4) * 8;

    bf16x8 bh[2][CTW], bl[2][CTW];
    #pragma unroll
    for (int c = 0; c < CTW; ++c) {
        size_t bidx = ((size_t)((c0 + c) * KT + 0) * 64 + l) * 8;
        bh[0][c] = *(const bf16x8*)(Whi + bidx);
        bl[0][c] = *(const bf16x8*)(Wlo + bidx);
    }

    f32x4 acc[CTW];
    #pragma unroll
    for (int c = 0; c < CTW; ++c) acc[c] = (f32x4){0.f, 0.f, 0.f, 0.f};

    #pragma unroll
    for (int kt = 0; kt < KT; ++kt) {
        const int cur = kt & 1, nxt = cur ^ 1;
        if (kt + 1 < KT) {
            #pragma unroll
            for (int c = 0; c < CTW; ++c) {
                size_t bidx = ((size_t)((c0 + c) * KT + (kt + 1)) * 64 + l) * 8;
                bh[nxt][c] = *(const bf16x8*)(Whi + bidx);
                bl[nxt][c] = *(const bf16x8*)(Wlo + bidx);
            }
        }
        bf16x8 ahi = *(const bf16x8*)&ah[rowL][kt * 32 + koff];
        bf16x8 alo = *(const bf16x8*)&al[rowL][kt * 32 + koff];
        #pragma unroll
        for (int c = 0; c < CTW; ++c) {
            acc[c] = __builtin_amdgcn_mfma_f32_16x16x32_bf16(ahi, bh[cur][c], acc[c], 0, 0, 0);
            acc[c] = __builtin_amdgcn_mfma_f32_16x16x32_bf16(ahi, bl[cur][c], acc[c], 0, 0, 0);
            acc[c] = __builtin_amdgcn_mfma_f32_16x16x32_bf16(alo, bh[cur][c], acc[c], 0, 0, 0);
        }
    }

    int crow0 = r0 + (l >> 4) * 4;
    int ccol = l & 15;

    #pragma unroll
    for (int c = 0; c < CTW; ++c) {
        #pragma unroll
        for (int r = 0; r < 4; ++r) {
            int row = crow0 + r;
            if (row < N_NODES)
                Cout[(size_t)row * HC1 + (c0 + c) * 16 + ccol] = (__bf16)acc[c][r];
        }
    }

    float as_c[CTW], ad_c[CTW];
    #pragma unroll
    for (int c = 0; c < CTW; ++c) {
        as_c[c] = a_s[(c0 + c) * 16 + ccol];
        ad_c[c] = a_d[(c0 + c) * 16 + ccol];
    }

    #pragma unroll
    for (int r = 0; r < 4; ++r) {
        int row = crow0 + r;
        #pragma unroll
        for (int hl = 0; hl < 2; ++hl) {
            int h = cg * 2 + hl;
            float vs = acc[2 * hl][r] * as_c[2 * hl] + acc[2 * hl + 1][r] * as_c[2 * hl + 1];
            float vd = acc[2 * hl][r] * ad_c[2 * hl] + acc[2 * hl + 1][r] * ad_c[2 * hl + 1];
            #pragma unroll
            for (int d = 1; d < 16; d <<= 1) {
                vs += __shfl_xor(vs, d);
                vd += __shfl_xor(vd, d);
            }
            if (ccol == 0 && row < N_NODES) { als[row * 4 + h] = vs; ald[row * 4 + h] = vd; }
        }
    }
}

// -------------------- bsort + fused p1 ----------------------------------------
// Per-bucket counting sort in LDS (computes own base via redundant 196-scan),
// writes rowp + sorted epair; the final write loop also computes p1 per edge
// (als1/ald1 gathers are L2-resident; ald1 nearly-sequential since sorted).

__global__ __launch_bounds__(1024) void bsortp1_kernel(const int* __restrict__ bcur,
                                                       const int2* __restrict__ bstage,
                                                       const float* __restrict__ als1,
                                                       const float* __restrict__ ald1,
                                                       int* __restrict__ rowp,
                                                       int2* __restrict__ epair,
                                                       float* __restrict__ p1) {
    __shared__ int cnt[256], cur[256], ws4[4];
    __shared__ int bbase_s;
    __shared__ int2 sorted[BMAX];
    int b = blockIdx.x, tid = threadIdx.x;
    int nb = bcur[b]; if (nb > BMAX) nb = BMAX;
    int d0 = b << 8;

    if (tid < 256) {
        int lane = tid & 63, w = tid >> 6;
        int v = (tid < NBKT) ? bcur[tid] : 0;
        int s = v;
        #pragma unroll
        for (int d = 1; d < 64; d <<= 1) {
            int t = __shfl_up(s, d);
            if (lane >= d) s += t;
        }
        if (lane == 63) ws4[w] = s;
        __syncthreads();
        if (tid == 0) {
            int r = 0;
            #pragma unroll
            for (int q = 0; q < 4; ++q) { int t = ws4[q]; ws4[q] = r; r += t; }
        }
        __syncthreads();
        if (tid == b) bbase_s = ws4[w] + s - v;
        if (b == 0 && tid == 0) rowp[N_NODES] = E_EDGES + N_NODES;
    } else {
        __syncthreads();
        __syncthreads();
    }
    if (tid < 256) cnt[tid] = 0;
    __syncthreads();
    int base = bbase_s;

    const int2* bs = bstage + (size_t)b * BMAX;
    for (int e = tid; e < nb; e += 1024)
        atomicAdd(&cnt[bs[e].y - d0], 1);
    __syncthreads();
    int v = 0, s = 0;
    if (tid < 256) {
        int lane = tid & 63, w = tid >> 6;
        v = cnt[tid];
        s = v;
        #pragma unroll
        for (int d = 1; d < 64; d <<= 1) {
            int t = __shfl_up(s, d);
            if (lane >= d) s += t;
        }
        if (lane == 63) ws4[w] = s;
    }
    __syncthreads();
    if (tid == 0) {
        int r = 0;
        #pragma unroll
        for (int q = 0; q < 4; ++q) { int t = ws4[q]; ws4[q] = r; r += t; }
    }
    __syncthreads();
    if (tid < 256) {
        int excl = ws4[tid >> 6] + s - v;
        cur[tid] = excl;
        int d = d0 + tid;
        if (d < N_NODES) rowp[d] = base + excl;
    }
    __syncthreads();
    for (int e = tid; e < nb; e += 1024) {
        int2 ed = bs[e];
        int p = atomicAdd(&cur[ed.y - d0], 1);
        sorted[p] = ed;
    }
    __syncthreads();
    for (int e = tid; e < nb; e += 1024) {
        int2 ed = sorted[e];
        epair[base + e] = ed;
        float4 as = *(const float4*)&als1[ed.x * 4];
        float4 ad = *(const float4*)&ald1[ed.y * 4];
        float4 p;
        p.x = __expf(lrelu(as.x + ad.x));
        p.y = __expf(lrelu(as.y + ad.y));
        p.z = __expf(lrelu(as.z + ad.z));
        p.w = __expf(lrelu(as.w + ad.w));
        *(float4*)&p1[(size_t)(base + e) * 4] = p;
    }
}

// -------------------- generic gemm (used for layer 2) -------------------------

template<int KDIM, int NC, bool CBF16, int CGROUPS>
__global__ __launch_bounds__(256) void gemm_mfma_kernel(const float* __restrict__ A,
                                                        const __bf16* __restrict__ Whi,
                                                        const __bf16* __restrict__ Wlo,
                                                        const float* __restrict__ a_s,
                                                        const float* __restrict__ a_d,
                                                        void* __restrict__ Cout,
                                                        float* __restrict__ als,
                                                        float* __restrict__ ald) {
    constexpr int KT   = KDIM / 32;
    constexpr int CT   = NC / 16;
    constexpr int CTW  = CT / CGROUPS;
    constexpr int RPB  = (CGROUPS == 2) ? 32 : 64;
    constexpr int LSTR = KDIM + 8;
    constexpr int F4PR = KDIM / 4;
    __shared__ __bf16 ah[RPB][LSTR];
    __shared__ __bf16 al[RPB][LSTR];

    int tid = threadIdx.x;

    #pragma unroll
    for (int it = 0; it < (RPB * F4PR) / 256; ++it) {
        int idx = it * 256 + tid;
        int row = idx / F4PR;
        int kk  = (idx - row * F4PR) * 4;
        int grow = blockIdx.x * RPB + row;
        const float* src = A + (size_t)(grow < N_NODES ? grow : N_NODES - 1) * KDIM + kk;
        float4 v = *(const float4*)src;
        bf16x4 h, lo;
        h[0] = (__bf16)v.x; h[1] = (__bf16)v.y; h[2] = (__bf16)v.z; h[3] = (__bf16)v.w;
        lo[0] = (__bf16)(v.x - (float)h[0]);
        lo[1] = (__bf16)(v.y - (float)h[1]);
        lo[2] = (__bf16)(v.z - (float)h[2]);
        lo[3] = (__bf16)(v.w - (float)h[3]);
        *(bf16x4*)&ah[row][kk] = h;
        *(bf16x4*)&al[row][kk] = lo;
    }
    __syncthreads();

    int w = tid >> 6, l = tid & 63;
    int rw = (CGROUPS == 2) ? (w & 1) : w;
    int cg = (CGROUPS == 2) ? (w >> 1) : 0;
    int c0 = cg * CTW;
    int r0 = blockIdx.x * RPB + rw * 16;
    int rowL = rw * 16 + (l & 15);
    int koff = (l >> 4) * 8;

    bf16x8 bh[2][CTW], bl[2][CTW];
    #pragma unroll
    for (int c = 0; c < CTW; ++c) {
        size_t bidx = ((size_t)((c0 + c) * KT + 0) * 64 + l) * 8;
        bh[0][c] = *(const bf16x8*)(Whi + bidx);
        bl[0][c] = *(const bf16x8*)(Wlo + bidx);
    }

    f32x4 acc[CTW];
    #pragma unroll
    for (int c = 0; c < CTW; ++c) acc[c] = (f32x4){0.f, 0.f, 0.f, 0.f};

    #pragma unroll
    for (int kt = 0; kt < KT; ++kt) {
        const int cur = kt & 1, nxt = cur ^ 1;
        if (kt + 1 < KT) {
            #pragma unroll
            for (int c = 0; c < CTW; ++c) {
                size_t bidx = ((size_t)((c0 + c) * KT + (kt + 1)) * 64 + l) * 8;
                bh[nxt][c] = *(const bf16x8*)(Whi + bidx);
                bl[nxt][c] = *(const bf16x8*)(Wlo + bidx);
            }
        }
        bf16x8 ahi = *(const bf16x8*)&ah[rowL][kt * 32 + koff];
        bf16x8 alo = *(const bf16x8*)&al[rowL][kt * 32 + koff];
        #pragma unroll
        for (int c = 0; c < CTW; ++c) {
            acc[c] = __builtin_amdgcn_mfma_f32_16x16x32_bf16(ahi, bh[cur][c], acc[c], 0, 0, 0);
            acc[c] = __builtin_amdgcn_mfma_f32_16x16x32_bf16(ahi, bl[cur][c], acc[c], 0, 0, 0);
            acc[c] = __builtin_amdgcn_mfma_f32_16x16x32_bf16(alo, bh[cur][c], acc[c], 0, 0, 0);
        }
    }

    int crow0 = r0 + (l >> 4) * 4;
    int ccol = l & 15;

    #pragma unroll
    for (int c = 0; c < CTW; ++c) {
        #pragma unroll
        for (int r = 0; r < 4; ++r) {
            int row = crow0 + r;
            if (row < N_NODES) {
                if constexpr (CBF16)
                    ((__bf16*)Cout)[(size_t)row * NC + (c0 + c) * 16 + ccol] = (__bf16)acc[c][r];
                else
                    ((float*)Cout)[(size_t)row * NC + (c0 + c) * 16 + ccol] = acc[c][r];
            }
        }
    }

    float as_c[CTW], ad_c[CTW];
    #pragma unroll
    for (int c = 0; c < CTW; ++c) {
        as_c[c] = a_s[(c0 + c) * 16 + ccol];
        ad_c[c] = a_d[(c0 + c) * 16 + ccol];
    }

    #pragma unroll
    for (int r = 0; r < 4; ++r) {
        int row = crow0 + r;
        if constexpr (NC == 128) {
            #pragma unroll
            for (int hl = 0; hl < 2; ++hl) {
                int h = cg * 2 + hl;
                float vs = acc[2 * hl][r] * as_c[2 * hl] + acc[2 * hl + 1][r] * as_c[2 * hl + 1];
                float vd = acc[2 * hl][r] * ad_c[2 * hl] + acc[2 * hl + 1][r] * ad_c[2 * hl + 1];
                #pragma unroll
                for (int d = 1; d < 16; d <<= 1) {
                    vs += __shfl_xor(vs, d);
                    vd += __shfl_xor(vd, d);
                }
                if (ccol == 0 && row < N_NODES) { als[row * 4 + h] = vs; ald[row * 4 + h] = vd; }
            }
        } else {
            float vs = 0.f, vd = 0.f;
            #pragma unroll
            for (int c = 0; c < CTW; ++c) { vs += acc[c][r] * as_c[c]; vd += acc[c][r] * ad_c[c]; }
            #pragma unroll
            for (int d = 1; d < 16; d <<= 1) {
                vs += __shfl_xor(vs, d);
                vd += __shfl_xor(vd, d);
            }
            if (ccol == 0 && row < N_NODES) { als[row] = vs; ald[row] = vd; }
        }
    }
}

// -------------------- aggregation ---------------------------------------------

// layer 1: 1 wave per dst; 4 edge-groups x 16 lanes; streamed p1.
__global__ __launch_bounds__(256) void aggr1_kernel(const int* __restrict__ row_ptr,
                                                    const int2* __restrict__ epair,
                                                    const float* __restrict__ p1,
                                                    const __bf16* __restrict__ h1b,
                                                    const float* __restrict__ b1,
                                                    float* __restrict__ h2out) {
    int wid = blockIdx.x * 4 + (threadIdx.x >> 6);
    int lane = threadIdx.x & 63;
    int grp = lane >> 4, li = lane & 15;
    int hh = li >> 2;
    int beg = row_ptr[wid], end = row_ptr[wid + 1];
    float acc[8] = {0,0,0,0,0,0,0,0};
    float S = 0.f;
    for (int j0 = beg; j0 < end; j0 += 4) {
        int j = j0 + grp;
        bool valid = (j < end);
        int s = valid ? epair[j].x : 0;
        float p = valid ? p1[(size_t)j * 4 + hh] : 0.f;
        uint4 v = *(const uint4*)(h1b + (size_t)s * HC1 + li * 8);
        acc[0] += p * bflo(v.x); acc[1] += p * bfhi(v.x);
        acc[2] += p * bflo(v.y); acc[3] += p * bfhi(v.y);
        acc[4] += p * bflo(v.z); acc[5] += p * bfhi(v.z);
        acc[6] += p * bflo(v.w); acc[7] += p * bfhi(v.w);
        S += p;
    }
    #pragma unroll
    for (int d = 16; d < 64; d <<= 1) {
        #pragma unroll
        for (int c = 0; c < 8; ++c) acc[c] += __shfl_xor(acc[c], d);
        S += __shfl_xor(S, d);
    }
    if (grp == 0) {
        float inv = 1.f / S;
        const float* bp = b1 + li * 8;
        float4 o0, o1;
        o0.x = lrelu(acc[0] * inv + bp[0]);
        o0.y = lrelu(acc[1] * inv + bp[1]);
        o0.z = lrelu(acc[2] * inv + bp[2]);
        o0.w = lrelu(acc[3] * inv + bp[3]);
        o1.x = lrelu(acc[4] * inv + bp[4]);
        o1.y = lrelu(acc[5] * inv + bp[5]);
        o1.z = lrelu(acc[6] * inv + bp[6]);
        o1.w = lrelu(acc[7] * inv + bp[7]);
        float* orow = h2out + (size_t)wid * HC1 + li * 8;
        *(float4*)orow = o0;
        *(float4*)(orow + 4) = o1;
    }
}

// layer 2: 1 wave per dst; p2 computed inline (ald2[wid] is wave-uniform;
// als2[e.x] is one broadcast 4B line per edge; exp on otherwise-idle VALU).
__global__ __launch_bounds__(256) void aggr2_kernel(const int* __restrict__ row_ptr,
                                                    const int2* __restrict__ epair,
                                                    const float* __restrict__ als2,
                                                    const float* __restrict__ ald2,
                                                    const float* __restrict__ g,
                                                    const float* __restrict__ b2,
                                                    float* __restrict__ out) {
    int wid = blockIdx.x * 4 + (threadIdx.x >> 6);
    int lane = threadIdx.x & 63;
    int grp = lane >> 4, li = lane & 15;
    int beg = row_ptr[wid], end = row_ptr[wid + 1];
    float ad = ald2[wid];
    float a0 = 0.f, a1 = 0.f, a2 = 0.f, a3 = 0.f, S = 0.f;
    for (int j0 = beg; j0 < end; j0 += 4) {
        int j = j0 + grp;
        bool valid = (j < end);
        int s = valid ? epair[j].x : 0;
        float p = valid ? __expf(lrelu(als2[s] + ad)) : 0.f;
        float4 gv = *(const float4*)(g + (size_t)s * F_OUT + li * 4);
        a0 += p * gv.x; a1 += p * gv.y; a2 += p * gv.z; a3 += p * gv.w;
        S += p;
    }
    #pragma unroll
    for (int d = 16; d < 64; d <<= 1) {
        a0 += __shfl_xor(a0, d); a1 += __shfl_xor(a1, d);
        a2 += __shfl_xor(a2, d); a3 += __shfl_xor(a3, d);
        S += __shfl_xor(S, d);
    }
    if (grp == 0) {
        float inv = 1.f / S;
        const float* bp = b2 + li * 4;
        float4 o;
        o.x = a0 * inv + bp[0];
        o.y = a1 * inv + bp[1];
        o.z = a2 * inv + bp[2];
        o.w = a3 * inv + bp[3];
        *(float4*)(out + (size_t)wid * F_OUT + li * 4) = o;
    }
}

// -------------------- launch --------------------------------------------------

extern "C" void kernel_launch(void* const* d_in, const int* in_sizes, int n_in,
                              void* d_out, int out_size, void* d_ws, size_t ws_size,
                              hipStream_t stream) {
    const float* x      = (const float*)d_in[0];
    const int*   ei     = (const int*)  d_in[1];
    const float* W1     = (const float*)d_in[2];
    const float* a_src1 = (const float*)d_in[3];
    const float* a_dst1 = (const float*)d_in[4];
    const float* b1     = (const float*)d_in[5];
    const float* W2     = (const float*)d_in[6];
    const float* a_src2 = (const float*)d_in[7];
    const float* a_dst2 = (const float*)d_in[8];
    const float* b2     = (const float*)d_in[9];
    float* out = (float*)d_out;
    char* ws = (char*)d_ws;

    // workspace layout (bytes)
    __bf16* h1b    = (__bf16*)(ws + 0);         // N*128*2 = 12,800,000
    float* h2      = (float*)(ws + 12800000);   // 25,600,000
    float* g       = (float*)(ws + 38400000);   // 12,800,000
    float* als1    = (float*)(ws + 51200000);   // 800,000
    float* ald1    = (float*)(ws + 52000000);   // 800,000
    float* als2    = (float*)(ws + 52800000);   // 200,000
    float* ald2    = (float*)(ws + 53000000);   // 200,000
    int*   rowp    = (int*)  (ws + 53200000);   // 200,004 (pad to 53,400,064)
    int*   bcur    = (int*)  (ws + 53400064);   // 784 (pad to 53,402,112)
    int2*  bstage  = (int2*) (ws + 53402112);   // NBKT*BMAX*8 = 9,633,792 -> 63,035,904
    int2*  epair   = (int2*) (ws + 63035904);   // (E+N)*8 = 5,200,000 -> 68,235,904
    __bf16* whi1   = (__bf16*)(ws + 68235904);  // 65,536
    __bf16* wlo1   = (__bf16*)(ws + 68301440);  // 65,536
    __bf16* whi2   = (__bf16*)(ws + 68366976);  // 16,384
    __bf16* wlo2   = (__bf16*)(ws + 68383360);  // 16,384 (end 68,399,744)
    // recycled regions:
    float* p1 = g;                // consumed by aggr1 before gemm2 writes g

    const int TOT = E_EDGES + N_NODES;

    init_kernel<<<1 + (NPACK + 255) / 256, 256, 0, stream>>>(
        W1, W2, whi1, wlo1, whi2, wlo2, bcur);

    gemm1_bappend_kernel<<<GB1 + NAB, 256, 0, stream>>>(
        x, whi1, wlo1, a_src1, a_dst1, h1b, als1, ald1, ei, bcur, bstage);

    bsortp1_kernel<<<NBKT, 1024, 0, stream>>>(bcur, bstage, als1, ald1, rowp, epair, p1);

    aggr1_kernel<<<N_NODES / 4, 256, 0, stream>>>(rowp, epair, p1, h1b, b1, h2);

    gemm_mfma_kernel<HC1, F_OUT, false, 1><<<(N_NODES + 63) / 64, 256, 0, stream>>>(
        h2, whi2, wlo2, a_src2, a_dst2, g, als2, ald2);

    aggr2_kernel<<<N_NODES / 4, 256, 0, stream>>>(rowp, epair, als2, ald2, g, b2, out);
}

// Round 21
// 138.660 us; speedup vs baseline: 4.0039x; 1.0761x over previous
//
#include <hip/hip_runtime.h>
#include <hip/hip_bf16.h>

#define N_NODES 50000
#define E_EDGES 600000
#define F_IN    256
#define HC1     128   // 4 heads * 32
#define F_OUT   64
#define NBKT    196   // ceil(N_NODES/256) coarse dst-buckets
#define BMAX    6144  // per-bucket capacity (mean 3316, sigma ~58)
#define APB     8192  // edges per bappend chunk
#define NAB     80    // ceil((E+N)/APB)
#define GB1     1563  // gemm1 tile blocks = ceil(N/32)
#define NPACK   (F_IN * HC1 + HC1 * F_OUT)   // 40960

typedef __bf16 bf16x8 __attribute__((ext_vector_type(8)));
typedef __bf16 bf16x4 __attribute__((ext_vector_type(4)));
typedef float  f32x4  __attribute__((ext_vector_type(4)));

__device__ __forceinline__ float lrelu(float x) { return x > 0.f ? x : 0.2f * x; }
__device__ __forceinline__ float bfhi(unsigned v) { return __uint_as_float(v & 0xffff0000u); }
__device__ __forceinline__ float bflo(unsigned v) { return __uint_as_float(v << 16); }

// -------------------- init: zero bucket cursors + pack W (fused) --------------

__global__ __launch_bounds__(256) void init_kernel(const float* __restrict__ W1,
                                                   const float* __restrict__ W2,
                                                   __bf16* __restrict__ hi1, __bf16* __restrict__ lo1,
                                                   __bf16* __restrict__ hi2, __bf16* __restrict__ lo2,
                                                   int* __restrict__ bcur) {
    if (blockIdx.x == 0) {
        if (threadIdx.x < NBKT) bcur[threadIdx.x] = 0;
        return;
    }
    int tid = (blockIdx.x - 1) * 256 + threadIdx.x;
    if (tid >= NPACK) return;
    if (tid < F_IN * HC1) {
        int t = tid;
        int j = t & 7, l = (t >> 3) & 63, kt = (t >> 9) & 7, ct = t >> 12;
        int k = kt * 32 + (l >> 4) * 8 + j;
        int col = ct * 16 + (l & 15);
        float v = W1[k * HC1 + col];
        __bf16 h = (__bf16)v;
        hi1[t] = h;
        lo1[t] = (__bf16)(v - (float)h);
    } else {
        int t = tid - F_IN * HC1;
        int j = t & 7, l = (t >> 3) & 63, kt = (t >> 9) & 3, ct = t >> 11;
        int k = kt * 32 + (l >> 4) * 8 + j;
        int col = ct * 16 + (l & 15);
        float v = W2[k * F_OUT + col];
        __bf16 h = (__bf16)v;
        hi2[t] = h;
        lo2[t] = (__bf16)(v - (float)h);
    }
}

// -------------------- fused gemm1 + bappend -----------------------------------
// Blocks [0,NAB): CSR bucket-append chunks -- placed at the FRONT of the grid
// so they are co-resident with the first gemm wave (R20 had them at the tail,
// where they serialized after gemm and cost ~20us). Blocks [NAB,NAB+GB1):
// 32-row gemm1 tiles (proven structure: LDS-staged bf16 hi/lo A, B
// reg-double-buffered, fused al epilogue).

__global__ __launch_bounds__(256) void gemm1_bappend_kernel(
        const float* __restrict__ A,
        const __bf16* __restrict__ Whi, const __bf16* __restrict__ Wlo,
        const float* __restrict__ a_s, const float* __restrict__ a_d,
        __bf16* __restrict__ Cout, float* __restrict__ als, float* __restrict__ ald,
        const int* __restrict__ ei, int* __restrict__ bcur, int2* __restrict__ bstage) {
    __shared__ __bf16 ah[32][F_IN + 8];
    __shared__ __bf16 al[32][F_IN + 8];
    __shared__ int lcnt[NBKT];
    int tid = threadIdx.x;

    if (blockIdx.x < NAB) {
        // ---------------- bappend chunk (front of grid: co-resident w/ gemm) ----
        const int TOT = E_EDGES + N_NODES;
        int bb = (int)blockIdx.x;
        int e0 = bb * APB;
        int e1 = e0 + APB < TOT ? e0 + APB : TOT;
        if (tid < NBKT) lcnt[tid] = 0;
        __syncthreads();
        for (int i = e0 + tid; i < e1; i += 256) {
            int d = (i < E_EDGES) ? ei[E_EDGES + i] : (i - E_EDGES);
            atomicAdd(&lcnt[d >> 8], 1);
        }
        __syncthreads();
        if (tid < NBKT) {
            int c = lcnt[tid];
            lcnt[tid] = c ? atomicAdd(&bcur[tid], c) : 0;
        }
        __syncthreads();
        for (int i = e0 + tid; i < e1; i += 256) {
            int s, d;
            if (i < E_EDGES) { s = ei[i]; d = ei[E_EDGES + i]; }
            else             { s = d = i - E_EDGES; }
            int b = d >> 8;
            int pos = atomicAdd(&lcnt[b], 1);
            bstage[(size_t)b * BMAX + pos] = make_int2(s, d);
        }
        return;
    }

    // ---------------- gemm1 tile (KDIM=256, NC=128, CGROUPS=2) ----------------
    constexpr int KT = 8, CTW = 4, F4PR = 64;
    int tb = (int)blockIdx.x - NAB;
    #pragma unroll
    for (int it = 0; it < 8; ++it) {
        int idx = it * 256 + tid;
        int row = idx / F4PR;
        int kk  = (idx - row * F4PR) * 4;
        int grow = tb * 32 + row;
        const float* src = A + (size_t)(grow < N_NODES ? grow : N_NODES - 1) * F_IN + kk;
        float4 v = *(const float4*)src;
        bf16x4 h, lo;
        h[0] = (__bf16)v.x; h[1] = (__bf16)v.y; h[2] = (__bf16)v.z; h[3] = (__bf16)v.w;
        lo[0] = (__bf16)(v.x - (float)h[0]);
        lo[1] = (__bf16)(v.y - (float)h[1]);
        lo[2] = (__bf16)(v.z - (float)h[2]);
        lo[3] = (__bf16)(v.w - (float)h[3]);
        *(bf16x4*)&ah[row][kk] = h;
        *(bf16x4*)&al[row][kk] = lo;
    }
    __syncthreads();

    int w = tid >> 6, l = tid & 63;
    int rw = w & 1, cg = w >> 1;
    int c0 = cg * CTW;
    int r0 = tb * 32 + rw * 16;
    int rowL = rw * 16 + (l & 15);
    int koff = (l >> 4) * 8;

    bf16x8 bh[2][CTW], bl[2][CTW];
    #pragma unroll
    for (int c = 0; c < CTW; ++c) {
        size_t bidx = ((size_t)((c0 + c) * KT + 0) * 64 + l) * 8;
        bh[0][c] = *(const bf16x8*)(Whi + bidx);
        bl[0][c] = *(const bf16x8*)(Wlo + bidx);
    }

    f32x4 acc[CTW];
    #pragma unroll
    for (int c = 0; c < CTW; ++c) acc[c] = (f32x4){0.f, 0.f, 0.f, 0.f};

    #pragma unroll
    for (int kt = 0; kt < KT; ++kt) {
        const int cur = kt & 1, nxt = cur ^ 1;
        if (kt + 1 < KT) {
            #pragma unroll
            for (int c = 0; c < CTW; ++c) {
                size_t bidx = ((size_t)((c0 + c) * KT + (kt + 1)) * 64 + l) * 8;
                bh[nxt][c] = *(const bf16x8*)(Whi + bidx);
                bl[nxt][c] = *(const bf16x8*)(Wlo + bidx);
            }
        }
        bf16x8 ahi = *(const bf16x8*)&ah[rowL][kt * 32 + koff];
        bf16x8 alo = *(const bf16x8*)&al[rowL][kt * 32 + koff];
        #pragma unroll
        for (int c = 0; c < CTW; ++c) {
            acc[c] = __builtin_amdgcn_mfma_f32_16x16x32_bf16(ahi, bh[cur][c], acc[c], 0, 0, 0);
            acc[c] = __builtin_amdgcn_mfma_f32_16x16x32_bf16(ahi, bl[cur][c], acc[c], 0, 0, 0);
            acc[c] = __builtin_amdgcn_mfma_f32_16x16x32_bf16(alo, bh[cur][c], acc[c], 0, 0, 0);
        }
    }

    int crow0 = r0 + (l >> 4) * 4;
    int ccol = l & 15;

    #pragma unroll
    for (int c = 0; c < CTW; ++c) {
        #pragma unroll
        for (int r = 0; r < 4; ++r) {
            int row = crow0 + r;
            if (row < N_NODES)
                Cout[(size_t)row * HC1 + (c0 + c) * 16 + ccol] = (__bf16)acc[c][r];
        }
    }

    float as_c[CTW], ad_c[CTW];
    #pragma unroll
    for (int c = 0; c < CTW; ++c) {
        as_c[c] = a_s[(c0 + c) * 16 + ccol];
        ad_c[c] = a_d[(c0 + c) * 16 + ccol];
    }

    #pragma unroll
    for (int r = 0; r < 4; ++r) {
        int row = crow0 + r;
        #pragma unroll
        for (int hl = 0; hl < 2; ++hl) {
            int h = cg * 2 + hl;
            float vs = acc[2 * hl][r] * as_c[2 * hl] + acc[2 * hl + 1][r] * as_c[2 * hl + 1];
            float vd = acc[2 * hl][r] * ad_c[2 * hl] + acc[2 * hl + 1][r] * ad_c[2 * hl + 1];
            #pragma unroll
            for (int d = 1; d < 16; d <<= 1) {
                vs += __shfl_xor(vs, d);
                vd += __shfl_xor(vd, d);
            }
            if (ccol == 0 && row < N_NODES) { als[row * 4 + h] = vs; ald[row * 4 + h] = vd; }
        }
    }
}

// -------------------- bsort + fused p1 ----------------------------------------

__global__ __launch_bounds__(1024) void bsortp1_kernel(const int* __restrict__ bcur,
                                                       const int2* __restrict__ bstage,
                                                       const float* __restrict__ als1,
                                                       const float* __restrict__ ald1,
                                                       int* __restrict__ rowp,
                                                       int2* __restrict__ epair,
                                                       float* __restrict__ p1) {
    __shared__ int cnt[256], cur[256], ws4[4];
    __shared__ int bbase_s;
    __shared__ int2 sorted[BMAX];
    int b = blockIdx.x, tid = threadIdx.x;
    int nb = bcur[b]; if (nb > BMAX) nb = BMAX;
    int d0 = b << 8;

    if (tid < 256) {
        int lane = tid & 63, w = tid >> 6;
        int v = (tid < NBKT) ? bcur[tid] : 0;
        int s = v;
        #pragma unroll
        for (int d = 1; d < 64; d <<= 1) {
            int t = __shfl_up(s, d);
            if (lane >= d) s += t;
        }
        if (lane == 63) ws4[w] = s;
        __syncthreads();
        if (tid == 0) {
            int r = 0;
            #pragma unroll
            for (int q = 0; q < 4; ++q) { int t = ws4[q]; ws4[q] = r; r += t; }
        }
        __syncthreads();
        if (tid == b) bbase_s = ws4[w] + s - v;
        if (b == 0 && tid == 0) rowp[N_NODES] = E_EDGES + N_NODES;
    } else {
        __syncthreads();
        __syncthreads();
    }
    if (tid < 256) cnt[tid] = 0;
    __syncthreads();
    int base = bbase_s;

    const int2* bs = bstage + (size_t)b * BMAX;
    for (int e = tid; e < nb; e += 1024)
        atomicAdd(&cnt[bs[e].y - d0], 1);
    __syncthreads();
    int v = 0, s = 0;
    if (tid < 256) {
        int lane = tid & 63, w = tid >> 6;
        v = cnt[tid];
        s = v;
        #pragma unroll
        for (int d = 1; d < 64; d <<= 1) {
            int t = __shfl_up(s, d);
            if (lane >= d) s += t;
        }
        if (lane == 63) ws4[w] = s;
    }
    __syncthreads();
    if (tid == 0) {
        int r = 0;
        #pragma unroll
        for (int q = 0; q < 4; ++q) { int t = ws4[q]; ws4[q] = r; r += t; }
    }
    __syncthreads();
    if (tid < 256) {
        int excl = ws4[tid >> 6] + s - v;
        cur[tid] = excl;
        int d = d0 + tid;
        if (d < N_NODES) rowp[d] = base + excl;
    }
    __syncthreads();
    for (int e = tid; e < nb; e += 1024) {
        int2 ed = bs[e];
        int p = atomicAdd(&cur[ed.y - d0], 1);
        sorted[p] = ed;
    }
    __syncthreads();
    for (int e = tid; e < nb; e += 1024) {
        int2 ed = sorted[e];
        epair[base + e] = ed;
        float4 as = *(const float4*)&als1[ed.x * 4];
        float4 ad = *(const float4*)&ald1[ed.y * 4];
        float4 p;
        p.x = __expf(lrelu(as.x + ad.x));
        p.y = __expf(lrelu(as.y + ad.y));
        p.z = __expf(lrelu(as.z + ad.z));
        p.w = __expf(lrelu(as.w + ad.w));
        *(float4*)&p1[(size_t)(base + e) * 4] = p;
    }
}

// -------------------- generic gemm (used for layer 2) -------------------------

template<int KDIM, int NC, bool CBF16, int CGROUPS>
__global__ __launch_bounds__(256) void gemm_mfma_kernel(const float* __restrict__ A,
                                                        const __bf16* __restrict__ Whi,
                                                        const __bf16* __restrict__ Wlo,
                                                        const float* __restrict__ a_s,
                                                        const float* __restrict__ a_d,
                                                        void* __restrict__ Cout,
                                                        float* __restrict__ als,
                                                        float* __restrict__ ald) {
    constexpr int KT   = KDIM / 32;
    constexpr int CT   = NC / 16;
    constexpr int CTW  = CT / CGROUPS;
    constexpr int RPB  = (CGROUPS == 2) ? 32 : 64;
    constexpr int LSTR = KDIM + 8;
    constexpr int F4PR = KDIM / 4;
    __shared__ __bf16 ah[RPB][LSTR];
    __shared__ __bf16 al[RPB][LSTR];

    int tid = threadIdx.x;

    #pragma unroll
    for (int it = 0; it < (RPB * F4PR) / 256; ++it) {
        int idx = it * 256 + tid;
        int row = idx / F4PR;
        int kk  = (idx - row * F4PR) * 4;
        int grow = blockIdx.x * RPB + row;
        const float* src = A + (size_t)(grow < N_NODES ? grow : N_NODES - 1) * KDIM + kk;
        float4 v = *(const float4*)src;
        bf16x4 h, lo;
        h[0] = (__bf16)v.x; h[1] = (__bf16)v.y; h[2] = (__bf16)v.z; h[3] = (__bf16)v.w;
        lo[0] = (__bf16)(v.x - (float)h[0]);
        lo[1] = (__bf16)(v.y - (float)h[1]);
        lo[2] = (__bf16)(v.z - (float)h[2]);
        lo[3] = (__bf16)(v.w - (float)h[3]);
        *(bf16x4*)&ah[row][kk] = h;
        *(bf16x4*)&al[row][kk] = lo;
    }
    __syncthreads();

    int w = tid >> 6, l = tid & 63;
    int rw = (CGROUPS == 2) ? (w & 1) : w;
    int cg = (CGROUPS == 2) ? (w >> 1) : 0;
    int c0 = cg * CTW;
    int r0 = blockIdx.x * RPB + rw * 16;
    int rowL = rw * 16 + (l & 15);
    int koff = (l >> 4) * 8;

    bf16x8 bh[2][CTW], bl[2][CTW];
    #pragma unroll
    for (int c = 0; c < CTW; ++c) {
        size_t bidx = ((size_t)((c0 + c) * KT + 0) * 64 + l) * 8;
        bh[0][c] = *(const bf16x8*)(Whi + bidx);
        bl[0][c] = *(const bf16x8*)(Wlo + bidx);
    }

    f32x4 acc[CTW];
    #pragma unroll
    for (int c = 0; c < CTW; ++c) acc[c] = (f32x4){0.f, 0.f, 0.f, 0.f};

    #pragma unroll
    for (int kt = 0; kt < KT; ++kt) {
        const int cur = kt & 1, nxt = cur ^ 1;
        if (kt + 1 < KT) {
            #pragma unroll
            for (int c = 0; c < CTW; ++c) {
                size_t bidx = ((size_t)((c0 + c) * KT + (kt + 1)) * 64 + l) * 8;
                bh[nxt][c] = *(const bf16x8*)(Whi + bidx);
                bl[nxt][c] = *(const bf16x8*)(Wlo + bidx);
            }
        }
        bf16x8 ahi = *(const bf16x8*)&ah[rowL][kt * 32 + koff];
        bf16x8 alo = *(const bf16x8*)&al[rowL][kt * 32 + koff];
        #pragma unroll
        for (int c = 0; c < CTW; ++c) {
            acc[c] = __builtin_amdgcn_mfma_f32_16x16x32_bf16(ahi, bh[cur][c], acc[c], 0, 0, 0);
            acc[c] = __builtin_amdgcn_mfma_f32_16x16x32_bf16(ahi, bl[cur][c], acc[c], 0, 0, 0);
            acc[c] = __builtin_amdgcn_mfma_f32_16x16x32_bf16(alo, bh[cur][c], acc[c], 0, 0, 0);
        }
    }

    int crow0 = r0 + (l >> 4) * 4;
    int ccol = l & 15;

    #pragma unroll
    for (int c = 0; c < CTW; ++c) {
        #pragma unroll
        for (int r = 0; r < 4; ++r) {
            int row = crow0 + r;
            if (row < N_NODES) {
                if constexpr (CBF16)
                    ((__bf16*)Cout)[(size_t)row * NC + (c0 + c) * 16 + ccol] = (__bf16)acc[c][r];
                else
                    ((float*)Cout)[(size_t)row * NC + (c0 + c) * 16 + ccol] = acc[c][r];
            }
        }
    }

    float as_c[CTW], ad_c[CTW];
    #pragma unroll
    for (int c = 0; c < CTW; ++c) {
        as_c[c] = a_s[(c0 + c) * 16 + ccol];
        ad_c[c] = a_d[(c0 + c) * 16 + ccol];
    }

    #pragma unroll
    for (int r = 0; r < 4; ++r) {
        int row = crow0 + r;
        if constexpr (NC == 128) {
            #pragma unroll
            for (int hl = 0; hl < 2; ++hl) {
                int h = cg * 2 + hl;
                float vs = acc[2 * hl][r] * as_c[2 * hl] + acc[2 * hl + 1][r] * as_c[2 * hl + 1];
                float vd = acc[2 * hl][r] * ad_c[2 * hl] + acc[2 * hl + 1][r] * ad_c[2 * hl + 1];
                #pragma unroll
                for (int d = 1; d < 16; d <<= 1) {
                    vs += __shfl_xor(vs, d);
                    vd += __shfl_xor(vd, d);
                }
                if (ccol == 0 && row < N_NODES) { als[row * 4 + h] = vs; ald[row * 4 + h] = vd; }
            }
        } else {
            float vs = 0.f, vd = 0.f;
            #pragma unroll
            for (int c = 0; c < CTW; ++c) { vs += acc[c][r] * as_c[c]; vd += acc[c][r] * ad_c[c]; }
            #pragma unroll
            for (int d = 1; d < 16; d <<= 1) {
                vs += __shfl_xor(vs, d);
                vd += __shfl_xor(vd, d);
            }
            if (ccol == 0 && row < N_NODES) { als[row] = vs; ald[row] = vd; }
        }
    }
}

// -------------------- aggregation ---------------------------------------------

__global__ __launch_bounds__(256) void aggr1_kernel(const int* __restrict__ row_ptr,
                                                    const int2* __restrict__ epair,
                                                    const float* __restrict__ p1,
                                                    const __bf16* __restrict__ h1b,
                                                    const float* __restrict__ b1,
                                                    float* __restrict__ h2out) {
    int wid = blockIdx.x * 4 + (threadIdx.x >> 6);
    int lane = threadIdx.x & 63;
    int grp = lane >> 4, li = lane & 15;
    int hh = li >> 2;
    int beg = row_ptr[wid], end = row_ptr[wid + 1];
    float acc[8] = {0,0,0,0,0,0,0,0};
    float S = 0.f;
    for (int j0 = beg; j0 < end; j0 += 4) {
        int j = j0 + grp;
        bool valid = (j < end);
        int s = valid ? epair[j].x : 0;
        float p = valid ? p1[(size_t)j * 4 + hh] : 0.f;
        uint4 v = *(const uint4*)(h1b + (size_t)s * HC1 + li * 8);
        acc[0] += p * bflo(v.x); acc[1] += p * bfhi(v.x);
        acc[2] += p * bflo(v.y); acc[3] += p * bfhi(v.y);
        acc[4] += p * bflo(v.z); acc[5] += p * bfhi(v.z);
        acc[6] += p * bflo(v.w); acc[7] += p * bfhi(v.w);
        S += p;
    }
    #pragma unroll
    for (int d = 16; d < 64; d <<= 1) {
        #pragma unroll
        for (int c = 0; c < 8; ++c) acc[c] += __shfl_xor(acc[c], d);
        S += __shfl_xor(S, d);
    }
    if (grp == 0) {
        float inv = 1.f / S;
        const float* bp = b1 + li * 8;
        float4 o0, o1;
        o0.x = lrelu(acc[0] * inv + bp[0]);
        o0.y = lrelu(acc[1] * inv + bp[1]);
        o0.z = lrelu(acc[2] * inv + bp[2]);
        o0.w = lrelu(acc[3] * inv + bp[3]);
        o1.x = lrelu(acc[4] * inv + bp[4]);
        o1.y = lrelu(acc[5] * inv + bp[5]);
        o1.z = lrelu(acc[6] * inv + bp[6]);
        o1.w = lrelu(acc[7] * inv + bp[7]);
        float* orow = h2out + (size_t)wid * HC1 + li * 8;
        *(float4*)orow = o0;
        *(float4*)(orow + 4) = o1;
    }
}

__global__ __launch_bounds__(256) void aggr2_kernel(const int* __restrict__ row_ptr,
                                                    const int2* __restrict__ epair,
                                                    const float* __restrict__ als2,
                                                    const float* __restrict__ ald2,
                                                    const float* __restrict__ g,
                                                    const float* __restrict__ b2,
                                                    float* __restrict__ out) {
    int wid = blockIdx.x * 4 + (threadIdx.x >> 6);
    int lane = threadIdx.x & 63;
    int grp = lane >> 4, li = lane & 15;
    int beg = row_ptr[wid], end = row_ptr[wid + 1];
    float ad = ald2[wid];
    float a0 = 0.f, a1 = 0.f, a2 = 0.f, a3 = 0.f, S = 0.f;
    for (int j0 = beg; j0 < end; j0 += 4) {
        int j = j0 + grp;
        bool valid = (j < end);
        int s = valid ? epair[j].x : 0;
        float p = valid ? __expf(lrelu(als2[s] + ad)) : 0.f;
        float4 gv = *(const float4*)(g + (size_t)s * F_OUT + li * 4);
        a0 += p * gv.x; a1 += p * gv.y; a2 += p * gv.z; a3 += p * gv.w;
        S += p;
    }
    #pragma unroll
    for (int d = 16; d < 64; d <<= 1) {
        a0 += __shfl_xor(a0, d); a1 += __shfl_xor(a1, d);
        a2 += __shfl_xor(a2, d); a3 += __shfl_xor(a3, d);
        S += __shfl_xor(S, d);
    }
    if (grp == 0) {
        float inv = 1.f / S;
        const float* bp = b2 + li * 4;
        float4 o;
        o.x = a0 * inv + bp[0];
        o.y = a1 * inv + bp[1];
        o.z = a2 * inv + bp[2];
        o.w = a3 * inv + bp[3];
        *(float4*)(out + (size_t)wid * F_OUT + li * 4) = o;
    }
}

// -------------------- launch --------------------------------------------------

extern "C" void kernel_launch(void* const* d_in, const int* in_sizes, int n_in,
                              void* d_out, int out_size, void* d_ws, size_t ws_size,
                              hipStream_t stream) {
    const float* x      = (const float*)d_in[0];
    const int*   ei     = (const int*)  d_in[1];
    const float* W1     = (const float*)d_in[2];
    const float* a_src1 = (const float*)d_in[3];
    const float* a_dst1 = (const float*)d_in[4];
    const float* b1     = (const float*)d_in[5];
    const float* W2     = (const float*)d_in[6];
    const float* a_src2 = (const float*)d_in[7];
    const float* a_dst2 = (const float*)d_in[8];
    const float* b2     = (const float*)d_in[9];
    float* out = (float*)d_out;
    char* ws = (char*)d_ws;

    // workspace layout (bytes)
    __bf16* h1b    = (__bf16*)(ws + 0);         // N*128*2 = 12,800,000
    float* h2      = (float*)(ws + 12800000);   // 25,600,000
    float* g       = (float*)(ws + 38400000);   // 12,800,000
    float* als1    = (float*)(ws + 51200000);   // 800,000
    float* ald1    = (float*)(ws + 52000000);   // 800,000
    float* als2    = (float*)(ws + 52800000);   // 200,000
    float* ald2    = (float*)(ws + 53000000);   // 200,000
    int*   rowp    = (int*)  (ws + 53200000);   // 200,004 (pad to 53,400,064)
    int*   bcur    = (int*)  (ws + 53400064);   // 784 (pad to 53,402,112)
    int2*  bstage  = (int2*) (ws + 53402112);   // NBKT*BMAX*8 = 9,633,792 -> 63,035,904
    int2*  epair   = (int2*) (ws + 63035904);   // (E+N)*8 = 5,200,000 -> 68,235,904
    __bf16* whi1   = (__bf16*)(ws + 68235904);  // 65,536
    __bf16* wlo1   = (__bf16*)(ws + 68301440);  // 65,536
    __bf16* whi2   = (__bf16*)(ws + 68366976);  // 16,384
    __bf16* wlo2   = (__bf16*)(ws + 68383360);  // 16,384 (end 68,399,744)
    // recycled regions:
    float* p1 = g;                // consumed by aggr1 before gemm2 writes g

    init_kernel<<<1 + (NPACK + 255) / 256, 256, 0, stream>>>(
        W1, W2, whi1, wlo1, whi2, wlo2, bcur);

    gemm1_bappend_kernel<<<NAB + GB1, 256, 0, stream>>>(
        x, whi1, wlo1, a_src1, a_dst1, h1b, als1, ald1, ei, bcur, bstage);

    bsortp1_kernel<<<NBKT, 1024, 0, stream>>>(bcur, bstage, als1, ald1, rowp, epair, p1);

    aggr1_kernel<<<N_NODES / 4, 256, 0, stream>>>(rowp, epair, p1, h1b, b1, h2);

    gemm_mfma_kernel<HC1, F_OUT, false, 1><<<(N_NODES + 63) / 64, 256, 0, stream>>>(
        h2, whi2, wlo2, a_src2, a_dst2, g, als2, ald2);

    aggr2_kernel<<<N_NODES / 4, 256, 0, stream>>>(rowp, epair, als2, ald2, g, b2, out);
}

// Round 22
// 137.878 us; speedup vs baseline: 4.0265x; 1.0057x over previous
//
#include <hip/hip_runtime.h>
#include <hip/hip_bf16.h>

#define N_NODES 50000
#define E_EDGES 600000
#define F_IN    256
#define HC1     128   // 4 heads * 32
#define F_OUT   64
#define NBKT    196   // ceil(N_NODES/256) coarse dst-buckets
#define BMAX    6144  // per-bucket capacity (mean 3316, sigma ~58)
#define APB     8192  // edges per bappend chunk
#define NAB     80    // ceil((E+N)/APB)
#define GB1     1563  // gemm1 tile blocks = ceil(N/32)
#define NPACK   (F_IN * HC1 + HC1 * F_OUT)   // 40960

typedef __bf16 bf16x8 __attribute__((ext_vector_type(8)));
typedef __bf16 bf16x4 __attribute__((ext_vector_type(4)));
typedef float  f32x4  __attribute__((ext_vector_type(4)));

__device__ __forceinline__ float lrelu(float x) { return x > 0.f ? x : 0.2f * x; }
__device__ __forceinline__ float bfhi(unsigned v) { return __uint_as_float(v & 0xffff0000u); }
__device__ __forceinline__ float bflo(unsigned v) { return __uint_as_float(v << 16); }

// -------------------- init: zero bucket cursors + pack W (fused) --------------

__global__ __launch_bounds__(256) void init_kernel(const float* __restrict__ W1,
                                                   const float* __restrict__ W2,
                                                   __bf16* __restrict__ hi1, __bf16* __restrict__ lo1,
                                                   __bf16* __restrict__ hi2, __bf16* __restrict__ lo2,
                                                   int* __restrict__ bcur) {
    if (blockIdx.x == 0) {
        if (threadIdx.x < NBKT) bcur[threadIdx.x] = 0;
        return;
    }
    int tid = (blockIdx.x - 1) * 256 + threadIdx.x;
    if (tid >= NPACK) return;
    if (tid < F_IN * HC1) {
        int t = tid;
        int j = t & 7, l = (t >> 3) & 63, kt = (t >> 9) & 7, ct = t >> 12;
        int k = kt * 32 + (l >> 4) * 8 + j;
        int col = ct * 16 + (l & 15);
        float v = W1[k * HC1 + col];
        __bf16 h = (__bf16)v;
        hi1[t] = h;
        lo1[t] = (__bf16)(v - (float)h);
    } else {
        int t = tid - F_IN * HC1;
        int j = t & 7, l = (t >> 3) & 63, kt = (t >> 9) & 3, ct = t >> 11;
        int k = kt * 32 + (l >> 4) * 8 + j;
        int col = ct * 16 + (l & 15);
        float v = W2[k * F_OUT + col];
        __bf16 h = (__bf16)v;
        hi2[t] = h;
        lo2[t] = (__bf16)(v - (float)h);
    }
}

// -------------------- fused gemm1 + bappend (bappend at grid front) -----------

__global__ __launch_bounds__(256) void gemm1_bappend_kernel(
        const float* __restrict__ A,
        const __bf16* __restrict__ Whi, const __bf16* __restrict__ Wlo,
        const float* __restrict__ a_s, const float* __restrict__ a_d,
        __bf16* __restrict__ Cout, float* __restrict__ als, float* __restrict__ ald,
        const int* __restrict__ ei, int* __restrict__ bcur, int2* __restrict__ bstage) {
    __shared__ __bf16 ah[32][F_IN + 8];
    __shared__ __bf16 al[32][F_IN + 8];
    __shared__ int lcnt[NBKT];
    int tid = threadIdx.x;

    if (blockIdx.x < NAB) {
        const int TOT = E_EDGES + N_NODES;
        int bb = (int)blockIdx.x;
        int e0 = bb * APB;
        int e1 = e0 + APB < TOT ? e0 + APB : TOT;
        if (tid < NBKT) lcnt[tid] = 0;
        __syncthreads();
        for (int i = e0 + tid; i < e1; i += 256) {
            int d = (i < E_EDGES) ? ei[E_EDGES + i] : (i - E_EDGES);
            atomicAdd(&lcnt[d >> 8], 1);
        }
        __syncthreads();
        if (tid < NBKT) {
            int c = lcnt[tid];
            lcnt[tid] = c ? atomicAdd(&bcur[tid], c) : 0;
        }
        __syncthreads();
        for (int i = e0 + tid; i < e1; i += 256) {
            int s, d;
            if (i < E_EDGES) { s = ei[i]; d = ei[E_EDGES + i]; }
            else             { s = d = i - E_EDGES; }
            int b = d >> 8;
            int pos = atomicAdd(&lcnt[b], 1);
            bstage[(size_t)b * BMAX + pos] = make_int2(s, d);
        }
        return;
    }

    // gemm1 tile (KDIM=256, NC=128, CGROUPS=2)
    constexpr int KT = 8, CTW = 4, F4PR = 64;
    int tb = (int)blockIdx.x - NAB;
    #pragma unroll
    for (int it = 0; it < 8; ++it) {
        int idx = it * 256 + tid;
        int row = idx / F4PR;
        int kk  = (idx - row * F4PR) * 4;
        int grow = tb * 32 + row;
        const float* src = A + (size_t)(grow < N_NODES ? grow : N_NODES - 1) * F_IN + kk;
        float4 v = *(const float4*)src;
        bf16x4 h, lo;
        h[0] = (__bf16)v.x; h[1] = (__bf16)v.y; h[2] = (__bf16)v.z; h[3] = (__bf16)v.w;
        lo[0] = (__bf16)(v.x - (float)h[0]);
        lo[1] = (__bf16)(v.y - (float)h[1]);
        lo[2] = (__bf16)(v.z - (float)h[2]);
        lo[3] = (__bf16)(v.w - (float)h[3]);
        *(bf16x4*)&ah[row][kk] = h;
        *(bf16x4*)&al[row][kk] = lo;
    }
    __syncthreads();

    int w = tid >> 6, l = tid & 63;
    int rw = w & 1, cg = w >> 1;
    int c0 = cg * CTW;
    int r0 = tb * 32 + rw * 16;
    int rowL = rw * 16 + (l & 15);
    int koff = (l >> 4) * 8;

    bf16x8 bh[2][CTW], bl[2][CTW];
    #pragma unroll
    for (int c = 0; c < CTW; ++c) {
        size_t bidx = ((size_t)((c0 + c) * KT + 0) * 64 + l) * 8;
        bh[0][c] = *(const bf16x8*)(Whi + bidx);
        bl[0][c] = *(const bf16x8*)(Wlo + bidx);
    }

    f32x4 acc[CTW];
    #pragma unroll
    for (int c = 0; c < CTW; ++c) acc[c] = (f32x4){0.f, 0.f, 0.f, 0.f};

    #pragma unroll
    for (int kt = 0; kt < KT; ++kt) {
        const int cur = kt & 1, nxt = cur ^ 1;
        if (kt + 1 < KT) {
            #pragma unroll
            for (int c = 0; c < CTW; ++c) {
                size_t bidx = ((size_t)((c0 + c) * KT + (kt + 1)) * 64 + l) * 8;
                bh[nxt][c] = *(const bf16x8*)(Whi + bidx);
                bl[nxt][c] = *(const bf16x8*)(Wlo + bidx);
            }
        }
        bf16x8 ahi = *(const bf16x8*)&ah[rowL][kt * 32 + koff];
        bf16x8 alo = *(const bf16x8*)&al[rowL][kt * 32 + koff];
        #pragma unroll
        for (int c = 0; c < CTW; ++c) {
            acc[c] = __builtin_amdgcn_mfma_f32_16x16x32_bf16(ahi, bh[cur][c], acc[c], 0, 0, 0);
            acc[c] = __builtin_amdgcn_mfma_f32_16x16x32_bf16(ahi, bl[cur][c], acc[c], 0, 0, 0);
            acc[c] = __builtin_amdgcn_mfma_f32_16x16x32_bf16(alo, bh[cur][c], acc[c], 0, 0, 0);
        }
    }

    int crow0 = r0 + (l >> 4) * 4;
    int ccol = l & 15;

    #pragma unroll
    for (int c = 0; c < CTW; ++c) {
        #pragma unroll
        for (int r = 0; r < 4; ++r) {
            int row = crow0 + r;
            if (row < N_NODES)
                Cout[(size_t)row * HC1 + (c0 + c) * 16 + ccol] = (__bf16)acc[c][r];
        }
    }

    float as_c[CTW], ad_c[CTW];
    #pragma unroll
    for (int c = 0; c < CTW; ++c) {
        as_c[c] = a_s[(c0 + c) * 16 + ccol];
        ad_c[c] = a_d[(c0 + c) * 16 + ccol];
    }

    #pragma unroll
    for (int r = 0; r < 4; ++r) {
        int row = crow0 + r;
        #pragma unroll
        for (int hl = 0; hl < 2; ++hl) {
            int h = cg * 2 + hl;
            float vs = acc[2 * hl][r] * as_c[2 * hl] + acc[2 * hl + 1][r] * as_c[2 * hl + 1];
            float vd = acc[2 * hl][r] * ad_c[2 * hl] + acc[2 * hl + 1][r] * ad_c[2 * hl + 1];
            #pragma unroll
            for (int d = 1; d < 16; d <<= 1) {
                vs += __shfl_xor(vs, d);
                vd += __shfl_xor(vd, d);
            }
            if (ccol == 0 && row < N_NODES) { als[row * 4 + h] = vs; ald[row * 4 + h] = vd; }
        }
    }
}

// -------------------- bsort + fused p1 ----------------------------------------

__global__ __launch_bounds__(1024) void bsortp1_kernel(const int* __restrict__ bcur,
                                                       const int2* __restrict__ bstage,
                                                       const float* __restrict__ als1,
                                                       const float* __restrict__ ald1,
                                                       int* __restrict__ rowp,
                                                       int2* __restrict__ epair,
                                                       float* __restrict__ p1) {
    __shared__ int cnt[256], cur[256], ws4[4];
    __shared__ int bbase_s;
    __shared__ int2 sorted[BMAX];
    int b = blockIdx.x, tid = threadIdx.x;
    int nb = bcur[b]; if (nb > BMAX) nb = BMAX;
    int d0 = b << 8;

    if (tid < 256) {
        int lane = tid & 63, w = tid >> 6;
        int v = (tid < NBKT) ? bcur[tid] : 0;
        int s = v;
        #pragma unroll
        for (int d = 1; d < 64; d <<= 1) {
            int t = __shfl_up(s, d);
            if (lane >= d) s += t;
        }
        if (lane == 63) ws4[w] = s;
        __syncthreads();
        if (tid == 0) {
            int r = 0;
            #pragma unroll
            for (int q = 0; q < 4; ++q) { int t = ws4[q]; ws4[q] = r; r += t; }
        }
        __syncthreads();
        if (tid == b) bbase_s = ws4[w] + s - v;
        if (b == 0 && tid == 0) rowp[N_NODES] = E_EDGES + N_NODES;
    } else {
        __syncthreads();
        __syncthreads();
    }
    if (tid < 256) cnt[tid] = 0;
    __syncthreads();
    int base = bbase_s;

    const int2* bs = bstage + (size_t)b * BMAX;
    for (int e = tid; e < nb; e += 1024)
        atomicAdd(&cnt[bs[e].y - d0], 1);
    __syncthreads();
    int v = 0, s = 0;
    if (tid < 256) {
        int lane = tid & 63, w = tid >> 6;
        v = cnt[tid];
        s = v;
        #pragma unroll
        for (int d = 1; d < 64; d <<= 1) {
            int t = __shfl_up(s, d);
            if (lane >= d) s += t;
        }
        if (lane == 63) ws4[w] = s;
    }
    __syncthreads();
    if (tid == 0) {
        int r = 0;
        #pragma unroll
        for (int q = 0; q < 4; ++q) { int t = ws4[q]; ws4[q] = r; r += t; }
    }
    __syncthreads();
    if (tid < 256) {
        int excl = ws4[tid >> 6] + s - v;
        cur[tid] = excl;
        int d = d0 + tid;
        if (d < N_NODES) rowp[d] = base + excl;
    }
    __syncthreads();
    for (int e = tid; e < nb; e += 1024) {
        int2 ed = bs[e];
        int p = atomicAdd(&cur[ed.y - d0], 1);
        sorted[p] = ed;
    }
    __syncthreads();
    for (int e = tid; e < nb; e += 1024) {
        int2 ed = sorted[e];
        epair[base + e] = ed;
        float4 as = *(const float4*)&als1[ed.x * 4];
        float4 ad = *(const float4*)&ald1[ed.y * 4];
        float4 p;
        p.x = __expf(lrelu(as.x + ad.x));
        p.y = __expf(lrelu(as.y + ad.y));
        p.z = __expf(lrelu(as.z + ad.z));
        p.w = __expf(lrelu(as.w + ad.w));
        *(float4*)&p1[(size_t)(base + e) * 4] = p;
    }
}

// -------------------- fused aggr1 + gemm2 -------------------------------------
// 1024 threads = 16 waves = 16 dsts (3125 blocks x 16 = 50000 exact). Each
// wave aggregates its dst row and deposits h2 (bf16 hi/lo, numerically same
// as the old fp32-store-then-split) into LDS. Then waves 0-3 each compute one
// 16-col tile of g = h2s @ W2 via the 3-MFMA split (B from packed whi2/wlo2,
// L2-hot), write g coalesced, and stage partial als2/ald2 reduced at the end.
// Kills the gemm2 kernel + 51MB of h2 global traffic; MFMA work hides under
// the gather-bound aggregation of neighboring waves.

__global__ __launch_bounds__(1024) void aggr1g_kernel(
        const int* __restrict__ rowp, const int2* __restrict__ epair,
        const float* __restrict__ p1, const __bf16* __restrict__ h1b,
        const float* __restrict__ b1,
        const __bf16* __restrict__ whi2, const __bf16* __restrict__ wlo2,
        const float* __restrict__ a_src2, const float* __restrict__ a_dst2,
        float* __restrict__ g, float* __restrict__ als2, float* __restrict__ ald2) {
    __shared__ __bf16 h2h[16][HC1 + 8];
    __shared__ __bf16 h2l[16][HC1 + 8];
    __shared__ float alsp[4][16], aldp[4][16];
    int tid = threadIdx.x;
    int w = tid >> 6, l = tid & 63;
    int wid = blockIdx.x * 16 + w;
    int grp = l >> 4, li = l & 15;
    int hh = li >> 2;
    int beg = rowp[wid], end = rowp[wid + 1];

    // ---- aggregation (same structure as before) ----
    float acc[8] = {0,0,0,0,0,0,0,0};
    float S = 0.f;
    for (int j0 = beg; j0 < end; j0 += 4) {
        int j = j0 + grp;
        bool valid = (j < end);
        int s = valid ? epair[j].x : 0;
        float p = valid ? p1[(size_t)j * 4 + hh] : 0.f;
        uint4 v = *(const uint4*)(h1b + (size_t)s * HC1 + li * 8);
        acc[0] += p * bflo(v.x); acc[1] += p * bfhi(v.x);
        acc[2] += p * bflo(v.y); acc[3] += p * bfhi(v.y);
        acc[4] += p * bflo(v.z); acc[5] += p * bfhi(v.z);
        acc[6] += p * bflo(v.w); acc[7] += p * bfhi(v.w);
        S += p;
    }
    #pragma unroll
    for (int d = 16; d < 64; d <<= 1) {
        #pragma unroll
        for (int c = 0; c < 8; ++c) acc[c] += __shfl_xor(acc[c], d);
        S += __shfl_xor(S, d);
    }
    if (grp == 0) {
        float inv = 1.f / S;
        const float* bp = b1 + li * 8;
        bf16x8 hv, lv;
        #pragma unroll
        for (int c = 0; c < 8; ++c) {
            float o = lrelu(acc[c] * inv + bp[c]);
            __bf16 h = (__bf16)o;
            hv[c] = h;
            lv[c] = (__bf16)(o - (float)h);
        }
        *(bf16x8*)&h2h[w][li * 8] = hv;
        *(bf16x8*)&h2l[w][li * 8] = lv;
    }
    __syncthreads();

    // ---- gemm2 for this block's 16 h2 rows: waves 0-3, one col-tile each ----
    if (w < 4) {
        constexpr int KT = 4;
        int c0 = w;
        bf16x8 bh[KT], bl[KT];
        #pragma unroll
        for (int kt = 0; kt < KT; ++kt) {
            size_t bidx = ((size_t)(c0 * KT + kt) * 64 + l) * 8;
            bh[kt] = *(const bf16x8*)(whi2 + bidx);
            bl[kt] = *(const bf16x8*)(wlo2 + bidx);
        }
        int ar = l & 15, koff = (l >> 4) * 8;
        f32x4 acc2 = (f32x4){0.f, 0.f, 0.f, 0.f};
        #pragma unroll
        for (int kt = 0; kt < KT; ++kt) {
            bf16x8 ahi = *(const bf16x8*)&h2h[ar][kt * 32 + koff];
            bf16x8 alo = *(const bf16x8*)&h2l[ar][kt * 32 + koff];
            acc2 = __builtin_amdgcn_mfma_f32_16x16x32_bf16(ahi, bh[kt], acc2, 0, 0, 0);
            acc2 = __builtin_amdgcn_mfma_f32_16x16x32_bf16(ahi, bl[kt], acc2, 0, 0, 0);
            acc2 = __builtin_amdgcn_mfma_f32_16x16x32_bf16(alo, bh[kt], acc2, 0, 0, 0);
        }
        int crow0 = (l >> 4) * 4;
        int ccol = l & 15;
        float as_c = a_src2[c0 * 16 + ccol];
        float ad_c = a_dst2[c0 * 16 + ccol];
        #pragma unroll
        for (int r = 0; r < 4; ++r) {
            int row = blockIdx.x * 16 + crow0 + r;
            g[(size_t)row * F_OUT + c0 * 16 + ccol] = acc2[r];
            float vs = acc2[r] * as_c;
            float vd = acc2[r] * ad_c;
            #pragma unroll
            for (int d = 1; d < 16; d <<= 1) {
                vs += __shfl_xor(vs, d);
                vd += __shfl_xor(vd, d);
            }
            if (ccol == 0) { alsp[c0][crow0 + r] = vs; aldp[c0][crow0 + r] = vd; }
        }
    }
    __syncthreads();
    if (tid < 16) {
        als2[blockIdx.x * 16 + tid] = alsp[0][tid] + alsp[1][tid] + alsp[2][tid] + alsp[3][tid];
        ald2[blockIdx.x * 16 + tid] = aldp[0][tid] + aldp[1][tid] + aldp[2][tid] + aldp[3][tid];
    }
}

// -------------------- aggr2 (inline p2) ---------------------------------------

__global__ __launch_bounds__(256) void aggr2_kernel(const int* __restrict__ row_ptr,
                                                    const int2* __restrict__ epair,
                                                    const float* __restrict__ als2,
                                                    const float* __restrict__ ald2,
                                                    const float* __restrict__ g,
                                                    const float* __restrict__ b2,
                                                    float* __restrict__ out) {
    int wid = blockIdx.x * 4 + (threadIdx.x >> 6);
    int lane = threadIdx.x & 63;
    int grp = lane >> 4, li = lane & 15;
    int beg = row_ptr[wid], end = row_ptr[wid + 1];
    float ad = ald2[wid];
    float a0 = 0.f, a1 = 0.f, a2 = 0.f, a3 = 0.f, S = 0.f;
    for (int j0 = beg; j0 < end; j0 += 4) {
        int j = j0 + grp;
        bool valid = (j < end);
        int s = valid ? epair[j].x : 0;
        float p = valid ? __expf(lrelu(als2[s] + ad)) : 0.f;
        float4 gv = *(const float4*)(g + (size_t)s * F_OUT + li * 4);
        a0 += p * gv.x; a1 += p * gv.y; a2 += p * gv.z; a3 += p * gv.w;
        S += p;
    }
    #pragma unroll
    for (int d = 16; d < 64; d <<= 1) {
        a0 += __shfl_xor(a0, d); a1 += __shfl_xor(a1, d);
        a2 += __shfl_xor(a2, d); a3 += __shfl_xor(a3, d);
        S += __shfl_xor(S, d);
    }
    if (grp == 0) {
        float inv = 1.f / S;
        const float* bp = b2 + li * 4;
        float4 o;
        o.x = a0 * inv + bp[0];
        o.y = a1 * inv + bp[1];
        o.z = a2 * inv + bp[2];
        o.w = a3 * inv + bp[3];
        *(float4*)(out + (size_t)wid * F_OUT + li * 4) = o;
    }
}

// -------------------- launch --------------------------------------------------

extern "C" void kernel_launch(void* const* d_in, const int* in_sizes, int n_in,
                              void* d_out, int out_size, void* d_ws, size_t ws_size,
                              hipStream_t stream) {
    const float* x      = (const float*)d_in[0];
    const int*   ei     = (const int*)  d_in[1];
    const float* W1     = (const float*)d_in[2];
    const float* a_src1 = (const float*)d_in[3];
    const float* a_dst1 = (const float*)d_in[4];
    const float* b1     = (const float*)d_in[5];
    const float* W2     = (const float*)d_in[6];
    const float* a_src2 = (const float*)d_in[7];
    const float* a_dst2 = (const float*)d_in[8];
    const float* b2     = (const float*)d_in[9];
    float* out = (float*)d_out;
    char* ws = (char*)d_ws;

    // workspace layout (bytes)
    __bf16* h1b    = (__bf16*)(ws + 0);         // N*128*2 = 12,800,000
    float* p1      = (float*)(ws + 12800000);   // (E+N)*4*4 = 10,400,000 (old h2 slot)
    float* g       = (float*)(ws + 38400000);   // N*64*4 = 12,800,000
    float* als1    = (float*)(ws + 51200000);   // 800,000
    float* ald1    = (float*)(ws + 52000000);   // 800,000
    float* als2    = (float*)(ws + 52800000);   // 200,000
    float* ald2    = (float*)(ws + 53000000);   // 200,000
    int*   rowp    = (int*)  (ws + 53200000);   // 200,004 (pad to 53,400,064)
    int*   bcur    = (int*)  (ws + 53400064);   // 784 (pad to 53,402,112)
    int2*  bstage  = (int2*) (ws + 53402112);   // NBKT*BMAX*8 = 9,633,792 -> 63,035,904
    int2*  epair   = (int2*) (ws + 63035904);   // (E+N)*8 = 5,200,000 -> 68,235,904
    __bf16* whi1   = (__bf16*)(ws + 68235904);  // 65,536
    __bf16* wlo1   = (__bf16*)(ws + 68301440);  // 65,536
    __bf16* whi2   = (__bf16*)(ws + 68366976);  // 16,384
    __bf16* wlo2   = (__bf16*)(ws + 68383360);  // 16,384 (end 68,399,744)

    init_kernel<<<1 + (NPACK + 255) / 256, 256, 0, stream>>>(
        W1, W2, whi1, wlo1, whi2, wlo2, bcur);

    gemm1_bappend_kernel<<<NAB + GB1, 256, 0, stream>>>(
        x, whi1, wlo1, a_src1, a_dst1, h1b, als1, ald1, ei, bcur, bstage);

    bsortp1_kernel<<<NBKT, 1024, 0, stream>>>(bcur, bstage, als1, ald1, rowp, epair, p1);

    aggr1g_kernel<<<N_NODES / 16, 1024, 0, stream>>>(
        rowp, epair, p1, h1b, b1, whi2, wlo2, a_src2, a_dst2, g, als2, ald2);

    aggr2_kernel<<<N_NODES / 4, 256, 0, stream>>>(rowp, epair, als2, ald2, g, b2, out);
}

// Round 23
// 135.596 us; speedup vs baseline: 4.0943x; 1.0168x over previous
//
#include <hip/hip_runtime.h>
#include <hip/hip_bf16.h>

#define N_NODES 50000
#define E_EDGES 600000
#define F_IN    256
#define HC1     128   // 4 heads * 32
#define F_OUT   64
#define NBKT    196   // ceil(N_NODES/256) coarse dst-buckets
#define BMAX    6144  // per-bucket capacity (mean 3316, sigma ~58)
#define APB     8192  // edges per bappend chunk
#define NAB     80    // ceil((E+N)/APB)
#define GB1     1563  // gemm1 tile blocks = ceil(N/32)
#define NPACK   (F_IN * HC1 + HC1 * F_OUT)   // 40960

typedef __bf16 bf16x8 __attribute__((ext_vector_type(8)));
typedef __bf16 bf16x4 __attribute__((ext_vector_type(4)));
typedef float  f32x4  __attribute__((ext_vector_type(4)));

__device__ __forceinline__ float lrelu(float x) { return x > 0.f ? x : 0.2f * x; }
__device__ __forceinline__ float bfhi(unsigned v) { return __uint_as_float(v & 0xffff0000u); }
__device__ __forceinline__ float bflo(unsigned v) { return __uint_as_float(v << 16); }

// -------------------- init: zero bucket cursors + pack W (fused) --------------

__global__ __launch_bounds__(256) void init_kernel(const float* __restrict__ W1,
                                                   const float* __restrict__ W2,
                                                   __bf16* __restrict__ hi1, __bf16* __restrict__ lo1,
                                                   __bf16* __restrict__ hi2, __bf16* __restrict__ lo2,
                                                   int* __restrict__ bcur) {
    if (blockIdx.x == 0) {
        if (threadIdx.x < NBKT) bcur[threadIdx.x] = 0;
        return;
    }
    int tid = (blockIdx.x - 1) * 256 + threadIdx.x;
    if (tid >= NPACK) return;
    if (tid < F_IN * HC1) {
        int t = tid;
        int j = t & 7, l = (t >> 3) & 63, kt = (t >> 9) & 7, ct = t >> 12;
        int k = kt * 32 + (l >> 4) * 8 + j;
        int col = ct * 16 + (l & 15);
        float v = W1[k * HC1 + col];
        __bf16 h = (__bf16)v;
        hi1[t] = h;
        lo1[t] = (__bf16)(v - (float)h);
    } else {
        int t = tid - F_IN * HC1;
        int j = t & 7, l = (t >> 3) & 63, kt = (t >> 9) & 3, ct = t >> 11;
        int k = kt * 32 + (l >> 4) * 8 + j;
        int col = ct * 16 + (l & 15);
        float v = W2[k * F_OUT + col];
        __bf16 h = (__bf16)v;
        hi2[t] = h;
        lo2[t] = (__bf16)(v - (float)h);
    }
}

// -------------------- fused gemm1 + bappend (bappend at grid front) -----------

__global__ __launch_bounds__(256) void gemm1_bappend_kernel(
        const float* __restrict__ A,
        const __bf16* __restrict__ Whi, const __bf16* __restrict__ Wlo,
        const float* __restrict__ a_s, const float* __restrict__ a_d,
        __bf16* __restrict__ Cout, float* __restrict__ als, float* __restrict__ ald,
        const int* __restrict__ ei, int* __restrict__ bcur, int2* __restrict__ bstage) {
    __shared__ __bf16 ah[32][F_IN + 8];
    __shared__ __bf16 al[32][F_IN + 8];
    __shared__ int lcnt[NBKT];
    int tid = threadIdx.x;

    if (blockIdx.x < NAB) {
        const int TOT = E_EDGES + N_NODES;
        int bb = (int)blockIdx.x;
        int e0 = bb * APB;
        int e1 = e0 + APB < TOT ? e0 + APB : TOT;
        if (tid < NBKT) lcnt[tid] = 0;
        __syncthreads();
        for (int i = e0 + tid; i < e1; i += 256) {
            int d = (i < E_EDGES) ? ei[E_EDGES + i] : (i - E_EDGES);
            atomicAdd(&lcnt[d >> 8], 1);
        }
        __syncthreads();
        if (tid < NBKT) {
            int c = lcnt[tid];
            lcnt[tid] = c ? atomicAdd(&bcur[tid], c) : 0;
        }
        __syncthreads();
        for (int i = e0 + tid; i < e1; i += 256) {
            int s, d;
            if (i < E_EDGES) { s = ei[i]; d = ei[E_EDGES + i]; }
            else             { s = d = i - E_EDGES; }
            int b = d >> 8;
            int pos = atomicAdd(&lcnt[b], 1);
            bstage[(size_t)b * BMAX + pos] = make_int2(s, d);
        }
        return;
    }

    // gemm1 tile (KDIM=256, NC=128, CGROUPS=2)
    constexpr int KT = 8, CTW = 4, F4PR = 64;
    int tb = (int)blockIdx.x - NAB;
    #pragma unroll
    for (int it = 0; it < 8; ++it) {
        int idx = it * 256 + tid;
        int row = idx / F4PR;
        int kk  = (idx - row * F4PR) * 4;
        int grow = tb * 32 + row;
        const float* src = A + (size_t)(grow < N_NODES ? grow : N_NODES - 1) * F_IN + kk;
        float4 v = *(const float4*)src;
        bf16x4 h, lo;
        h[0] = (__bf16)v.x; h[1] = (__bf16)v.y; h[2] = (__bf16)v.z; h[3] = (__bf16)v.w;
        lo[0] = (__bf16)(v.x - (float)h[0]);
        lo[1] = (__bf16)(v.y - (float)h[1]);
        lo[2] = (__bf16)(v.z - (float)h[2]);
        lo[3] = (__bf16)(v.w - (float)h[3]);
        *(bf16x4*)&ah[row][kk] = h;
        *(bf16x4*)&al[row][kk] = lo;
    }
    __syncthreads();

    int w = tid >> 6, l = tid & 63;
    int rw = w & 1, cg = w >> 1;
    int c0 = cg * CTW;
    int r0 = tb * 32 + rw * 16;
    int rowL = rw * 16 + (l & 15);
    int koff = (l >> 4) * 8;

    bf16x8 bh[2][CTW], bl[2][CTW];
    #pragma unroll
    for (int c = 0; c < CTW; ++c) {
        size_t bidx = ((size_t)((c0 + c) * KT + 0) * 64 + l) * 8;
        bh[0][c] = *(const bf16x8*)(Whi + bidx);
        bl[0][c] = *(const bf16x8*)(Wlo + bidx);
    }

    f32x4 acc[CTW];
    #pragma unroll
    for (int c = 0; c < CTW; ++c) acc[c] = (f32x4){0.f, 0.f, 0.f, 0.f};

    #pragma unroll
    for (int kt = 0; kt < KT; ++kt) {
        const int cur = kt & 1, nxt = cur ^ 1;
        if (kt + 1 < KT) {
            #pragma unroll
            for (int c = 0; c < CTW; ++c) {
                size_t bidx = ((size_t)((c0 + c) * KT + (kt + 1)) * 64 + l) * 8;
                bh[nxt][c] = *(const bf16x8*)(Whi + bidx);
                bl[nxt][c] = *(const bf16x8*)(Wlo + bidx);
            }
        }
        bf16x8 ahi = *(const bf16x8*)&ah[rowL][kt * 32 + koff];
        bf16x8 alo = *(const bf16x8*)&al[rowL][kt * 32 + koff];
        #pragma unroll
        for (int c = 0; c < CTW; ++c) {
            acc[c] = __builtin_amdgcn_mfma_f32_16x16x32_bf16(ahi, bh[cur][c], acc[c], 0, 0, 0);
            acc[c] = __builtin_amdgcn_mfma_f32_16x16x32_bf16(ahi, bl[cur][c], acc[c], 0, 0, 0);
            acc[c] = __builtin_amdgcn_mfma_f32_16x16x32_bf16(alo, bh[cur][c], acc[c], 0, 0, 0);
        }
    }

    int crow0 = r0 + (l >> 4) * 4;
    int ccol = l & 15;

    #pragma unroll
    for (int c = 0; c < CTW; ++c) {
        #pragma unroll
        for (int r = 0; r < 4; ++r) {
            int row = crow0 + r;
            if (row < N_NODES)
                Cout[(size_t)row * HC1 + (c0 + c) * 16 + ccol] = (__bf16)acc[c][r];
        }
    }

    float as_c[CTW], ad_c[CTW];
    #pragma unroll
    for (int c = 0; c < CTW; ++c) {
        as_c[c] = a_s[(c0 + c) * 16 + ccol];
        ad_c[c] = a_d[(c0 + c) * 16 + ccol];
    }

    #pragma unroll
    for (int r = 0; r < 4; ++r) {
        int row = crow0 + r;
        #pragma unroll
        for (int hl = 0; hl < 2; ++hl) {
            int h = cg * 2 + hl;
            float vs = acc[2 * hl][r] * as_c[2 * hl] + acc[2 * hl + 1][r] * as_c[2 * hl + 1];
            float vd = acc[2 * hl][r] * ad_c[2 * hl] + acc[2 * hl + 1][r] * ad_c[2 * hl + 1];
            #pragma unroll
            for (int d = 1; d < 16; d <<= 1) {
                vs += __shfl_xor(vs, d);
                vd += __shfl_xor(vd, d);
            }
            if (ccol == 0 && row < N_NODES) { als[row * 4 + h] = vs; ald[row * 4 + h] = vd; }
        }
    }
}

// -------------------- bsort + fused p1 ----------------------------------------

__global__ __launch_bounds__(1024) void bsortp1_kernel(const int* __restrict__ bcur,
                                                       const int2* __restrict__ bstage,
                                                       const float* __restrict__ als1,
                                                       const float* __restrict__ ald1,
                                                       int* __restrict__ rowp,
                                                       int2* __restrict__ epair,
                                                       float* __restrict__ p1) {
    __shared__ int cnt[256], cur[256], ws4[4];
    __shared__ int bbase_s;
    __shared__ int2 sorted[BMAX];
    int b = blockIdx.x, tid = threadIdx.x;
    int nb = bcur[b]; if (nb > BMAX) nb = BMAX;
    int d0 = b << 8;

    if (tid < 256) {
        int lane = tid & 63, w = tid >> 6;
        int v = (tid < NBKT) ? bcur[tid] : 0;
        int s = v;
        #pragma unroll
        for (int d = 1; d < 64; d <<= 1) {
            int t = __shfl_up(s, d);
            if (lane >= d) s += t;
        }
        if (lane == 63) ws4[w] = s;
        __syncthreads();
        if (tid == 0) {
            int r = 0;
            #pragma unroll
            for (int q = 0; q < 4; ++q) { int t = ws4[q]; ws4[q] = r; r += t; }
        }
        __syncthreads();
        if (tid == b) bbase_s = ws4[w] + s - v;
        if (b == 0 && tid == 0) rowp[N_NODES] = E_EDGES + N_NODES;
    } else {
        __syncthreads();
        __syncthreads();
    }
    if (tid < 256) cnt[tid] = 0;
    __syncthreads();
    int base = bbase_s;

    const int2* bs = bstage + (size_t)b * BMAX;
    for (int e = tid; e < nb; e += 1024)
        atomicAdd(&cnt[bs[e].y - d0], 1);
    __syncthreads();
    int v = 0, s = 0;
    if (tid < 256) {
        int lane = tid & 63, w = tid >> 6;
        v = cnt[tid];
        s = v;
        #pragma unroll
        for (int d = 1; d < 64; d <<= 1) {
            int t = __shfl_up(s, d);
            if (lane >= d) s += t;
        }
        if (lane == 63) ws4[w] = s;
    }
    __syncthreads();
    if (tid == 0) {
        int r = 0;
        #pragma unroll
        for (int q = 0; q < 4; ++q) { int t = ws4[q]; ws4[q] = r; r += t; }
    }
    __syncthreads();
    if (tid < 256) {
        int excl = ws4[tid >> 6] + s - v;
        cur[tid] = excl;
        int d = d0 + tid;
        if (d < N_NODES) rowp[d] = base + excl;
    }
    __syncthreads();
    for (int e = tid; e < nb; e += 1024) {
        int2 ed = bs[e];
        int p = atomicAdd(&cur[ed.y - d0], 1);
        sorted[p] = ed;
    }
    __syncthreads();
    for (int e = tid; e < nb; e += 1024) {
        int2 ed = sorted[e];
        epair[base + e] = ed;
        float4 as = *(const float4*)&als1[ed.x * 4];
        float4 ad = *(const float4*)&ald1[ed.y * 4];
        float4 p;
        p.x = __expf(lrelu(as.x + ad.x));
        p.y = __expf(lrelu(as.y + ad.y));
        p.z = __expf(lrelu(as.z + ad.z));
        p.w = __expf(lrelu(as.w + ad.w));
        *(float4*)&p1[(size_t)(base + e) * 4] = p;
    }
}

// -------------------- fused aggr1 + gemm2 -------------------------------------
// 16 waves = 16 dsts per block. R23: 8 edge-groups x 8 lanes (iterations per
// dst = ceil(deg/8): max-of-16 critical path ~3 iters, was ~5.5 at deg/4) and
// (src,p) index prefetch one iteration ahead (overlaps the epair->gather
// dependent chain; only the h1b gather latency stays exposed per iter).

__global__ __launch_bounds__(1024) void aggr1g_kernel(
        const int* __restrict__ rowp, const int2* __restrict__ epair,
        const float* __restrict__ p1, const __bf16* __restrict__ h1b,
        const float* __restrict__ b1,
        const __bf16* __restrict__ whi2, const __bf16* __restrict__ wlo2,
        const float* __restrict__ a_src2, const float* __restrict__ a_dst2,
        float* __restrict__ g, float* __restrict__ als2, float* __restrict__ ald2) {
    __shared__ __bf16 h2h[16][HC1 + 8];
    __shared__ __bf16 h2l[16][HC1 + 8];
    __shared__ float alsp[4][16], aldp[4][16];
    int tid = threadIdx.x;
    int w = tid >> 6, l = tid & 63;
    int wid = blockIdx.x * 16 + w;
    int grp = l >> 3, li = l & 7;          // 8 groups x 8 lanes
    int hh = li >> 1;                      // head of this lane's 16 cols
    int beg = rowp[wid], end = rowp[wid + 1];

    // ---- aggregation: 8 edges in flight per wave, (s,p) prefetched ----
    float acc[16];
    #pragma unroll
    for (int c = 0; c < 16; ++c) acc[c] = 0.f;
    float S = 0.f;

    int j = beg + grp;
    int s_c = 0; float p_c = 0.f;
    if (j < end) { s_c = epair[j].x; p_c = p1[(size_t)j * 4 + hh]; }
    for (int j0 = beg; j0 < end; j0 += 8) {
        int jn = j0 + 8 + grp;
        int s_n = 0; float p_n = 0.f;
        if (jn < end) { s_n = epair[jn].x; p_n = p1[(size_t)jn * 4 + hh]; }
        const __bf16* hrow = h1b + (size_t)s_c * HC1 + li * 16;
        uint4 v0 = *(const uint4*)hrow;
        uint4 v1 = *(const uint4*)(hrow + 8);
        acc[0]  += p_c * bflo(v0.x); acc[1]  += p_c * bfhi(v0.x);
        acc[2]  += p_c * bflo(v0.y); acc[3]  += p_c * bfhi(v0.y);
        acc[4]  += p_c * bflo(v0.z); acc[5]  += p_c * bfhi(v0.z);
        acc[6]  += p_c * bflo(v0.w); acc[7]  += p_c * bfhi(v0.w);
        acc[8]  += p_c * bflo(v1.x); acc[9]  += p_c * bfhi(v1.x);
        acc[10] += p_c * bflo(v1.y); acc[11] += p_c * bfhi(v1.y);
        acc[12] += p_c * bflo(v1.z); acc[13] += p_c * bfhi(v1.z);
        acc[14] += p_c * bflo(v1.w); acc[15] += p_c * bfhi(v1.w);
        S += p_c;
        s_c = s_n; p_c = p_n;
    }
    #pragma unroll
    for (int d = 8; d < 64; d <<= 1) {
        #pragma unroll
        for (int c = 0; c < 16; ++c) acc[c] += __shfl_xor(acc[c], d);
        S += __shfl_xor(S, d);
    }
    if (grp == 0) {
        float inv = 1.f / S;
        const float* bp = b1 + li * 16;
        bf16x8 hv0, lv0, hv1, lv1;
        #pragma unroll
        for (int c = 0; c < 8; ++c) {
            float o = lrelu(acc[c] * inv + bp[c]);
            __bf16 h = (__bf16)o;
            hv0[c] = h;
            lv0[c] = (__bf16)(o - (float)h);
        }
        #pragma unroll
        for (int c = 0; c < 8; ++c) {
            float o = lrelu(acc[8 + c] * inv + bp[8 + c]);
            __bf16 h = (__bf16)o;
            hv1[c] = h;
            lv1[c] = (__bf16)(o - (float)h);
        }
        *(bf16x8*)&h2h[w][li * 16] = hv0;
        *(bf16x8*)&h2l[w][li * 16] = lv0;
        *(bf16x8*)&h2h[w][li * 16 + 8] = hv1;
        *(bf16x8*)&h2l[w][li * 16 + 8] = lv1;
    }
    __syncthreads();

    // ---- gemm2 for this block's 16 h2 rows: waves 0-3, one col-tile each ----
    if (w < 4) {
        constexpr int KT = 4;
        int c0 = w;
        bf16x8 bh[KT], bl[KT];
        #pragma unroll
        for (int kt = 0; kt < KT; ++kt) {
            size_t bidx = ((size_t)(c0 * KT + kt) * 64 + l) * 8;
            bh[kt] = *(const bf16x8*)(whi2 + bidx);
            bl[kt] = *(const bf16x8*)(wlo2 + bidx);
        }
        int ar = l & 15, koff = (l >> 4) * 8;
        f32x4 acc2 = (f32x4){0.f, 0.f, 0.f, 0.f};
        #pragma unroll
        for (int kt = 0; kt < KT; ++kt) {
            bf16x8 ahi = *(const bf16x8*)&h2h[ar][kt * 32 + koff];
            bf16x8 alo = *(const bf16x8*)&h2l[ar][kt * 32 + koff];
            acc2 = __builtin_amdgcn_mfma_f32_16x16x32_bf16(ahi, bh[kt], acc2, 0, 0, 0);
            acc2 = __builtin_amdgcn_mfma_f32_16x16x32_bf16(ahi, bl[kt], acc2, 0, 0, 0);
            acc2 = __builtin_amdgcn_mfma_f32_16x16x32_bf16(alo, bh[kt], acc2, 0, 0, 0);
        }
        int crow0 = (l >> 4) * 4;
        int ccol = l & 15;
        float as_c = a_src2[c0 * 16 + ccol];
        float ad_c = a_dst2[c0 * 16 + ccol];
        #pragma unroll
        for (int r = 0; r < 4; ++r) {
            int row = blockIdx.x * 16 + crow0 + r;
            g[(size_t)row * F_OUT + c0 * 16 + ccol] = acc2[r];
            float vs = acc2[r] * as_c;
            float vd = acc2[r] * ad_c;
            #pragma unroll
            for (int d = 1; d < 16; d <<= 1) {
                vs += __shfl_xor(vs, d);
                vd += __shfl_xor(vd, d);
            }
            if (ccol == 0) { alsp[c0][crow0 + r] = vs; aldp[c0][crow0 + r] = vd; }
        }
    }
    __syncthreads();
    if (tid < 16) {
        als2[blockIdx.x * 16 + tid] = alsp[0][tid] + alsp[1][tid] + alsp[2][tid] + alsp[3][tid];
        ald2[blockIdx.x * 16 + tid] = aldp[0][tid] + aldp[1][tid] + aldp[2][tid] + aldp[3][tid];
    }
}

// -------------------- aggr2 (inline p2, 8x8 groups + prefetch) ----------------

__global__ __launch_bounds__(256) void aggr2_kernel(const int* __restrict__ row_ptr,
                                                    const int2* __restrict__ epair,
                                                    const float* __restrict__ als2,
                                                    const float* __restrict__ ald2,
                                                    const float* __restrict__ g,
                                                    const float* __restrict__ b2,
                                                    float* __restrict__ out) {
    int wid = blockIdx.x * 4 + (threadIdx.x >> 6);
    int lane = threadIdx.x & 63;
    int grp = lane >> 3, li = lane & 7;    // 8 groups x 8 lanes, 8 cols/lane
    int beg = row_ptr[wid], end = row_ptr[wid + 1];
    float ad = ald2[wid];
    float a[8];
    #pragma unroll
    for (int c = 0; c < 8; ++c) a[c] = 0.f;
    float S = 0.f;

    int j = beg + grp;
    int s_c = 0; float p_c = 0.f;
    if (j < end) { s_c = epair[j].x; p_c = __expf(lrelu(als2[s_c] + ad)); }
    for (int j0 = beg; j0 < end; j0 += 8) {
        int jn = j0 + 8 + grp;
        int s_n = 0; float p_n = 0.f;
        if (jn < end) { s_n = epair[jn].x; p_n = __expf(lrelu(als2[s_n] + ad)); }
        const float* grow = g + (size_t)s_c * F_OUT + li * 8;
        float4 g0 = *(const float4*)grow;
        float4 g1 = *(const float4*)(grow + 4);
        a[0] += p_c * g0.x; a[1] += p_c * g0.y; a[2] += p_c * g0.z; a[3] += p_c * g0.w;
        a[4] += p_c * g1.x; a[5] += p_c * g1.y; a[6] += p_c * g1.z; a[7] += p_c * g1.w;
        S += p_c;
        s_c = s_n; p_c = p_n;
    }
    #pragma unroll
    for (int d = 8; d < 64; d <<= 1) {
        #pragma unroll
        for (int c = 0; c < 8; ++c) a[c] += __shfl_xor(a[c], d);
        S += __shfl_xor(S, d);
    }
    if (grp == 0) {
        float inv = 1.f / S;
        const float* bp = b2 + li * 8;
        float4 o0, o1;
        o0.x = a[0] * inv + bp[0];
        o0.y = a[1] * inv + bp[1];
        o0.z = a[2] * inv + bp[2];
        o0.w = a[3] * inv + bp[3];
        o1.x = a[4] * inv + bp[4];
        o1.y = a[5] * inv + bp[5];
        o1.z = a[6] * inv + bp[6];
        o1.w = a[7] * inv + bp[7];
        float* orow = out + (size_t)wid * F_OUT + li * 8;
        *(float4*)orow = o0;
        *(float4*)(orow + 4) = o1;
    }
}

// -------------------- launch --------------------------------------------------

extern "C" void kernel_launch(void* const* d_in, const int* in_sizes, int n_in,
                              void* d_out, int out_size, void* d_ws, size_t ws_size,
                              hipStream_t stream) {
    const float* x      = (const float*)d_in[0];
    const int*   ei     = (const int*)  d_in[1];
    const float* W1     = (const float*)d_in[2];
    const float* a_src1 = (const float*)d_in[3];
    const float* a_dst1 = (const float*)d_in[4];
    const float* b1     = (const float*)d_in[5];
    const float* W2     = (const float*)d_in[6];
    const float* a_src2 = (const float*)d_in[7];
    const float* a_dst2 = (const float*)d_in[8];
    const float* b2     = (const float*)d_in[9];
    float* out = (float*)d_out;
    char* ws = (char*)d_ws;

    // workspace layout (bytes)
    __bf16* h1b    = (__bf16*)(ws + 0);         // N*128*2 = 12,800,000
    float* p1      = (float*)(ws + 12800000);   // (E+N)*4*4 = 10,400,000
    float* g       = (float*)(ws + 38400000);   // N*64*4 = 12,800,000
    float* als1    = (float*)(ws + 51200000);   // 800,000
    float* ald1    = (float*)(ws + 52000000);   // 800,000
    float* als2    = (float*)(ws + 52800000);   // 200,000
    float* ald2    = (float*)(ws + 53000000);   // 200,000
    int*   rowp    = (int*)  (ws + 53200000);   // 200,004 (pad to 53,400,064)
    int*   bcur    = (int*)  (ws + 53400064);   // 784 (pad to 53,402,112)
    int2*  bstage  = (int2*) (ws + 53402112);   // NBKT*BMAX*8 = 9,633,792 -> 63,035,904
    int2*  epair   = (int2*) (ws + 63035904);   // (E+N)*8 = 5,200,000 -> 68,235,904
    __bf16* whi1   = (__bf16*)(ws + 68235904);  // 65,536
    __bf16* wlo1   = (__bf16*)(ws + 68301440);  // 65,536
    __bf16* whi2   = (__bf16*)(ws + 68366976);  // 16,384
    __bf16* wlo2   = (__bf16*)(ws + 68383360);  // 16,384 (end 68,399,744)

    init_kernel<<<1 + (NPACK + 255) / 256, 256, 0, stream>>>(
        W1, W2, whi1, wlo1, whi2, wlo2, bcur);

    gemm1_bappend_kernel<<<NAB + GB1, 256, 0, stream>>>(
        x, whi1, wlo1, a_src1, a_dst1, h1b, als1, ald1, ei, bcur, bstage);

    bsortp1_kernel<<<NBKT, 1024, 0, stream>>>(bcur, bstage, als1, ald1, rowp, epair, p1);

    aggr1g_kernel<<<N_NODES / 16, 1024, 0, stream>>>(
        rowp, epair, p1, h1b, b1, whi2, wlo2, a_src2, a_dst2, g, als2, ald2);

    aggr2_kernel<<<N_NODES / 4, 256, 0, stream>>>(rowp, epair, als2, ald2, g, b2, out);
}

// Round 24
// 128.935 us; speedup vs baseline: 4.3058x; 1.0517x over previous
//
#include <hip/hip_runtime.h>
#include <hip/hip_bf16.h>

#define N_NODES 50000
#define E_EDGES 600000
#define F_IN    256
#define HC1     128   // 4 heads * 32
#define F_OUT   64
#define NBKT    196   // ceil(N_NODES/256) coarse dst-buckets
#define BMAX    6144  // per-bucket capacity (mean 3316, sigma ~58)
#define APB     8192  // edges per bappend chunk
#define NAB     80    // ceil((E+N)/APB)
#define GB1     1563  // gemm1 tile blocks = ceil(N/32)
#define NPACK   (F_IN * HC1 + HC1 * F_OUT)   // 40960

typedef __bf16 bf16x8 __attribute__((ext_vector_type(8)));
typedef __bf16 bf16x4 __attribute__((ext_vector_type(4)));
typedef float  f32x4  __attribute__((ext_vector_type(4)));

__device__ __forceinline__ float lrelu(float x) { return x > 0.f ? x : 0.2f * x; }
__device__ __forceinline__ float bfhi(unsigned v) { return __uint_as_float(v & 0xffff0000u); }
__device__ __forceinline__ float bflo(unsigned v) { return __uint_as_float(v << 16); }

// -------------------- init: zero bucket cursors + pack W (fused) --------------

__global__ __launch_bounds__(256) void init_kernel(const float* __restrict__ W1,
                                                   const float* __restrict__ W2,
                                                   __bf16* __restrict__ hi1, __bf16* __restrict__ lo1,
                                                   __bf16* __restrict__ hi2, __bf16* __restrict__ lo2,
                                                   int* __restrict__ bcur) {
    if (blockIdx.x == 0) {
        if (threadIdx.x < NBKT) bcur[threadIdx.x] = 0;
        return;
    }
    int tid = (blockIdx.x - 1) * 256 + threadIdx.x;
    if (tid >= NPACK) return;
    if (tid < F_IN * HC1) {
        int t = tid;
        int j = t & 7, l = (t >> 3) & 63, kt = (t >> 9) & 7, ct = t >> 12;
        int k = kt * 32 + (l >> 4) * 8 + j;
        int col = ct * 16 + (l & 15);
        float v = W1[k * HC1 + col];
        __bf16 h = (__bf16)v;
        hi1[t] = h;
        lo1[t] = (__bf16)(v - (float)h);
    } else {
        int t = tid - F_IN * HC1;
        int j = t & 7, l = (t >> 3) & 63, kt = (t >> 9) & 3, ct = t >> 11;
        int k = kt * 32 + (l >> 4) * 8 + j;
        int col = ct * 16 + (l & 15);
        float v = W2[k * F_OUT + col];
        __bf16 h = (__bf16)v;
        hi2[t] = h;
        lo2[t] = (__bf16)(v - (float)h);
    }
}

// -------------------- fused gemm1 + bappend (bappend at grid front) -----------

__global__ __launch_bounds__(256) void gemm1_bappend_kernel(
        const float* __restrict__ A,
        const __bf16* __restrict__ Whi, const __bf16* __restrict__ Wlo,
        const float* __restrict__ a_s, const float* __restrict__ a_d,
        __bf16* __restrict__ Cout, float* __restrict__ als, float* __restrict__ ald,
        const int* __restrict__ ei, int* __restrict__ bcur, int2* __restrict__ bstage) {
    __shared__ __bf16 ah[32][F_IN + 8];
    __shared__ __bf16 al[32][F_IN + 8];
    __shared__ int lcnt[NBKT];
    int tid = threadIdx.x;

    if (blockIdx.x < NAB) {
        const int TOT = E_EDGES + N_NODES;
        int bb = (int)blockIdx.x;
        int e0 = bb * APB;
        int e1 = e0 + APB < TOT ? e0 + APB : TOT;
        if (tid < NBKT) lcnt[tid] = 0;
        __syncthreads();
        for (int i = e0 + tid; i < e1; i += 256) {
            int d = (i < E_EDGES) ? ei[E_EDGES + i] : (i - E_EDGES);
            atomicAdd(&lcnt[d >> 8], 1);
        }
        __syncthreads();
        if (tid < NBKT) {
            int c = lcnt[tid];
            lcnt[tid] = c ? atomicAdd(&bcur[tid], c) : 0;
        }
        __syncthreads();
        for (int i = e0 + tid; i < e1; i += 256) {
            int s, d;
            if (i < E_EDGES) { s = ei[i]; d = ei[E_EDGES + i]; }
            else             { s = d = i - E_EDGES; }
            int b = d >> 8;
            int pos = atomicAdd(&lcnt[b], 1);
            bstage[(size_t)b * BMAX + pos] = make_int2(s, d);
        }
        return;
    }

    // gemm1 tile (KDIM=256, NC=128, CGROUPS=2)
    constexpr int KT = 8, CTW = 4, F4PR = 64;
    int tb = (int)blockIdx.x - NAB;
    #pragma unroll
    for (int it = 0; it < 8; ++it) {
        int idx = it * 256 + tid;
        int row = idx / F4PR;
        int kk  = (idx - row * F4PR) * 4;
        int grow = tb * 32 + row;
        const float* src = A + (size_t)(grow < N_NODES ? grow : N_NODES - 1) * F_IN + kk;
        float4 v = *(const float4*)src;
        bf16x4 h, lo;
        h[0] = (__bf16)v.x; h[1] = (__bf16)v.y; h[2] = (__bf16)v.z; h[3] = (__bf16)v.w;
        lo[0] = (__bf16)(v.x - (float)h[0]);
        lo[1] = (__bf16)(v.y - (float)h[1]);
        lo[2] = (__bf16)(v.z - (float)h[2]);
        lo[3] = (__bf16)(v.w - (float)h[3]);
        *(bf16x4*)&ah[row][kk] = h;
        *(bf16x4*)&al[row][kk] = lo;
    }
    __syncthreads();

    int w = tid >> 6, l = tid & 63;
    int rw = w & 1, cg = w >> 1;
    int c0 = cg * CTW;
    int r0 = tb * 32 + rw * 16;
    int rowL = rw * 16 + (l & 15);
    int koff = (l >> 4) * 8;

    bf16x8 bh[2][CTW], bl[2][CTW];
    #pragma unroll
    for (int c = 0; c < CTW; ++c) {
        size_t bidx = ((size_t)((c0 + c) * KT + 0) * 64 + l) * 8;
        bh[0][c] = *(const bf16x8*)(Whi + bidx);
        bl[0][c] = *(const bf16x8*)(Wlo + bidx);
    }

    f32x4 acc[CTW];
    #pragma unroll
    for (int c = 0; c < CTW; ++c) acc[c] = (f32x4){0.f, 0.f, 0.f, 0.f};

    #pragma unroll
    for (int kt = 0; kt < KT; ++kt) {
        const int cur = kt & 1, nxt = cur ^ 1;
        if (kt + 1 < KT) {
            #pragma unroll
            for (int c = 0; c < CTW; ++c) {
                size_t bidx = ((size_t)((c0 + c) * KT + (kt + 1)) * 64 + l) * 8;
                bh[nxt][c] = *(const bf16x8*)(Whi + bidx);
                bl[nxt][c] = *(const bf16x8*)(Wlo + bidx);
            }
        }
        bf16x8 ahi = *(const bf16x8*)&ah[rowL][kt * 32 + koff];
        bf16x8 alo = *(const bf16x8*)&al[rowL][kt * 32 + koff];
        #pragma unroll
        for (int c = 0; c < CTW; ++c) {
            acc[c] = __builtin_amdgcn_mfma_f32_16x16x32_bf16(ahi, bh[cur][c], acc[c], 0, 0, 0);
            acc[c] = __builtin_amdgcn_mfma_f32_16x16x32_bf16(ahi, bl[cur][c], acc[c], 0, 0, 0);
            acc[c] = __builtin_amdgcn_mfma_f32_16x16x32_bf16(alo, bh[cur][c], acc[c], 0, 0, 0);
        }
    }

    int crow0 = r0 + (l >> 4) * 4;
    int ccol = l & 15;

    #pragma unroll
    for (int c = 0; c < CTW; ++c) {
        #pragma unroll
        for (int r = 0; r < 4; ++r) {
            int row = crow0 + r;
            if (row < N_NODES)
                Cout[(size_t)row * HC1 + (c0 + c) * 16 + ccol] = (__bf16)acc[c][r];
        }
    }

    float as_c[CTW], ad_c[CTW];
    #pragma unroll
    for (int c = 0; c < CTW; ++c) {
        as_c[c] = a_s[(c0 + c) * 16 + ccol];
        ad_c[c] = a_d[(c0 + c) * 16 + ccol];
    }

    #pragma unroll
    for (int r = 0; r < 4; ++r) {
        int row = crow0 + r;
        #pragma unroll
        for (int hl = 0; hl < 2; ++hl) {
            int h = cg * 2 + hl;
            float vs = acc[2 * hl][r] * as_c[2 * hl] + acc[2 * hl + 1][r] * as_c[2 * hl + 1];
            float vd = acc[2 * hl][r] * ad_c[2 * hl] + acc[2 * hl + 1][r] * ad_c[2 * hl + 1];
            #pragma unroll
            for (int d = 1; d < 16; d <<= 1) {
                vs += __shfl_xor(vs, d);
                vd += __shfl_xor(vd, d);
            }
            if (ccol == 0 && row < N_NODES) { als[row * 4 + h] = vs; ald[row * 4 + h] = vd; }
        }
    }
}

// -------------------- bsort + fused p1 ----------------------------------------

__global__ __launch_bounds__(1024) void bsortp1_kernel(const int* __restrict__ bcur,
                                                       const int2* __restrict__ bstage,
                                                       const float* __restrict__ als1,
                                                       const float* __restrict__ ald1,
                                                       int* __restrict__ rowp,
                                                       int2* __restrict__ epair,
                                                       float* __restrict__ p1) {
    __shared__ int cnt[256], cur[256], ws4[4];
    __shared__ int bbase_s;
    __shared__ int2 sorted[BMAX];
    int b = blockIdx.x, tid = threadIdx.x;
    int nb = bcur[b]; if (nb > BMAX) nb = BMAX;
    int d0 = b << 8;

    if (tid < 256) {
        int lane = tid & 63, w = tid >> 6;
        int v = (tid < NBKT) ? bcur[tid] : 0;
        int s = v;
        #pragma unroll
        for (int d = 1; d < 64; d <<= 1) {
            int t = __shfl_up(s, d);
            if (lane >= d) s += t;
        }
        if (lane == 63) ws4[w] = s;
        __syncthreads();
        if (tid == 0) {
            int r = 0;
            #pragma unroll
            for (int q = 0; q < 4; ++q) { int t = ws4[q]; ws4[q] = r; r += t; }
        }
        __syncthreads();
        if (tid == b) bbase_s = ws4[w] + s - v;
        if (b == 0 && tid == 0) rowp[N_NODES] = E_EDGES + N_NODES;
    } else {
        __syncthreads();
        __syncthreads();
    }
    if (tid < 256) cnt[tid] = 0;
    __syncthreads();
    int base = bbase_s;

    const int2* bs = bstage + (size_t)b * BMAX;
    for (int e = tid; e < nb; e += 1024)
        atomicAdd(&cnt[bs[e].y - d0], 1);
    __syncthreads();
    int v = 0, s = 0;
    if (tid < 256) {
        int lane = tid & 63, w = tid >> 6;
        v = cnt[tid];
        s = v;
        #pragma unroll
        for (int d = 1; d < 64; d <<= 1) {
            int t = __shfl_up(s, d);
            if (lane >= d) s += t;
        }
        if (lane == 63) ws4[w] = s;
    }
    __syncthreads();
    if (tid == 0) {
        int r = 0;
        #pragma unroll
        for (int q = 0; q < 4; ++q) { int t = ws4[q]; ws4[q] = r; r += t; }
    }
    __syncthreads();
    if (tid < 256) {
        int excl = ws4[tid >> 6] + s - v;
        cur[tid] = excl;
        int d = d0 + tid;
        if (d < N_NODES) rowp[d] = base + excl;
    }
    __syncthreads();
    for (int e = tid; e < nb; e += 1024) {
        int2 ed = bs[e];
        int p = atomicAdd(&cur[ed.y - d0], 1);
        sorted[p] = ed;
    }
    __syncthreads();
    for (int e = tid; e < nb; e += 1024) {
        int2 ed = sorted[e];
        epair[base + e] = ed;
        float4 as = *(const float4*)&als1[ed.x * 4];
        float4 ad = *(const float4*)&ald1[ed.y * 4];
        float4 p;
        p.x = __expf(lrelu(as.x + ad.x));
        p.y = __expf(lrelu(as.y + ad.y));
        p.z = __expf(lrelu(as.z + ad.z));
        p.w = __expf(lrelu(as.w + ad.w));
        *(float4*)&p1[(size_t)(base + e) * 4] = p;
    }
}

// -------------------- fused aggr1 + gemm2 -------------------------------------
// 16 waves = 16 dsts per block. R24: aggregation back to 4 edge-groups x 16
// lanes (8 cols/lane: half the per-lane bf16-unpack VALU of R23's 8x8, which
// regressed), KEEPING the (s,p) one-iteration prefetch (overlaps the
// epair->p1 dependent chain).

__global__ __launch_bounds__(1024) void aggr1g_kernel(
        const int* __restrict__ rowp, const int2* __restrict__ epair,
        const float* __restrict__ p1, const __bf16* __restrict__ h1b,
        const float* __restrict__ b1,
        const __bf16* __restrict__ whi2, const __bf16* __restrict__ wlo2,
        const float* __restrict__ a_src2, const float* __restrict__ a_dst2,
        float* __restrict__ g, float* __restrict__ als2, float* __restrict__ ald2) {
    __shared__ __bf16 h2h[16][HC1 + 8];
    __shared__ __bf16 h2l[16][HC1 + 8];
    __shared__ float alsp[4][16], aldp[4][16];
    int tid = threadIdx.x;
    int w = tid >> 6, l = tid & 63;
    int wid = blockIdx.x * 16 + w;
    int grp = l >> 4, li = l & 15;         // 4 groups x 16 lanes, 8 cols/lane
    int hh = li >> 2;
    int beg = rowp[wid], end = rowp[wid + 1];

    float acc[8] = {0,0,0,0,0,0,0,0};
    float S = 0.f;

    int j = beg + grp;
    int s_c = 0; float p_c = 0.f;
    if (j < end) { s_c = epair[j].x; p_c = p1[(size_t)j * 4 + hh]; }
    for (int j0 = beg; j0 < end; j0 += 4) {
        int jn = j0 + 4 + grp;
        int s_n = 0; float p_n = 0.f;
        if (jn < end) { s_n = epair[jn].x; p_n = p1[(size_t)jn * 4 + hh]; }
        uint4 v = *(const uint4*)(h1b + (size_t)s_c * HC1 + li * 8);
        acc[0] += p_c * bflo(v.x); acc[1] += p_c * bfhi(v.x);
        acc[2] += p_c * bflo(v.y); acc[3] += p_c * bfhi(v.y);
        acc[4] += p_c * bflo(v.z); acc[5] += p_c * bfhi(v.z);
        acc[6] += p_c * bflo(v.w); acc[7] += p_c * bfhi(v.w);
        S += p_c;
        s_c = s_n; p_c = p_n;
    }
    #pragma unroll
    for (int d = 16; d < 64; d <<= 1) {
        #pragma unroll
        for (int c = 0; c < 8; ++c) acc[c] += __shfl_xor(acc[c], d);
        S += __shfl_xor(S, d);
    }
    if (grp == 0) {
        float inv = 1.f / S;
        const float* bp = b1 + li * 8;
        bf16x8 hv, lv;
        #pragma unroll
        for (int c = 0; c < 8; ++c) {
            float o = lrelu(acc[c] * inv + bp[c]);
            __bf16 h = (__bf16)o;
            hv[c] = h;
            lv[c] = (__bf16)(o - (float)h);
        }
        *(bf16x8*)&h2h[w][li * 8] = hv;
        *(bf16x8*)&h2l[w][li * 8] = lv;
    }
    __syncthreads();

    // ---- gemm2 for this block's 16 h2 rows: waves 0-3, one col-tile each ----
    if (w < 4) {
        constexpr int KT = 4;
        int c0 = w;
        bf16x8 bh[KT], bl[KT];
        #pragma unroll
        for (int kt = 0; kt < KT; ++kt) {
            size_t bidx = ((size_t)(c0 * KT + kt) * 64 + l) * 8;
            bh[kt] = *(const bf16x8*)(whi2 + bidx);
            bl[kt] = *(const bf16x8*)(wlo2 + bidx);
        }
        int ar = l & 15, koff = (l >> 4) * 8;
        f32x4 acc2 = (f32x4){0.f, 0.f, 0.f, 0.f};
        #pragma unroll
        for (int kt = 0; kt < KT; ++kt) {
            bf16x8 ahi = *(const bf16x8*)&h2h[ar][kt * 32 + koff];
            bf16x8 alo = *(const bf16x8*)&h2l[ar][kt * 32 + koff];
            acc2 = __builtin_amdgcn_mfma_f32_16x16x32_bf16(ahi, bh[kt], acc2, 0, 0, 0);
            acc2 = __builtin_amdgcn_mfma_f32_16x16x32_bf16(ahi, bl[kt], acc2, 0, 0, 0);
            acc2 = __builtin_amdgcn_mfma_f32_16x16x32_bf16(alo, bh[kt], acc2, 0, 0, 0);
        }
        int crow0 = (l >> 4) * 4;
        int ccol = l & 15;
        float as_c = a_src2[c0 * 16 + ccol];
        float ad_c = a_dst2[c0 * 16 + ccol];
        #pragma unroll
        for (int r = 0; r < 4; ++r) {
            int row = blockIdx.x * 16 + crow0 + r;
            g[(size_t)row * F_OUT + c0 * 16 + ccol] = acc2[r];
            float vs = acc2[r] * as_c;
            float vd = acc2[r] * ad_c;
            #pragma unroll
            for (int d = 1; d < 16; d <<= 1) {
                vs += __shfl_xor(vs, d);
                vd += __shfl_xor(vd, d);
            }
            if (ccol == 0) { alsp[c0][crow0 + r] = vs; aldp[c0][crow0 + r] = vd; }
        }
    }
    __syncthreads();
    if (tid < 16) {
        als2[blockIdx.x * 16 + tid] = alsp[0][tid] + alsp[1][tid] + alsp[2][tid] + alsp[3][tid];
        ald2[blockIdx.x * 16 + tid] = aldp[0][tid] + aldp[1][tid] + aldp[2][tid] + aldp[3][tid];
    }
}

// -------------------- aggr2 (inline p2, 8x8 groups + prefetch; R23 form) ------

__global__ __launch_bounds__(256) void aggr2_kernel(const int* __restrict__ row_ptr,
                                                    const int2* __restrict__ epair,
                                                    const float* __restrict__ als2,
                                                    const float* __restrict__ ald2,
                                                    const float* __restrict__ g,
                                                    const float* __restrict__ b2,
                                                    float* __restrict__ out) {
    int wid = blockIdx.x * 4 + (threadIdx.x >> 6);
    int lane = threadIdx.x & 63;
    int grp = lane >> 3, li = lane & 7;    // 8 groups x 8 lanes, 8 cols/lane
    int beg = row_ptr[wid], end = row_ptr[wid + 1];
    float ad = ald2[wid];
    float a[8];
    #pragma unroll
    for (int c = 0; c < 8; ++c) a[c] = 0.f;
    float S = 0.f;

    int j = beg + grp;
    int s_c = 0; float p_c = 0.f;
    if (j < end) { s_c = epair[j].x; p_c = __expf(lrelu(als2[s_c] + ad)); }
    for (int j0 = beg; j0 < end; j0 += 8) {
        int jn = j0 + 8 + grp;
        int s_n = 0; float p_n = 0.f;
        if (jn < end) { s_n = epair[jn].x; p_n = __expf(lrelu(als2[s_n] + ad)); }
        const float* grow = g + (size_t)s_c * F_OUT + li * 8;
        float4 g0 = *(const float4*)grow;
        float4 g1 = *(const float4*)(grow + 4);
        a[0] += p_c * g0.x; a[1] += p_c * g0.y; a[2] += p_c * g0.z; a[3] += p_c * g0.w;
        a[4] += p_c * g1.x; a[5] += p_c * g1.y; a[6] += p_c * g1.z; a[7] += p_c * g1.w;
        S += p_c;
        s_c = s_n; p_c = p_n;
    }
    #pragma unroll
    for (int d = 8; d < 64; d <<= 1) {
        #pragma unroll
        for (int c = 0; c < 8; ++c) a[c] += __shfl_xor(a[c], d);
        S += __shfl_xor(S, d);
    }
    if (grp == 0) {
        float inv = 1.f / S;
        const float* bp = b2 + li * 8;
        float4 o0, o1;
        o0.x = a[0] * inv + bp[0];
        o0.y = a[1] * inv + bp[1];
        o0.z = a[2] * inv + bp[2];
        o0.w = a[3] * inv + bp[3];
        o1.x = a[4] * inv + bp[4];
        o1.y = a[5] * inv + bp[5];
        o1.z = a[6] * inv + bp[6];
        o1.w = a[7] * inv + bp[7];
        float* orow = out + (size_t)wid * F_OUT + li * 8;
        *(float4*)orow = o0;
        *(float4*)(orow + 4) = o1;
    }
}

// -------------------- launch --------------------------------------------------

extern "C" void kernel_launch(void* const* d_in, const int* in_sizes, int n_in,
                              void* d_out, int out_size, void* d_ws, size_t ws_size,
                              hipStream_t stream) {
    const float* x      = (const float*)d_in[0];
    const int*   ei     = (const int*)  d_in[1];
    const float* W1     = (const float*)d_in[2];
    const float* a_src1 = (const float*)d_in[3];
    const float* a_dst1 = (const float*)d_in[4];
    const float* b1     = (const float*)d_in[5];
    const float* W2     = (const float*)d_in[6];
    const float* a_src2 = (const float*)d_in[7];
    const float* a_dst2 = (const float*)d_in[8];
    const float* b2     = (const float*)d_in[9];
    float* out = (float*)d_out;
    char* ws = (char*)d_ws;

    // workspace layout (bytes)
    __bf16* h1b    = (__bf16*)(ws + 0);         // N*128*2 = 12,800,000
    float* p1      = (float*)(ws + 12800000);   // (E+N)*4*4 = 10,400,000
    float* g       = (float*)(ws + 38400000);   // N*64*4 = 12,800,000
    float* als1    = (float*)(ws + 51200000);   // 800,000
    float* ald1    = (float*)(ws + 52000000);   // 800,000
    float* als2    = (float*)(ws + 52800000);   // 200,000
    float* ald2    = (float*)(ws + 53000000);   // 200,000
    int*   rowp    = (int*)  (ws + 53200000);   // 200,004 (pad to 53,400,064)
    int*   bcur    = (int*)  (ws + 53400064);   // 784 (pad to 53,402,112)
    int2*  bstage  = (int2*) (ws + 53402112);   // NBKT*BMAX*8 = 9,633,792 -> 63,035,904
    int2*  epair   = (int2*) (ws + 63035904);   // (E+N)*8 = 5,200,000 -> 68,235,904
    __bf16* whi1   = (__bf16*)(ws + 68235904);  // 65,536
    __bf16* wlo1   = (__bf16*)(ws + 68301440);  // 65,536
    __bf16* whi2   = (__bf16*)(ws + 68366976);  // 16,384
    __bf16* wlo2   = (__bf16*)(ws + 68383360);  // 16,384 (end 68,399,744)

    init_kernel<<<1 + (NPACK + 255) / 256, 256, 0, stream>>>(
        W1, W2, whi1, wlo1, whi2, wlo2, bcur);

    gemm1_bappend_kernel<<<NAB + GB1, 256, 0, stream>>>(
        x, whi1, wlo1, a_src1, a_dst1, h1b, als1, ald1, ei, bcur, bstage);

    bsortp1_kernel<<<NBKT, 1024, 0, stream>>>(bcur, bstage, als1, ald1, rowp, epair, p1);

    aggr1g_kernel<<<N_NODES / 16, 1024, 0, stream>>>(
        rowp, epair, p1, h1b, b1, whi2, wlo2, a_src2, a_dst2, g, als2, ald2);

    aggr2_kernel<<<N_NODES / 4, 256, 0, stream>>>(rowp, epair, als2, ald2, g, b2, out);
}

// Round 25
// 124.393 us; speedup vs baseline: 4.4631x; 1.0365x over previous
//
#include <hip/hip_runtime.h>
#include <hip/hip_bf16.h>

#define N_NODES 50000
#define E_EDGES 600000
#define F_IN    256
#define HC1     128   // 4 heads * 32
#define F_OUT   64
#define NBKT    196   // ceil(N_NODES/256) coarse dst-buckets
#define BMAX    6144  // per-bucket capacity (mean 3316, sigma ~58)
#define APB     8192  // edges per bappend chunk
#define NAB     80    // ceil((E+N)/APB)
#define GB1     1563  // gemm1 tile blocks = ceil(N/32)
#define NPACK   (F_IN * HC1 + HC1 * F_OUT)   // 40960

typedef __bf16 bf16x8 __attribute__((ext_vector_type(8)));
typedef __bf16 bf16x4 __attribute__((ext_vector_type(4)));
typedef float  f32x4  __attribute__((ext_vector_type(4)));

__device__ __forceinline__ float lrelu(float x) { return x > 0.f ? x : 0.2f * x; }
__device__ __forceinline__ float bfhi(unsigned v) { return __uint_as_float(v & 0xffff0000u); }
__device__ __forceinline__ float bflo(unsigned v) { return __uint_as_float(v << 16); }

// -------------------- init: zero bucket cursors + pack W (fused) --------------

__global__ __launch_bounds__(256) void init_kernel(const float* __restrict__ W1,
                                                   const float* __restrict__ W2,
                                                   __bf16* __restrict__ hi1, __bf16* __restrict__ lo1,
                                                   __bf16* __restrict__ hi2, __bf16* __restrict__ lo2,
                                                   int* __restrict__ bcur) {
    if (blockIdx.x == 0) {
        if (threadIdx.x < NBKT) bcur[threadIdx.x] = 0;
        return;
    }
    int tid = (blockIdx.x - 1) * 256 + threadIdx.x;
    if (tid >= NPACK) return;
    if (tid < F_IN * HC1) {
        int t = tid;
        int j = t & 7, l = (t >> 3) & 63, kt = (t >> 9) & 7, ct = t >> 12;
        int k = kt * 32 + (l >> 4) * 8 + j;
        int col = ct * 16 + (l & 15);
        float v = W1[k * HC1 + col];
        __bf16 h = (__bf16)v;
        hi1[t] = h;
        lo1[t] = (__bf16)(v - (float)h);
    } else {
        int t = tid - F_IN * HC1;
        int j = t & 7, l = (t >> 3) & 63, kt = (t >> 9) & 3, ct = t >> 11;
        int k = kt * 32 + (l >> 4) * 8 + j;
        int col = ct * 16 + (l & 15);
        float v = W2[k * F_OUT + col];
        __bf16 h = (__bf16)v;
        hi2[t] = h;
        lo2[t] = (__bf16)(v - (float)h);
    }
}

// -------------------- fused gemm1 + bappend (bappend at grid front) -----------

__global__ __launch_bounds__(256) void gemm1_bappend_kernel(
        const float* __restrict__ A,
        const __bf16* __restrict__ Whi, const __bf16* __restrict__ Wlo,
        const float* __restrict__ a_s, const float* __restrict__ a_d,
        __bf16* __restrict__ Cout, float* __restrict__ als, float* __restrict__ ald,
        const int* __restrict__ ei, int* __restrict__ bcur, int2* __restrict__ bstage) {
    __shared__ __bf16 ah[32][F_IN + 8];
    __shared__ __bf16 al[32][F_IN + 8];
    __shared__ int lcnt[NBKT];
    int tid = threadIdx.x;

    if (blockIdx.x < NAB) {
        const int TOT = E_EDGES + N_NODES;
        int bb = (int)blockIdx.x;
        int e0 = bb * APB;
        int e1 = e0 + APB < TOT ? e0 + APB : TOT;
        if (tid < NBKT) lcnt[tid] = 0;
        __syncthreads();
        for (int i = e0 + tid; i < e1; i += 256) {
            int d = (i < E_EDGES) ? ei[E_EDGES + i] : (i - E_EDGES);
            atomicAdd(&lcnt[d >> 8], 1);
        }
        __syncthreads();
        if (tid < NBKT) {
            int c = lcnt[tid];
            lcnt[tid] = c ? atomicAdd(&bcur[tid], c) : 0;
        }
        __syncthreads();
        for (int i = e0 + tid; i < e1; i += 256) {
            int s, d;
            if (i < E_EDGES) { s = ei[i]; d = ei[E_EDGES + i]; }
            else             { s = d = i - E_EDGES; }
            int b = d >> 8;
            int pos = atomicAdd(&lcnt[b], 1);
            bstage[(size_t)b * BMAX + pos] = make_int2(s, d);
        }
        return;
    }

    // gemm1 tile (KDIM=256, NC=128, CGROUPS=2)
    constexpr int KT = 8, CTW = 4, F4PR = 64;
    int tb = (int)blockIdx.x - NAB;
    #pragma unroll
    for (int it = 0; it < 8; ++it) {
        int idx = it * 256 + tid;
        int row = idx / F4PR;
        int kk  = (idx - row * F4PR) * 4;
        int grow = tb * 32 + row;
        const float* src = A + (size_t)(grow < N_NODES ? grow : N_NODES - 1) * F_IN + kk;
        float4 v = *(const float4*)src;
        bf16x4 h, lo;
        h[0] = (__bf16)v.x; h[1] = (__bf16)v.y; h[2] = (__bf16)v.z; h[3] = (__bf16)v.w;
        lo[0] = (__bf16)(v.x - (float)h[0]);
        lo[1] = (__bf16)(v.y - (float)h[1]);
        lo[2] = (__bf16)(v.z - (float)h[2]);
        lo[3] = (__bf16)(v.w - (float)h[3]);
        *(bf16x4*)&ah[row][kk] = h;
        *(bf16x4*)&al[row][kk] = lo;
    }
    __syncthreads();

    int w = tid >> 6, l = tid & 63;
    int rw = w & 1, cg = w >> 1;
    int c0 = cg * CTW;
    int r0 = tb * 32 + rw * 16;
    int rowL = rw * 16 + (l & 15);
    int koff = (l >> 4) * 8;

    bf16x8 bh[2][CTW], bl[2][CTW];
    #pragma unroll
    for (int c = 0; c < CTW; ++c) {
        size_t bidx = ((size_t)((c0 + c) * KT + 0) * 64 + l) * 8;
        bh[0][c] = *(const bf16x8*)(Whi + bidx);
        bl[0][c] = *(const bf16x8*)(Wlo + bidx);
    }

    f32x4 acc[CTW];
    #pragma unroll
    for (int c = 0; c < CTW; ++c) acc[c] = (f32x4){0.f, 0.f, 0.f, 0.f};

    #pragma unroll
    for (int kt = 0; kt < KT; ++kt) {
        const int cur = kt & 1, nxt = cur ^ 1;
        if (kt + 1 < KT) {
            #pragma unroll
            for (int c = 0; c < CTW; ++c) {
                size_t bidx = ((size_t)((c0 + c) * KT + (kt + 1)) * 64 + l) * 8;
                bh[nxt][c] = *(const bf16x8*)(Whi + bidx);
                bl[nxt][c] = *(const bf16x8*)(Wlo + bidx);
            }
        }
        bf16x8 ahi = *(const bf16x8*)&ah[rowL][kt * 32 + koff];
        bf16x8 alo = *(const bf16x8*)&al[rowL][kt * 32 + koff];
        #pragma unroll
        for (int c = 0; c < CTW; ++c) {
            acc[c] = __builtin_amdgcn_mfma_f32_16x16x32_bf16(ahi, bh[cur][c], acc[c], 0, 0, 0);
            acc[c] = __builtin_amdgcn_mfma_f32_16x16x32_bf16(ahi, bl[cur][c], acc[c], 0, 0, 0);
            acc[c] = __builtin_amdgcn_mfma_f32_16x16x32_bf16(alo, bh[cur][c], acc[c], 0, 0, 0);
        }
    }

    int crow0 = r0 + (l >> 4) * 4;
    int ccol = l & 15;

    #pragma unroll
    for (int c = 0; c < CTW; ++c) {
        #pragma unroll
        for (int r = 0; r < 4; ++r) {
            int row = crow0 + r;
            if (row < N_NODES)
                Cout[(size_t)row * HC1 + (c0 + c) * 16 + ccol] = (__bf16)acc[c][r];
        }
    }

    float as_c[CTW], ad_c[CTW];
    #pragma unroll
    for (int c = 0; c < CTW; ++c) {
        as_c[c] = a_s[(c0 + c) * 16 + ccol];
        ad_c[c] = a_d[(c0 + c) * 16 + ccol];
    }

    #pragma unroll
    for (int r = 0; r < 4; ++r) {
        int row = crow0 + r;
        #pragma unroll
        for (int hl = 0; hl < 2; ++hl) {
            int h = cg * 2 + hl;
            float vs = acc[2 * hl][r] * as_c[2 * hl] + acc[2 * hl + 1][r] * as_c[2 * hl + 1];
            float vd = acc[2 * hl][r] * ad_c[2 * hl] + acc[2 * hl + 1][r] * ad_c[2 * hl + 1];
            #pragma unroll
            for (int d = 1; d < 16; d <<= 1) {
                vs += __shfl_xor(vs, d);
                vd += __shfl_xor(vd, d);
            }
            if (ccol == 0 && row < N_NODES) { als[row * 4 + h] = vs; ald[row * 4 + h] = vd; }
        }
    }
}

// -------------------- bsort + fused p1 ----------------------------------------

__global__ __launch_bounds__(1024) void bsortp1_kernel(const int* __restrict__ bcur,
                                                       const int2* __restrict__ bstage,
                                                       const float* __restrict__ als1,
                                                       const float* __restrict__ ald1,
                                                       int* __restrict__ rowp,
                                                       int2* __restrict__ epair,
                                                       float* __restrict__ p1) {
    __shared__ int cnt[256], cur[256], ws4[4];
    __shared__ int bbase_s;
    __shared__ int2 sorted[BMAX];
    int b = blockIdx.x, tid = threadIdx.x;
    int nb = bcur[b]; if (nb > BMAX) nb = BMAX;
    int d0 = b << 8;

    if (tid < 256) {
        int lane = tid & 63, w = tid >> 6;
        int v = (tid < NBKT) ? bcur[tid] : 0;
        int s = v;
        #pragma unroll
        for (int d = 1; d < 64; d <<= 1) {
            int t = __shfl_up(s, d);
            if (lane >= d) s += t;
        }
        if (lane == 63) ws4[w] = s;
        __syncthreads();
        if (tid == 0) {
            int r = 0;
            #pragma unroll
            for (int q = 0; q < 4; ++q) { int t = ws4[q]; ws4[q] = r; r += t; }
        }
        __syncthreads();
        if (tid == b) bbase_s = ws4[w] + s - v;
        if (b == 0 && tid == 0) rowp[N_NODES] = E_EDGES + N_NODES;
    } else {
        __syncthreads();
        __syncthreads();
    }
    if (tid < 256) cnt[tid] = 0;
    __syncthreads();
    int base = bbase_s;

    const int2* bs = bstage + (size_t)b * BMAX;
    for (int e = tid; e < nb; e += 1024)
        atomicAdd(&cnt[bs[e].y - d0], 1);
    __syncthreads();
    int v = 0, s = 0;
    if (tid < 256) {
        int lane = tid & 63, w = tid >> 6;
        v = cnt[tid];
        s = v;
        #pragma unroll
        for (int d = 1; d < 64; d <<= 1) {
            int t = __shfl_up(s, d);
            if (lane >= d) s += t;
        }
        if (lane == 63) ws4[w] = s;
    }
    __syncthreads();
    if (tid == 0) {
        int r = 0;
        #pragma unroll
        for (int q = 0; q < 4; ++q) { int t = ws4[q]; ws4[q] = r; r += t; }
    }
    __syncthreads();
    if (tid < 256) {
        int excl = ws4[tid >> 6] + s - v;
        cur[tid] = excl;
        int d = d0 + tid;
        if (d < N_NODES) rowp[d] = base + excl;
    }
    __syncthreads();
    for (int e = tid; e < nb; e += 1024) {
        int2 ed = bs[e];
        int p = atomicAdd(&cur[ed.y - d0], 1);
        sorted[p] = ed;
    }
    __syncthreads();
    for (int e = tid; e < nb; e += 1024) {
        int2 ed = sorted[e];
        epair[base + e] = ed;
        float4 as = *(const float4*)&als1[ed.x * 4];
        float4 ad = *(const float4*)&ald1[ed.y * 4];
        float4 p;
        p.x = __expf(lrelu(as.x + ad.x));
        p.y = __expf(lrelu(as.y + ad.y));
        p.z = __expf(lrelu(as.z + ad.z));
        p.w = __expf(lrelu(as.w + ad.w));
        *(float4*)&p1[(size_t)(base + e) * 4] = p;
    }
}

// -------------------- fused aggr1 + gemm2 -------------------------------------
// 16 waves = 16 dsts per block; 4 edge-groups x 16 lanes (8 cols/lane), R25:
// 2x edge unroll -- each group processes edges {j0+grp, j0+4+grp} per
// iteration (stride 8) with both (s,p) pairs prefetched one iteration ahead.
// Two independent h1b gathers in flight halve the serial-iteration count on
// the barrier-critical wave without adding per-lane unpack VALU per edge.

__global__ __launch_bounds__(1024) void aggr1g_kernel(
        const int* __restrict__ rowp, const int2* __restrict__ epair,
        const float* __restrict__ p1, const __bf16* __restrict__ h1b,
        const float* __restrict__ b1,
        const __bf16* __restrict__ whi2, const __bf16* __restrict__ wlo2,
        const float* __restrict__ a_src2, const float* __restrict__ a_dst2,
        float* __restrict__ g, float* __restrict__ als2, float* __restrict__ ald2) {
    __shared__ __bf16 h2h[16][HC1 + 8];
    __shared__ __bf16 h2l[16][HC1 + 8];
    __shared__ float alsp[4][16], aldp[4][16];
    int tid = threadIdx.x;
    int w = tid >> 6, l = tid & 63;
    int wid = blockIdx.x * 16 + w;
    int grp = l >> 4, li = l & 15;         // 4 groups x 16 lanes, 8 cols/lane
    int hh = li >> 2;
    int beg = rowp[wid], end = rowp[wid + 1];

    float acc[8] = {0,0,0,0,0,0,0,0};
    float S = 0.f;

    // 2 edges in flight per group: a = j0+grp, b = j0+4+grp (stride 8)
    int ja = beg + grp, jb = beg + 4 + grp;
    int sa = 0, sb = 0; float pa = 0.f, pb = 0.f;
    if (ja < end) { sa = epair[ja].x; pa = p1[(size_t)ja * 4 + hh]; }
    if (jb < end) { sb = epair[jb].x; pb = p1[(size_t)jb * 4 + hh]; }
    for (int j0 = beg; j0 < end; j0 += 8) {
        int jan = j0 + 8 + grp, jbn = j0 + 12 + grp;
        int san = 0, sbn = 0; float pan = 0.f, pbn = 0.f;
        if (jan < end) { san = epair[jan].x; pan = p1[(size_t)jan * 4 + hh]; }
        if (jbn < end) { sbn = epair[jbn].x; pbn = p1[(size_t)jbn * 4 + hh]; }
        uint4 va = *(const uint4*)(h1b + (size_t)sa * HC1 + li * 8);
        uint4 vb = *(const uint4*)(h1b + (size_t)sb * HC1 + li * 8);
        acc[0] += pa * bflo(va.x) + pb * bflo(vb.x);
        acc[1] += pa * bfhi(va.x) + pb * bfhi(vb.x);
        acc[2] += pa * bflo(va.y) + pb * bflo(vb.y);
        acc[3] += pa * bfhi(va.y) + pb * bfhi(vb.y);
        acc[4] += pa * bflo(va.z) + pb * bflo(vb.z);
        acc[5] += pa * bfhi(va.z) + pb * bfhi(vb.z);
        acc[6] += pa * bflo(va.w) + pb * bflo(vb.w);
        acc[7] += pa * bfhi(va.w) + pb * bfhi(vb.w);
        S += pa + pb;
        sa = san; pa = pan; sb = sbn; pb = pbn;
    }
    #pragma unroll
    for (int d = 16; d < 64; d <<= 1) {
        #pragma unroll
        for (int c = 0; c < 8; ++c) acc[c] += __shfl_xor(acc[c], d);
        S += __shfl_xor(S, d);
    }
    if (grp == 0) {
        float inv = 1.f / S;
        const float* bp = b1 + li * 8;
        bf16x8 hv, lv;
        #pragma unroll
        for (int c = 0; c < 8; ++c) {
            float o = lrelu(acc[c] * inv + bp[c]);
            __bf16 h = (__bf16)o;
            hv[c] = h;
            lv[c] = (__bf16)(o - (float)h);
        }
        *(bf16x8*)&h2h[w][li * 8] = hv;
        *(bf16x8*)&h2l[w][li * 8] = lv;
    }
    __syncthreads();

    // ---- gemm2 for this block's 16 h2 rows: waves 0-3, one col-tile each ----
    if (w < 4) {
        constexpr int KT = 4;
        int c0 = w;
        bf16x8 bh[KT], bl[KT];
        #pragma unroll
        for (int kt = 0; kt < KT; ++kt) {
            size_t bidx = ((size_t)(c0 * KT + kt) * 64 + l) * 8;
            bh[kt] = *(const bf16x8*)(whi2 + bidx);
            bl[kt] = *(const bf16x8*)(wlo2 + bidx);
        }
        int ar = l & 15, koff = (l >> 4) * 8;
        f32x4 acc2 = (f32x4){0.f, 0.f, 0.f, 0.f};
        #pragma unroll
        for (int kt = 0; kt < KT; ++kt) {
            bf16x8 ahi = *(const bf16x8*)&h2h[ar][kt * 32 + koff];
            bf16x8 alo = *(const bf16x8*)&h2l[ar][kt * 32 + koff];
            acc2 = __builtin_amdgcn_mfma_f32_16x16x32_bf16(ahi, bh[kt], acc2, 0, 0, 0);
            acc2 = __builtin_amdgcn_mfma_f32_16x16x32_bf16(ahi, bl[kt], acc2, 0, 0, 0);
            acc2 = __builtin_amdgcn_mfma_f32_16x16x32_bf16(alo, bh[kt], acc2, 0, 0, 0);
        }
        int crow0 = (l >> 4) * 4;
        int ccol = l & 15;
        float as_c = a_src2[c0 * 16 + ccol];
        float ad_c = a_dst2[c0 * 16 + ccol];
        #pragma unroll
        for (int r = 0; r < 4; ++r) {
            int row = blockIdx.x * 16 + crow0 + r;
            g[(size_t)row * F_OUT + c0 * 16 + ccol] = acc2[r];
            float vs = acc2[r] * as_c;
            float vd = acc2[r] * ad_c;
            #pragma unroll
            for (int d = 1; d < 16; d <<= 1) {
                vs += __shfl_xor(vs, d);
                vd += __shfl_xor(vd, d);
            }
            if (ccol == 0) { alsp[c0][crow0 + r] = vs; aldp[c0][crow0 + r] = vd; }
        }
    }
    __syncthreads();
    if (tid < 16) {
        als2[blockIdx.x * 16 + tid] = alsp[0][tid] + alsp[1][tid] + alsp[2][tid] + alsp[3][tid];
        ald2[blockIdx.x * 16 + tid] = aldp[0][tid] + aldp[1][tid] + aldp[2][tid] + aldp[3][tid];
    }
}

// -------------------- aggr2 (inline p2, 8x8 groups + prefetch) ----------------

__global__ __launch_bounds__(256) void aggr2_kernel(const int* __restrict__ row_ptr,
                                                    const int2* __restrict__ epair,
                                                    const float* __restrict__ als2,
                                                    const float* __restrict__ ald2,
                                                    const float* __restrict__ g,
                                                    const float* __restrict__ b2,
                                                    float* __restrict__ out) {
    int wid = blockIdx.x * 4 + (threadIdx.x >> 6);
    int lane = threadIdx.x & 63;
    int grp = lane >> 3, li = lane & 7;    // 8 groups x 8 lanes, 8 cols/lane
    int beg = row_ptr[wid], end = row_ptr[wid + 1];
    float ad = ald2[wid];
    float a[8];
    #pragma unroll
    for (int c = 0; c < 8; ++c) a[c] = 0.f;
    float S = 0.f;

    int j = beg + grp;
    int s_c = 0; float p_c = 0.f;
    if (j < end) { s_c = epair[j].x; p_c = __expf(lrelu(als2[s_c] + ad)); }
    for (int j0 = beg; j0 < end; j0 += 8) {
        int jn = j0 + 8 + grp;
        int s_n = 0; float p_n = 0.f;
        if (jn < end) { s_n = epair[jn].x; p_n = __expf(lrelu(als2[s_n] + ad)); }
        const float* grow = g + (size_t)s_c * F_OUT + li * 8;
        float4 g0 = *(const float4*)grow;
        float4 g1 = *(const float4*)(grow + 4);
        a[0] += p_c * g0.x; a[1] += p_c * g0.y; a[2] += p_c * g0.z; a[3] += p_c * g0.w;
        a[4] += p_c * g1.x; a[5] += p_c * g1.y; a[6] += p_c * g1.z; a[7] += p_c * g1.w;
        S += p_c;
        s_c = s_n; p_c = p_n;
    }
    #pragma unroll
    for (int d = 8; d < 64; d <<= 1) {
        #pragma unroll
        for (int c = 0; c < 8; ++c) a[c] += __shfl_xor(a[c], d);
        S += __shfl_xor(S, d);
    }
    if (grp == 0) {
        float inv = 1.f / S;
        const float* bp = b2 + li * 8;
        float4 o0, o1;
        o0.x = a[0] * inv + bp[0];
        o0.y = a[1] * inv + bp[1];
        o0.z = a[2] * inv + bp[2];
        o0.w = a[3] * inv + bp[3];
        o1.x = a[4] * inv + bp[4];
        o1.y = a[5] * inv + bp[5];
        o1.z = a[6] * inv + bp[6];
        o1.w = a[7] * inv + bp[7];
        float* orow = out + (size_t)wid * F_OUT + li * 8;
        *(float4*)orow = o0;
        *(float4*)(orow + 4) = o1;
    }
}

// -------------------- launch --------------------------------------------------

extern "C" void kernel_launch(void* const* d_in, const int* in_sizes, int n_in,
                              void* d_out, int out_size, void* d_ws, size_t ws_size,
                              hipStream_t stream) {
    const float* x      = (const float*)d_in[0];
    const int*   ei     = (const int*)  d_in[1];
    const float* W1     = (const float*)d_in[2];
    const float* a_src1 = (const float*)d_in[3];
    const float* a_dst1 = (const float*)d_in[4];
    const float* b1     = (const float*)d_in[5];
    const float* W2     = (const float*)d_in[6];
    const float* a_src2 = (const float*)d_in[7];
    const float* a_dst2 = (const float*)d_in[8];
    const float* b2     = (const float*)d_in[9];
    float* out = (float*)d_out;
    char* ws = (char*)d_ws;

    // workspace layout (bytes)
    __bf16* h1b    = (__bf16*)(ws + 0);         // N*128*2 = 12,800,000
    float* p1      = (float*)(ws + 12800000);   // (E+N)*4*4 = 10,400,000
    float* g       = (float*)(ws + 38400000);   // N*64*4 = 12,800,000
    float* als1    = (float*)(ws + 51200000);   // 800,000
    float* ald1    = (float*)(ws + 52000000);   // 800,000
    float* als2    = (float*)(ws + 52800000);   // 200,000
    float* ald2    = (float*)(ws + 53000000);   // 200,000
    int*   rowp    = (int*)  (ws + 53200000);   // 200,004 (pad to 53,400,064)
    int*   bcur    = (int*)  (ws + 53400064);   // 784 (pad to 53,402,112)
    int2*  bstage  = (int2*) (ws + 53402112);   // NBKT*BMAX*8 = 9,633,792 -> 63,035,904
    int2*  epair   = (int2*) (ws + 63035904);   // (E+N)*8 = 5,200,000 -> 68,235,904
    __bf16* whi1   = (__bf16*)(ws + 68235904);  // 65,536
    __bf16* wlo1   = (__bf16*)(ws + 68301440);  // 65,536
    __bf16* whi2   = (__bf16*)(ws + 68366976);  // 16,384
    __bf16* wlo2   = (__bf16*)(ws + 68383360);  // 16,384 (end 68,399,744)

    init_kernel<<<1 + (NPACK + 255) / 256, 256, 0, stream>>>(
        W1, W2, whi1, wlo1, whi2, wlo2, bcur);

    gemm1_bappend_kernel<<<NAB + GB1, 256, 0, stream>>>(
        x, whi1, wlo1, a_src1, a_dst1, h1b, als1, ald1, ei, bcur, bstage);

    bsortp1_kernel<<<NBKT, 1024, 0, stream>>>(bcur, bstage, als1, ald1, rowp, epair, p1);

    aggr1g_kernel<<<N_NODES / 16, 1024, 0, stream>>>(
        rowp, epair, p1, h1b, b1, whi2, wlo2, a_src2, a_dst2, g, als2, ald2);

    aggr2_kernel<<<N_NODES / 4, 256, 0, stream>>>(rowp, epair, als2, ald2, g, b2, out);
}

// Round 26
// 119.194 us; speedup vs baseline: 4.6577x; 1.0436x over previous
//
#include <hip/hip_runtime.h>
#include <hip/hip_bf16.h>

#define N_NODES 50000
#define E_EDGES 600000
#define F_IN    256
#define HC1     128   // 4 heads * 32
#define F_OUT   64
#define NBKT    196   // ceil(N_NODES/256) coarse dst-buckets
#define BMAX    6144  // per-bucket capacity (mean 3316, sigma ~58)
#define APB     8192  // edges per bappend chunk
#define NAB     80    // ceil((E+N)/APB)
#define GB1     1563  // gemm1 tile blocks = ceil(N/32)
#define NPACK   (F_IN * HC1 + HC1 * F_OUT)   // 40960

typedef __bf16 bf16x8 __attribute__((ext_vector_type(8)));
typedef __bf16 bf16x4 __attribute__((ext_vector_type(4)));
typedef float  f32x4  __attribute__((ext_vector_type(4)));

__device__ __forceinline__ float lrelu(float x) { return x > 0.f ? x : 0.2f * x; }
__device__ __forceinline__ float bfhi(unsigned v) { return __uint_as_float(v & 0xffff0000u); }
__device__ __forceinline__ float bflo(unsigned v) { return __uint_as_float(v << 16); }

// -------------------- init: zero bucket cursors + pack W (fused) --------------

__global__ __launch_bounds__(256) void init_kernel(const float* __restrict__ W1,
                                                   const float* __restrict__ W2,
                                                   __bf16* __restrict__ hi1, __bf16* __restrict__ lo1,
                                                   __bf16* __restrict__ hi2, __bf16* __restrict__ lo2,
                                                   int* __restrict__ bcur) {
    if (blockIdx.x == 0) {
        if (threadIdx.x < NBKT) bcur[threadIdx.x] = 0;
        return;
    }
    int tid = (blockIdx.x - 1) * 256 + threadIdx.x;
    if (tid >= NPACK) return;
    if (tid < F_IN * HC1) {
        int t = tid;
        int j = t & 7, l = (t >> 3) & 63, kt = (t >> 9) & 7, ct = t >> 12;
        int k = kt * 32 + (l >> 4) * 8 + j;
        int col = ct * 16 + (l & 15);
        float v = W1[k * HC1 + col];
        __bf16 h = (__bf16)v;
        hi1[t] = h;
        lo1[t] = (__bf16)(v - (float)h);
    } else {
        int t = tid - F_IN * HC1;
        int j = t & 7, l = (t >> 3) & 63, kt = (t >> 9) & 3, ct = t >> 11;
        int k = kt * 32 + (l >> 4) * 8 + j;
        int col = ct * 16 + (l & 15);
        float v = W2[k * F_OUT + col];
        __bf16 h = (__bf16)v;
        hi2[t] = h;
        lo2[t] = (__bf16)(v - (float)h);
    }
}

// -------------------- fused gemm1 + bappend (bappend at grid front) -----------

__global__ __launch_bounds__(256) void gemm1_bappend_kernel(
        const float* __restrict__ A,
        const __bf16* __restrict__ Whi, const __bf16* __restrict__ Wlo,
        const float* __restrict__ a_s, const float* __restrict__ a_d,
        __bf16* __restrict__ Cout, float* __restrict__ als, float* __restrict__ ald,
        const int* __restrict__ ei, int* __restrict__ bcur, int2* __restrict__ bstage) {
    __shared__ __bf16 ah[32][F_IN + 8];
    __shared__ __bf16 al[32][F_IN + 8];
    __shared__ int lcnt[NBKT];
    int tid = threadIdx.x;

    if (blockIdx.x < NAB) {
        const int TOT = E_EDGES + N_NODES;
        int bb = (int)blockIdx.x;
        int e0 = bb * APB;
        int e1 = e0 + APB < TOT ? e0 + APB : TOT;
        if (tid < NBKT) lcnt[tid] = 0;
        __syncthreads();
        for (int i = e0 + tid; i < e1; i += 256) {
            int d = (i < E_EDGES) ? ei[E_EDGES + i] : (i - E_EDGES);
            atomicAdd(&lcnt[d >> 8], 1);
        }
        __syncthreads();
        if (tid < NBKT) {
            int c = lcnt[tid];
            lcnt[tid] = c ? atomicAdd(&bcur[tid], c) : 0;
        }
        __syncthreads();
        for (int i = e0 + tid; i < e1; i += 256) {
            int s, d;
            if (i < E_EDGES) { s = ei[i]; d = ei[E_EDGES + i]; }
            else             { s = d = i - E_EDGES; }
            int b = d >> 8;
            int pos = atomicAdd(&lcnt[b], 1);
            bstage[(size_t)b * BMAX + pos] = make_int2(s, d);
        }
        return;
    }

    // gemm1 tile (KDIM=256, NC=128, CGROUPS=2)
    constexpr int KT = 8, CTW = 4, F4PR = 64;
    int tb = (int)blockIdx.x - NAB;
    #pragma unroll
    for (int it = 0; it < 8; ++it) {
        int idx = it * 256 + tid;
        int row = idx / F4PR;
        int kk  = (idx - row * F4PR) * 4;
        int grow = tb * 32 + row;
        const float* src = A + (size_t)(grow < N_NODES ? grow : N_NODES - 1) * F_IN + kk;
        float4 v = *(const float4*)src;
        bf16x4 h, lo;
        h[0] = (__bf16)v.x; h[1] = (__bf16)v.y; h[2] = (__bf16)v.z; h[3] = (__bf16)v.w;
        lo[0] = (__bf16)(v.x - (float)h[0]);
        lo[1] = (__bf16)(v.y - (float)h[1]);
        lo[2] = (__bf16)(v.z - (float)h[2]);
        lo[3] = (__bf16)(v.w - (float)h[3]);
        *(bf16x4*)&ah[row][kk] = h;
        *(bf16x4*)&al[row][kk] = lo;
    }
    __syncthreads();

    int w = tid >> 6, l = tid & 63;
    int rw = w & 1, cg = w >> 1;
    int c0 = cg * CTW;
    int r0 = tb * 32 + rw * 16;
    int rowL = rw * 16 + (l & 15);
    int koff = (l >> 4) * 8;

    bf16x8 bh[2][CTW], bl[2][CTW];
    #pragma unroll
    for (int c = 0; c < CTW; ++c) {
        size_t bidx = ((size_t)((c0 + c) * KT + 0) * 64 + l) * 8;
        bh[0][c] = *(const bf16x8*)(Whi + bidx);
        bl[0][c] = *(const bf16x8*)(Wlo + bidx);
    }

    f32x4 acc[CTW];
    #pragma unroll
    for (int c = 0; c < CTW; ++c) acc[c] = (f32x4){0.f, 0.f, 0.f, 0.f};

    #pragma unroll
    for (int kt = 0; kt < KT; ++kt) {
        const int cur = kt & 1, nxt = cur ^ 1;
        if (kt + 1 < KT) {
            #pragma unroll
            for (int c = 0; c < CTW; ++c) {
                size_t bidx = ((size_t)((c0 + c) * KT + (kt + 1)) * 64 + l) * 8;
                bh[nxt][c] = *(const bf16x8*)(Whi + bidx);
                bl[nxt][c] = *(const bf16x8*)(Wlo + bidx);
            }
        }
        bf16x8 ahi = *(const bf16x8*)&ah[rowL][kt * 32 + koff];
        bf16x8 alo = *(const bf16x8*)&al[rowL][kt * 32 + koff];
        #pragma unroll
        for (int c = 0; c < CTW; ++c) {
            acc[c] = __builtin_amdgcn_mfma_f32_16x16x32_bf16(ahi, bh[cur][c], acc[c], 0, 0, 0);
            acc[c] = __builtin_amdgcn_mfma_f32_16x16x32_bf16(ahi, bl[cur][c], acc[c], 0, 0, 0);
            acc[c] = __builtin_amdgcn_mfma_f32_16x16x32_bf16(alo, bh[cur][c], acc[c], 0, 0, 0);
        }
    }

    int crow0 = r0 + (l >> 4) * 4;
    int ccol = l & 15;

    #pragma unroll
    for (int c = 0; c < CTW; ++c) {
        #pragma unroll
        for (int r = 0; r < 4; ++r) {
            int row = crow0 + r;
            if (row < N_NODES)
                Cout[(size_t)row * HC1 + (c0 + c) * 16 + ccol] = (__bf16)acc[c][r];
        }
    }

    float as_c[CTW], ad_c[CTW];
    #pragma unroll
    for (int c = 0; c < CTW; ++c) {
        as_c[c] = a_s[(c0 + c) * 16 + ccol];
        ad_c[c] = a_d[(c0 + c) * 16 + ccol];
    }

    #pragma unroll
    for (int r = 0; r < 4; ++r) {
        int row = crow0 + r;
        #pragma unroll
        for (int hl = 0; hl < 2; ++hl) {
            int h = cg * 2 + hl;
            float vs = acc[2 * hl][r] * as_c[2 * hl] + acc[2 * hl + 1][r] * as_c[2 * hl + 1];
            float vd = acc[2 * hl][r] * ad_c[2 * hl] + acc[2 * hl + 1][r] * ad_c[2 * hl + 1];
            #pragma unroll
            for (int d = 1; d < 16; d <<= 1) {
                vs += __shfl_xor(vs, d);
                vd += __shfl_xor(vd, d);
            }
            if (ccol == 0 && row < N_NODES) { als[row * 4 + h] = vs; ald[row * 4 + h] = vd; }
        }
    }
}

// -------------------- bsort + fused p1 ----------------------------------------

__global__ __launch_bounds__(1024) void bsortp1_kernel(const int* __restrict__ bcur,
                                                       const int2* __restrict__ bstage,
                                                       const float* __restrict__ als1,
                                                       const float* __restrict__ ald1,
                                                       int* __restrict__ rowp,
                                                       int2* __restrict__ epair,
                                                       float* __restrict__ p1) {
    __shared__ int cnt[256], cur[256], ws4[4];
    __shared__ int bbase_s;
    __shared__ int2 sorted[BMAX];
    int b = blockIdx.x, tid = threadIdx.x;
    int nb = bcur[b]; if (nb > BMAX) nb = BMAX;
    int d0 = b << 8;

    if (tid < 256) {
        int lane = tid & 63, w = tid >> 6;
        int v = (tid < NBKT) ? bcur[tid] : 0;
        int s = v;
        #pragma unroll
        for (int d = 1; d < 64; d <<= 1) {
            int t = __shfl_up(s, d);
            if (lane >= d) s += t;
        }
        if (lane == 63) ws4[w] = s;
        __syncthreads();
        if (tid == 0) {
            int r = 0;
            #pragma unroll
            for (int q = 0; q < 4; ++q) { int t = ws4[q]; ws4[q] = r; r += t; }
        }
        __syncthreads();
        if (tid == b) bbase_s = ws4[w] + s - v;
        if (b == 0 && tid == 0) rowp[N_NODES] = E_EDGES + N_NODES;
    } else {
        __syncthreads();
        __syncthreads();
    }
    if (tid < 256) cnt[tid] = 0;
    __syncthreads();
    int base = bbase_s;

    const int2* bs = bstage + (size_t)b * BMAX;
    for (int e = tid; e < nb; e += 1024)
        atomicAdd(&cnt[bs[e].y - d0], 1);
    __syncthreads();
    int v = 0, s = 0;
    if (tid < 256) {
        int lane = tid & 63, w = tid >> 6;
        v = cnt[tid];
        s = v;
        #pragma unroll
        for (int d = 1; d < 64; d <<= 1) {
            int t = __shfl_up(s, d);
            if (lane >= d) s += t;
        }
        if (lane == 63) ws4[w] = s;
    }
    __syncthreads();
    if (tid == 0) {
        int r = 0;
        #pragma unroll
        for (int q = 0; q < 4; ++q) { int t = ws4[q]; ws4[q] = r; r += t; }
    }
    __syncthreads();
    if (tid < 256) {
        int excl = ws4[tid >> 6] + s - v;
        cur[tid] = excl;
        int d = d0 + tid;
        if (d < N_NODES) rowp[d] = base + excl;
    }
    __syncthreads();
    for (int e = tid; e < nb; e += 1024) {
        int2 ed = bs[e];
        int p = atomicAdd(&cur[ed.y - d0], 1);
        sorted[p] = ed;
    }
    __syncthreads();
    for (int e = tid; e < nb; e += 1024) {
        int2 ed = sorted[e];
        epair[base + e] = ed;
        float4 as = *(const float4*)&als1[ed.x * 4];
        float4 ad = *(const float4*)&ald1[ed.y * 4];
        float4 p;
        p.x = __expf(lrelu(as.x + ad.x));
        p.y = __expf(lrelu(as.y + ad.y));
        p.z = __expf(lrelu(as.z + ad.z));
        p.w = __expf(lrelu(as.w + ad.w));
        *(float4*)&p1[(size_t)(base + e) * 4] = p;
    }
}

// -------------------- fused aggr1 + gemm2 -------------------------------------
// R26: 4 waves x 4 SEQUENTIAL dsts each (still 16 dsts/block for the gemm2
// 16-row tile). Barrier-critical path becomes max-of-4(sum-of-4 degrees)
// ~1.14x mean instead of max-of-16(single) ~1.8x mean: ~36% fewer critical
// aggregation iterations, zero extra traffic. Inner loop keeps R25's 2x edge
// unroll + (s,p) prefetch.

__global__ __launch_bounds__(256) void aggr1g_kernel(
        const int* __restrict__ rowp, const int2* __restrict__ epair,
        const float* __restrict__ p1, const __bf16* __restrict__ h1b,
        const float* __restrict__ b1,
        const __bf16* __restrict__ whi2, const __bf16* __restrict__ wlo2,
        const float* __restrict__ a_src2, const float* __restrict__ a_dst2,
        float* __restrict__ g, float* __restrict__ als2, float* __restrict__ ald2) {
    __shared__ __bf16 h2h[16][HC1 + 8];
    __shared__ __bf16 h2l[16][HC1 + 8];
    __shared__ float alsp[4][16], aldp[4][16];
    int tid = threadIdx.x;
    int w = tid >> 6, l = tid & 63;
    int grp = l >> 4, li = l & 15;         // 4 groups x 16 lanes, 8 cols/lane
    int hh = li >> 2;

    // ---- aggregation: wave w handles dsts w*4 .. w*4+3 sequentially ----
    #pragma unroll
    for (int q = 0; q < 4; ++q) {
        int row = w * 4 + q;
        int wid = blockIdx.x * 16 + row;
        int beg = rowp[wid], end = rowp[wid + 1];

        float acc[8] = {0,0,0,0,0,0,0,0};
        float S = 0.f;

        int ja = beg + grp, jb = beg + 4 + grp;
        int sa = 0, sb = 0; float pa = 0.f, pb = 0.f;
        if (ja < end) { sa = epair[ja].x; pa = p1[(size_t)ja * 4 + hh]; }
        if (jb < end) { sb = epair[jb].x; pb = p1[(size_t)jb * 4 + hh]; }
        for (int j0 = beg; j0 < end; j0 += 8) {
            int jan = j0 + 8 + grp, jbn = j0 + 12 + grp;
            int san = 0, sbn = 0; float pan = 0.f, pbn = 0.f;
            if (jan < end) { san = epair[jan].x; pan = p1[(size_t)jan * 4 + hh]; }
            if (jbn < end) { sbn = epair[jbn].x; pbn = p1[(size_t)jbn * 4 + hh]; }
            uint4 va = *(const uint4*)(h1b + (size_t)sa * HC1 + li * 8);
            uint4 vb = *(const uint4*)(h1b + (size_t)sb * HC1 + li * 8);
            acc[0] += pa * bflo(va.x) + pb * bflo(vb.x);
            acc[1] += pa * bfhi(va.x) + pb * bfhi(vb.x);
            acc[2] += pa * bflo(va.y) + pb * bflo(vb.y);
            acc[3] += pa * bfhi(va.y) + pb * bfhi(vb.y);
            acc[4] += pa * bflo(va.z) + pb * bflo(vb.z);
            acc[5] += pa * bfhi(va.z) + pb * bfhi(vb.z);
            acc[6] += pa * bflo(va.w) + pb * bflo(vb.w);
            acc[7] += pa * bfhi(va.w) + pb * bfhi(vb.w);
            S += pa + pb;
            sa = san; pa = pan; sb = sbn; pb = pbn;
        }
        #pragma unroll
        for (int d = 16; d < 64; d <<= 1) {
            #pragma unroll
            for (int c = 0; c < 8; ++c) acc[c] += __shfl_xor(acc[c], d);
            S += __shfl_xor(S, d);
        }
        if (grp == 0) {
            float inv = 1.f / S;
            const float* bp = b1 + li * 8;
            bf16x8 hv, lv;
            #pragma unroll
            for (int c = 0; c < 8; ++c) {
                float o = lrelu(acc[c] * inv + bp[c]);
                __bf16 h = (__bf16)o;
                hv[c] = h;
                lv[c] = (__bf16)(o - (float)h);
            }
            *(bf16x8*)&h2h[row][li * 8] = hv;
            *(bf16x8*)&h2l[row][li * 8] = lv;
        }
    }
    __syncthreads();

    // ---- gemm2 for this block's 16 h2 rows: 4 waves, one col-tile each ----
    {
        constexpr int KT = 4;
        int c0 = w;
        bf16x8 bh[KT], bl[KT];
        #pragma unroll
        for (int kt = 0; kt < KT; ++kt) {
            size_t bidx = ((size_t)(c0 * KT + kt) * 64 + l) * 8;
            bh[kt] = *(const bf16x8*)(whi2 + bidx);
            bl[kt] = *(const bf16x8*)(wlo2 + bidx);
        }
        int ar = l & 15, koff = (l >> 4) * 8;
        f32x4 acc2 = (f32x4){0.f, 0.f, 0.f, 0.f};
        #pragma unroll
        for (int kt = 0; kt < KT; ++kt) {
            bf16x8 ahi = *(const bf16x8*)&h2h[ar][kt * 32 + koff];
            bf16x8 alo = *(const bf16x8*)&h2l[ar][kt * 32 + koff];
            acc2 = __builtin_amdgcn_mfma_f32_16x16x32_bf16(ahi, bh[kt], acc2, 0, 0, 0);
            acc2 = __builtin_amdgcn_mfma_f32_16x16x32_bf16(ahi, bl[kt], acc2, 0, 0, 0);
            acc2 = __builtin_amdgcn_mfma_f32_16x16x32_bf16(alo, bh[kt], acc2, 0, 0, 0);
        }
        int crow0 = (l >> 4) * 4;
        int ccol = l & 15;
        float as_c = a_src2[c0 * 16 + ccol];
        float ad_c = a_dst2[c0 * 16 + ccol];
        #pragma unroll
        for (int r = 0; r < 4; ++r) {
            int row = blockIdx.x * 16 + crow0 + r;
            g[(size_t)row * F_OUT + c0 * 16 + ccol] = acc2[r];
            float vs = acc2[r] * as_c;
            float vd = acc2[r] * ad_c;
            #pragma unroll
            for (int d = 1; d < 16; d <<= 1) {
                vs += __shfl_xor(vs, d);
                vd += __shfl_xor(vd, d);
            }
            if (ccol == 0) { alsp[c0][crow0 + r] = vs; aldp[c0][crow0 + r] = vd; }
        }
    }
    __syncthreads();
    if (tid < 16) {
        als2[blockIdx.x * 16 + tid] = alsp[0][tid] + alsp[1][tid] + alsp[2][tid] + alsp[3][tid];
        ald2[blockIdx.x * 16 + tid] = aldp[0][tid] + aldp[1][tid] + aldp[2][tid] + aldp[3][tid];
    }
}

// -------------------- aggr2 (inline p2, 8x8 groups + prefetch) ----------------

__global__ __launch_bounds__(256) void aggr2_kernel(const int* __restrict__ row_ptr,
                                                    const int2* __restrict__ epair,
                                                    const float* __restrict__ als2,
                                                    const float* __restrict__ ald2,
                                                    const float* __restrict__ g,
                                                    const float* __restrict__ b2,
                                                    float* __restrict__ out) {
    int wid = blockIdx.x * 4 + (threadIdx.x >> 6);
    int lane = threadIdx.x & 63;
    int grp = lane >> 3, li = lane & 7;    // 8 groups x 8 lanes, 8 cols/lane
    int beg = row_ptr[wid], end = row_ptr[wid + 1];
    float ad = ald2[wid];
    float a[8];
    #pragma unroll
    for (int c = 0; c < 8; ++c) a[c] = 0.f;
    float S = 0.f;

    int j = beg + grp;
    int s_c = 0; float p_c = 0.f;
    if (j < end) { s_c = epair[j].x; p_c = __expf(lrelu(als2[s_c] + ad)); }
    for (int j0 = beg; j0 < end; j0 += 8) {
        int jn = j0 + 8 + grp;
        int s_n = 0; float p_n = 0.f;
        if (jn < end) { s_n = epair[jn].x; p_n = __expf(lrelu(als2[s_n] + ad)); }
        const float* grow = g + (size_t)s_c * F_OUT + li * 8;
        float4 g0 = *(const float4*)grow;
        float4 g1 = *(const float4*)(grow + 4);
        a[0] += p_c * g0.x; a[1] += p_c * g0.y; a[2] += p_c * g0.z; a[3] += p_c * g0.w;
        a[4] += p_c * g1.x; a[5] += p_c * g1.y; a[6] += p_c * g1.z; a[7] += p_c * g1.w;
        S += p_c;
        s_c = s_n; p_c = p_n;
    }
    #pragma unroll
    for (int d = 8; d < 64; d <<= 1) {
        #pragma unroll
        for (int c = 0; c < 8; ++c) a[c] += __shfl_xor(a[c], d);
        S += __shfl_xor(S, d);
    }
    if (grp == 0) {
        float inv = 1.f / S;
        const float* bp = b2 + li * 8;
        float4 o0, o1;
        o0.x = a[0] * inv + bp[0];
        o0.y = a[1] * inv + bp[1];
        o0.z = a[2] * inv + bp[2];
        o0.w = a[3] * inv + bp[3];
        o1.x = a[4] * inv + bp[4];
        o1.y = a[5] * inv + bp[5];
        o1.z = a[6] * inv + bp[6];
        o1.w = a[7] * inv + bp[7];
        float* orow = out + (size_t)wid * F_OUT + li * 8;
        *(float4*)orow = o0;
        *(float4*)(orow + 4) = o1;
    }
}

// -------------------- launch --------------------------------------------------

extern "C" void kernel_launch(void* const* d_in, const int* in_sizes, int n_in,
                              void* d_out, int out_size, void* d_ws, size_t ws_size,
                              hipStream_t stream) {
    const float* x      = (const float*)d_in[0];
    const int*   ei     = (const int*)  d_in[1];
    const float* W1     = (const float*)d_in[2];
    const float* a_src1 = (const float*)d_in[3];
    const float* a_dst1 = (const float*)d_in[4];
    const float* b1     = (const float*)d_in[5];
    const float* W2     = (const float*)d_in[6];
    const float* a_src2 = (const float*)d_in[7];
    const float* a_dst2 = (const float*)d_in[8];
    const float* b2     = (const float*)d_in[9];
    float* out = (float*)d_out;
    char* ws = (char*)d_ws;

    // workspace layout (bytes)
    __bf16* h1b    = (__bf16*)(ws + 0);         // N*128*2 = 12,800,000
    float* p1      = (float*)(ws + 12800000);   // (E+N)*4*4 = 10,400,000
    float* g       = (float*)(ws + 38400000);   // N*64*4 = 12,800,000
    float* als1    = (float*)(ws + 51200000);   // 800,000
    float* ald1    = (float*)(ws + 52000000);   // 800,000
    float* als2    = (float*)(ws + 52800000);   // 200,000
    float* ald2    = (float*)(ws + 53000000);   // 200,000
    int*   rowp    = (int*)  (ws + 53200000);   // 200,004 (pad to 53,400,064)
    int*   bcur    = (int*)  (ws + 53400064);   // 784 (pad to 53,402,112)
    int2*  bstage  = (int2*) (ws + 53402112);   // NBKT*BMAX*8 = 9,633,792 -> 63,035,904
    int2*  epair   = (int2*) (ws + 63035904);   // (E+N)*8 = 5,200,000 -> 68,235,904
    __bf16* whi1   = (__bf16*)(ws + 68235904);  // 65,536
    __bf16* wlo1   = (__bf16*)(ws + 68301440);  // 65,536
    __bf16* whi2   = (__bf16*)(ws + 68366976);  // 16,384
    __bf16* wlo2   = (__bf16*)(ws + 68383360);  // 16,384 (end 68,399,744)

    init_kernel<<<1 + (NPACK + 255) / 256, 256, 0, stream>>>(
        W1, W2, whi1, wlo1, whi2, wlo2, bcur);

    gemm1_bappend_kernel<<<NAB + GB1, 256, 0, stream>>>(
        x, whi1, wlo1, a_src1, a_dst1, h1b, als1, ald1, ei, bcur, bstage);

    bsortp1_kernel<<<NBKT, 1024, 0, stream>>>(bcur, bstage, als1, ald1, rowp, epair, p1);

    aggr1g_kernel<<<N_NODES / 16, 256, 0, stream>>>(
        rowp, epair, p1, h1b, b1, whi2, wlo2, a_src2, a_dst2, g, als2, ald2);

    aggr2_kernel<<<N_NODES / 4, 256, 0, stream>>>(rowp, epair, als2, ald2, g, b2, out);
}

// Round 27
// 116.603 us; speedup vs baseline: 4.7612x; 1.0222x over previous
//
#include <hip/hip_runtime.h>
#include <hip/hip_bf16.h>

#define N_NODES 50000
#define E_EDGES 600000
#define F_IN    256
#define HC1     128   // 4 heads * 32
#define F_OUT   64
#define NBKT    196   // ceil(N_NODES/256) coarse dst-buckets
#define BMAX    6144  // per-bucket capacity (mean 3316, sigma ~58)
#define APB     8192  // edges per bappend chunk
#define NAB     80    // ceil((E+N)/APB)
#define GB1     3125  // gemm1 tile blocks = N/16 (exact)
#define NPACK   (F_IN * HC1 + HC1 * F_OUT)   // 40960

typedef __bf16 bf16x8 __attribute__((ext_vector_type(8)));
typedef __bf16 bf16x4 __attribute__((ext_vector_type(4)));
typedef float  f32x4  __attribute__((ext_vector_type(4)));

__device__ __forceinline__ float lrelu(float x) { return x > 0.f ? x : 0.2f * x; }
__device__ __forceinline__ float bfhi(unsigned v) { return __uint_as_float(v & 0xffff0000u); }
__device__ __forceinline__ float bflo(unsigned v) { return __uint_as_float(v << 16); }

// -------------------- init: zero bucket cursors + pack W (fused) --------------

__global__ __launch_bounds__(256) void init_kernel(const float* __restrict__ W1,
                                                   const float* __restrict__ W2,
                                                   __bf16* __restrict__ hi1, __bf16* __restrict__ lo1,
                                                   __bf16* __restrict__ hi2, __bf16* __restrict__ lo2,
                                                   int* __restrict__ bcur) {
    if (blockIdx.x == 0) {
        if (threadIdx.x < NBKT) bcur[threadIdx.x] = 0;
        return;
    }
    int tid = (blockIdx.x - 1) * 256 + threadIdx.x;
    if (tid >= NPACK) return;
    if (tid < F_IN * HC1) {
        int t = tid;
        int j = t & 7, l = (t >> 3) & 63, kt = (t >> 9) & 7, ct = t >> 12;
        int k = kt * 32 + (l >> 4) * 8 + j;
        int col = ct * 16 + (l & 15);
        float v = W1[k * HC1 + col];
        __bf16 h = (__bf16)v;
        hi1[t] = h;
        lo1[t] = (__bf16)(v - (float)h);
    } else {
        int t = tid - F_IN * HC1;
        int j = t & 7, l = (t >> 3) & 63, kt = (t >> 9) & 3, ct = t >> 11;
        int k = kt * 32 + (l >> 4) * 8 + j;
        int col = ct * 16 + (l & 15);
        float v = W2[k * F_OUT + col];
        __bf16 h = (__bf16)v;
        hi2[t] = h;
        lo2[t] = (__bf16)(v - (float)h);
    }
}

// -------------------- fused gemm1 + bappend (bappend at grid front) -----------
// R27: gemm1 tile shrunk to 16 rows/block (4 waves; wave = 16 rows x 32 cols =
// one whole head, CTW=2). LDS ~17.7KB -> 8 blocks/CU = 32 waves/CU, double the
// TLP of the 32-row tile (R26: occupancy 28%, latency-bound at 48us). Cost:
// B L2 traffic doubles (~400MB, B is L2-resident) -- hidden by the added TLP.

__global__ __launch_bounds__(256) void gemm1_bappend_kernel(
        const float* __restrict__ A,
        const __bf16* __restrict__ Whi, const __bf16* __restrict__ Wlo,
        const float* __restrict__ a_s, const float* __restrict__ a_d,
        __bf16* __restrict__ Cout, float* __restrict__ als, float* __restrict__ ald,
        const int* __restrict__ ei, int* __restrict__ bcur, int2* __restrict__ bstage) {
    __shared__ __bf16 ah[16][F_IN + 8];
    __shared__ __bf16 al[16][F_IN + 8];
    __shared__ int lcnt[NBKT];
    int tid = threadIdx.x;

    if (blockIdx.x < NAB) {
        const int TOT = E_EDGES + N_NODES;
        int bb = (int)blockIdx.x;
        int e0 = bb * APB;
        int e1 = e0 + APB < TOT ? e0 + APB : TOT;
        if (tid < NBKT) lcnt[tid] = 0;
        __syncthreads();
        for (int i = e0 + tid; i < e1; i += 256) {
            int d = (i < E_EDGES) ? ei[E_EDGES + i] : (i - E_EDGES);
            atomicAdd(&lcnt[d >> 8], 1);
        }
        __syncthreads();
        if (tid < NBKT) {
            int c = lcnt[tid];
            lcnt[tid] = c ? atomicAdd(&bcur[tid], c) : 0;
        }
        __syncthreads();
        for (int i = e0 + tid; i < e1; i += 256) {
            int s, d;
            if (i < E_EDGES) { s = ei[i]; d = ei[E_EDGES + i]; }
            else             { s = d = i - E_EDGES; }
            int b = d >> 8;
            int pos = atomicAdd(&lcnt[b], 1);
            bstage[(size_t)b * BMAX + pos] = make_int2(s, d);
        }
        return;
    }

    // gemm1 tile (KDIM=256, NC=128): 16 rows, 4 waves x CTW=2 col tiles
    constexpr int KT = 8, CTW = 2, F4PR = 64;
    int tb = (int)blockIdx.x - NAB;
    #pragma unroll
    for (int it = 0; it < 4; ++it) {
        int idx = it * 256 + tid;
        int row = idx / F4PR;
        int kk  = (idx - row * F4PR) * 4;
        int grow = tb * 16 + row;                 // GB1*16 == N_NODES: in range
        const float* src = A + (size_t)grow * F_IN + kk;
        float4 v = *(const float4*)src;
        bf16x4 h, lo;
        h[0] = (__bf16)v.x; h[1] = (__bf16)v.y; h[2] = (__bf16)v.z; h[3] = (__bf16)v.w;
        lo[0] = (__bf16)(v.x - (float)h[0]);
        lo[1] = (__bf16)(v.y - (float)h[1]);
        lo[2] = (__bf16)(v.z - (float)h[2]);
        lo[3] = (__bf16)(v.w - (float)h[3]);
        *(bf16x4*)&ah[row][kk] = h;
        *(bf16x4*)&al[row][kk] = lo;
    }
    __syncthreads();

    int w = tid >> 6, l = tid & 63;
    int c0 = w * CTW;                             // wave w covers head w (cols 32w..32w+31)
    int r0 = tb * 16;
    int rowL = l & 15;
    int koff = (l >> 4) * 8;

    bf16x8 bh[2][CTW], bl[2][CTW];
    #pragma unroll
    for (int c = 0; c < CTW; ++c) {
        size_t bidx = ((size_t)((c0 + c) * KT + 0) * 64 + l) * 8;
        bh[0][c] = *(const bf16x8*)(Whi + bidx);
        bl[0][c] = *(const bf16x8*)(Wlo + bidx);
    }

    f32x4 acc[CTW];
    #pragma unroll
    for (int c = 0; c < CTW; ++c) acc[c] = (f32x4){0.f, 0.f, 0.f, 0.f};

    #pragma unroll
    for (int kt = 0; kt < KT; ++kt) {
        const int cur = kt & 1, nxt = cur ^ 1;
        if (kt + 1 < KT) {
            #pragma unroll
            for (int c = 0; c < CTW; ++c) {
                size_t bidx = ((size_t)((c0 + c) * KT + (kt + 1)) * 64 + l) * 8;
                bh[nxt][c] = *(const bf16x8*)(Whi + bidx);
                bl[nxt][c] = *(const bf16x8*)(Wlo + bidx);
            }
        }
        bf16x8 ahi = *(const bf16x8*)&ah[rowL][kt * 32 + koff];
        bf16x8 alo = *(const bf16x8*)&al[rowL][kt * 32 + koff];
        #pragma unroll
        for (int c = 0; c < CTW; ++c) {
            acc[c] = __builtin_amdgcn_mfma_f32_16x16x32_bf16(ahi, bh[cur][c], acc[c], 0, 0, 0);
            acc[c] = __builtin_amdgcn_mfma_f32_16x16x32_bf16(ahi, bl[cur][c], acc[c], 0, 0, 0);
            acc[c] = __builtin_amdgcn_mfma_f32_16x16x32_bf16(alo, bh[cur][c], acc[c], 0, 0, 0);
        }
    }

    int crow0 = r0 + (l >> 4) * 4;
    int ccol = l & 15;

    #pragma unroll
    for (int c = 0; c < CTW; ++c) {
        #pragma unroll
        for (int r = 0; r < 4; ++r) {
            int row = crow0 + r;
            Cout[(size_t)row * HC1 + (c0 + c) * 16 + ccol] = (__bf16)acc[c][r];
        }
    }

    float as_c[CTW], ad_c[CTW];
    #pragma unroll
    for (int c = 0; c < CTW; ++c) {
        as_c[c] = a_s[(c0 + c) * 16 + ccol];
        ad_c[c] = a_d[(c0 + c) * 16 + ccol];
    }

    #pragma unroll
    for (int r = 0; r < 4; ++r) {
        int row = crow0 + r;
        float vs = acc[0][r] * as_c[0] + acc[1][r] * as_c[1];
        float vd = acc[0][r] * ad_c[0] + acc[1][r] * ad_c[1];
        #pragma unroll
        for (int d = 1; d < 16; d <<= 1) {
            vs += __shfl_xor(vs, d);
            vd += __shfl_xor(vd, d);
        }
        if (ccol == 0) { als[row * 4 + w] = vs; ald[row * 4 + w] = vd; }
    }
}

// -------------------- bsort + fused p1 ----------------------------------------

__global__ __launch_bounds__(1024) void bsortp1_kernel(const int* __restrict__ bcur,
                                                       const int2* __restrict__ bstage,
                                                       const float* __restrict__ als1,
                                                       const float* __restrict__ ald1,
                                                       int* __restrict__ rowp,
                                                       int2* __restrict__ epair,
                                                       float* __restrict__ p1) {
    __shared__ int cnt[256], cur[256], ws4[4];
    __shared__ int bbase_s;
    __shared__ int2 sorted[BMAX];
    int b = blockIdx.x, tid = threadIdx.x;
    int nb = bcur[b]; if (nb > BMAX) nb = BMAX;
    int d0 = b << 8;

    if (tid < 256) {
        int lane = tid & 63, w = tid >> 6;
        int v = (tid < NBKT) ? bcur[tid] : 0;
        int s = v;
        #pragma unroll
        for (int d = 1; d < 64; d <<= 1) {
            int t = __shfl_up(s, d);
            if (lane >= d) s += t;
        }
        if (lane == 63) ws4[w] = s;
        __syncthreads();
        if (tid == 0) {
            int r = 0;
            #pragma unroll
            for (int q = 0; q < 4; ++q) { int t = ws4[q]; ws4[q] = r; r += t; }
        }
        __syncthreads();
        if (tid == b) bbase_s = ws4[w] + s - v;
        if (b == 0 && tid == 0) rowp[N_NODES] = E_EDGES + N_NODES;
    } else {
        __syncthreads();
        __syncthreads();
    }
    if (tid < 256) cnt[tid] = 0;
    __syncthreads();
    int base = bbase_s;

    const int2* bs = bstage + (size_t)b * BMAX;
    for (int e = tid; e < nb; e += 1024)
        atomicAdd(&cnt[bs[e].y - d0], 1);
    __syncthreads();
    int v = 0, s = 0;
    if (tid < 256) {
        int lane = tid & 63, w = tid >> 6;
        v = cnt[tid];
        s = v;
        #pragma unroll
        for (int d = 1; d < 64; d <<= 1) {
            int t = __shfl_up(s, d);
            if (lane >= d) s += t;
        }
        if (lane == 63) ws4[w] = s;
    }
    __syncthreads();
    if (tid == 0) {
        int r = 0;
        #pragma unroll
        for (int q = 0; q < 4; ++q) { int t = ws4[q]; ws4[q] = r; r += t; }
    }
    __syncthreads();
    if (tid < 256) {
        int excl = ws4[tid >> 6] + s - v;
        cur[tid] = excl;
        int d = d0 + tid;
        if (d < N_NODES) rowp[d] = base + excl;
    }
    __syncthreads();
    for (int e = tid; e < nb; e += 1024) {
        int2 ed = bs[e];
        int p = atomicAdd(&cur[ed.y - d0], 1);
        sorted[p] = ed;
    }
    __syncthreads();
    for (int e = tid; e < nb; e += 1024) {
        int2 ed = sorted[e];
        epair[base + e] = ed;
        float4 as = *(const float4*)&als1[ed.x * 4];
        float4 ad = *(const float4*)&ald1[ed.y * 4];
        float4 p;
        p.x = __expf(lrelu(as.x + ad.x));
        p.y = __expf(lrelu(as.y + ad.y));
        p.z = __expf(lrelu(as.z + ad.z));
        p.w = __expf(lrelu(as.w + ad.w));
        *(float4*)&p1[(size_t)(base + e) * 4] = p;
    }
}

// -------------------- fused aggr1 + gemm2 -------------------------------------
// 4 waves x 4 sequential dsts (variance smoothing, R26) + 2x edge unroll with
// (s,p) prefetch (R25).

__global__ __launch_bounds__(256) void aggr1g_kernel(
        const int* __restrict__ rowp, const int2* __restrict__ epair,
        const float* __restrict__ p1, const __bf16* __restrict__ h1b,
        const float* __restrict__ b1,
        const __bf16* __restrict__ whi2, const __bf16* __restrict__ wlo2,
        const float* __restrict__ a_src2, const float* __restrict__ a_dst2,
        float* __restrict__ g, float* __restrict__ als2, float* __restrict__ ald2) {
    __shared__ __bf16 h2h[16][HC1 + 8];
    __shared__ __bf16 h2l[16][HC1 + 8];
    __shared__ float alsp[4][16], aldp[4][16];
    int tid = threadIdx.x;
    int w = tid >> 6, l = tid & 63;
    int grp = l >> 4, li = l & 15;         // 4 groups x 16 lanes, 8 cols/lane
    int hh = li >> 2;

    #pragma unroll
    for (int q = 0; q < 4; ++q) {
        int row = w * 4 + q;
        int wid = blockIdx.x * 16 + row;
        int beg = rowp[wid], end = rowp[wid + 1];

        float acc[8] = {0,0,0,0,0,0,0,0};
        float S = 0.f;

        int ja = beg + grp, jb = beg + 4 + grp;
        int sa = 0, sb = 0; float pa = 0.f, pb = 0.f;
        if (ja < end) { sa = epair[ja].x; pa = p1[(size_t)ja * 4 + hh]; }
        if (jb < end) { sb = epair[jb].x; pb = p1[(size_t)jb * 4 + hh]; }
        for (int j0 = beg; j0 < end; j0 += 8) {
            int jan = j0 + 8 + grp, jbn = j0 + 12 + grp;
            int san = 0, sbn = 0; float pan = 0.f, pbn = 0.f;
            if (jan < end) { san = epair[jan].x; pan = p1[(size_t)jan * 4 + hh]; }
            if (jbn < end) { sbn = epair[jbn].x; pbn = p1[(size_t)jbn * 4 + hh]; }
            uint4 va = *(const uint4*)(h1b + (size_t)sa * HC1 + li * 8);
            uint4 vb = *(const uint4*)(h1b + (size_t)sb * HC1 + li * 8);
            acc[0] += pa * bflo(va.x) + pb * bflo(vb.x);
            acc[1] += pa * bfhi(va.x) + pb * bfhi(vb.x);
            acc[2] += pa * bflo(va.y) + pb * bflo(vb.y);
            acc[3] += pa * bfhi(va.y) + pb * bfhi(vb.y);
            acc[4] += pa * bflo(va.z) + pb * bflo(vb.z);
            acc[5] += pa * bfhi(va.z) + pb * bfhi(vb.z);
            acc[6] += pa * bflo(va.w) + pb * bflo(vb.w);
            acc[7] += pa * bfhi(va.w) + pb * bfhi(vb.w);
            S += pa + pb;
            sa = san; pa = pan; sb = sbn; pb = pbn;
        }
        #pragma unroll
        for (int d = 16; d < 64; d <<= 1) {
            #pragma unroll
            for (int c = 0; c < 8; ++c) acc[c] += __shfl_xor(acc[c], d);
            S += __shfl_xor(S, d);
        }
        if (grp == 0) {
            float inv = 1.f / S;
            const float* bp = b1 + li * 8;
            bf16x8 hv, lv;
            #pragma unroll
            for (int c = 0; c < 8; ++c) {
                float o = lrelu(acc[c] * inv + bp[c]);
                __bf16 h = (__bf16)o;
                hv[c] = h;
                lv[c] = (__bf16)(o - (float)h);
            }
            *(bf16x8*)&h2h[row][li * 8] = hv;
            *(bf16x8*)&h2l[row][li * 8] = lv;
        }
    }
    __syncthreads();

    // ---- gemm2 for this block's 16 h2 rows: 4 waves, one col-tile each ----
    {
        constexpr int KT = 4;
        int c0 = w;
        bf16x8 bh[KT], bl[KT];
        #pragma unroll
        for (int kt = 0; kt < KT; ++kt) {
            size_t bidx = ((size_t)(c0 * KT + kt) * 64 + l) * 8;
            bh[kt] = *(const bf16x8*)(whi2 + bidx);
            bl[kt] = *(const bf16x8*)(wlo2 + bidx);
        }
        int ar = l & 15, koff = (l >> 4) * 8;
        f32x4 acc2 = (f32x4){0.f, 0.f, 0.f, 0.f};
        #pragma unroll
        for (int kt = 0; kt < KT; ++kt) {
            bf16x8 ahi = *(const bf16x8*)&h2h[ar][kt * 32 + koff];
            bf16x8 alo = *(const bf16x8*)&h2l[ar][kt * 32 + koff];
            acc2 = __builtin_amdgcn_mfma_f32_16x16x32_bf16(ahi, bh[kt], acc2, 0, 0, 0);
            acc2 = __builtin_amdgcn_mfma_f32_16x16x32_bf16(ahi, bl[kt], acc2, 0, 0, 0);
            acc2 = __builtin_amdgcn_mfma_f32_16x16x32_bf16(alo, bh[kt], acc2, 0, 0, 0);
        }
        int crow0 = (l >> 4) * 4;
        int ccol = l & 15;
        float as_c = a_src2[c0 * 16 + ccol];
        float ad_c = a_dst2[c0 * 16 + ccol];
        #pragma unroll
        for (int r = 0; r < 4; ++r) {
            int row = blockIdx.x * 16 + crow0 + r;
            g[(size_t)row * F_OUT + c0 * 16 + ccol] = acc2[r];
            float vs = acc2[r] * as_c;
            float vd = acc2[r] * ad_c;
            #pragma unroll
            for (int d = 1; d < 16; d <<= 1) {
                vs += __shfl_xor(vs, d);
                vd += __shfl_xor(vd, d);
            }
            if (ccol == 0) { alsp[c0][crow0 + r] = vs; aldp[c0][crow0 + r] = vd; }
        }
    }
    __syncthreads();
    if (tid < 16) {
        als2[blockIdx.x * 16 + tid] = alsp[0][tid] + alsp[1][tid] + alsp[2][tid] + alsp[3][tid];
        ald2[blockIdx.x * 16 + tid] = aldp[0][tid] + aldp[1][tid] + aldp[2][tid] + aldp[3][tid];
    }
}

// -------------------- aggr2 (inline p2, 8x8 groups + prefetch) ----------------

__global__ __launch_bounds__(256) void aggr2_kernel(const int* __restrict__ row_ptr,
                                                    const int2* __restrict__ epair,
                                                    const float* __restrict__ als2,
                                                    const float* __restrict__ ald2,
                                                    const float* __restrict__ g,
                                                    const float* __restrict__ b2,
                                                    float* __restrict__ out) {
    int wid = blockIdx.x * 4 + (threadIdx.x >> 6);
    int lane = threadIdx.x & 63;
    int grp = lane >> 3, li = lane & 7;    // 8 groups x 8 lanes, 8 cols/lane
    int beg = row_ptr[wid], end = row_ptr[wid + 1];
    float ad = ald2[wid];
    float a[8];
    #pragma unroll
    for (int c = 0; c < 8; ++c) a[c] = 0.f;
    float S = 0.f;

    int j = beg + grp;
    int s_c = 0; float p_c = 0.f;
    if (j < end) { s_c = epair[j].x; p_c = __expf(lrelu(als2[s_c] + ad)); }
    for (int j0 = beg; j0 < end; j0 += 8) {
        int jn = j0 + 8 + grp;
        int s_n = 0; float p_n = 0.f;
        if (jn < end) { s_n = epair[jn].x; p_n = __expf(lrelu(als2[s_n] + ad)); }
        const float* grow = g + (size_t)s_c * F_OUT + li * 8;
        float4 g0 = *(const float4*)grow;
        float4 g1 = *(const float4*)(grow + 4);
        a[0] += p_c * g0.x; a[1] += p_c * g0.y; a[2] += p_c * g0.z; a[3] += p_c * g0.w;
        a[4] += p_c * g1.x; a[5] += p_c * g1.y; a[6] += p_c * g1.z; a[7] += p_c * g1.w;
        S += p_c;
        s_c = s_n; p_c = p_n;
    }
    #pragma unroll
    for (int d = 8; d < 64; d <<= 1) {
        #pragma unroll
        for (int c = 0; c < 8; ++c) a[c] += __shfl_xor(a[c], d);
        S += __shfl_xor(S, d);
    }
    if (grp == 0) {
        float inv = 1.f / S;
        const float* bp = b2 + li * 8;
        float4 o0, o1;
        o0.x = a[0] * inv + bp[0];
        o0.y = a[1] * inv + bp[1];
        o0.z = a[2] * inv + bp[2];
        o0.w = a[3] * inv + bp[3];
        o1.x = a[4] * inv + bp[4];
        o1.y = a[5] * inv + bp[5];
        o1.z = a[6] * inv + bp[6];
        o1.w = a[7] * inv + bp[7];
        float* orow = out + (size_t)wid * F_OUT + li * 8;
        *(float4*)orow = o0;
        *(float4*)(orow + 4) = o1;
    }
}

// -------------------- launch --------------------------------------------------

extern "C" void kernel_launch(void* const* d_in, const int* in_sizes, int n_in,
                              void* d_out, int out_size, void* d_ws, size_t ws_size,
                              hipStream_t stream) {
    const float* x      = (const float*)d_in[0];
    const int*   ei     = (const int*)  d_in[1];
    const float* W1     = (const float*)d_in[2];
    const float* a_src1 = (const float*)d_in[3];
    const float* a_dst1 = (const float*)d_in[4];
    const float* b1     = (const float*)d_in[5];
    const float* W2     = (const float*)d_in[6];
    const float* a_src2 = (const float*)d_in[7];
    const float* a_dst2 = (const float*)d_in[8];
    const float* b2     = (const float*)d_in[9];
    float* out = (float*)d_out;
    char* ws = (char*)d_ws;

    // workspace layout (bytes)
    __bf16* h1b    = (__bf16*)(ws + 0);         // N*128*2 = 12,800,000
    float* p1      = (float*)(ws + 12800000);   // (E+N)*4*4 = 10,400,000
    float* g       = (float*)(ws + 38400000);   // N*64*4 = 12,800,000
    float* als1    = (float*)(ws + 51200000);   // 800,000
    float* ald1    = (float*)(ws + 52000000);   // 800,000
    float* als2    = (float*)(ws + 52800000);   // 200,000
    float* ald2    = (float*)(ws + 53000000);   // 200,000
    int*   rowp    = (int*)  (ws + 53200000);   // 200,004 (pad to 53,400,064)
    int*   bcur    = (int*)  (ws + 53400064);   // 784 (pad to 53,402,112)
    int2*  bstage  = (int2*) (ws + 53402112);   // NBKT*BMAX*8 = 9,633,792 -> 63,035,904
    int2*  epair   = (int2*) (ws + 63035904);   // (E+N)*8 = 5,200,000 -> 68,235,904
    __bf16* whi1   = (__bf16*)(ws + 68235904);  // 65,536
    __bf16* wlo1   = (__bf16*)(ws + 68301440);  // 65,536
    __bf16* whi2   = (__bf16*)(ws + 68366976);  // 16,384
    __bf16* wlo2   = (__bf16*)(ws + 68383360);  // 16,384 (end 68,399,744)

    init_kernel<<<1 + (NPACK + 255) / 256, 256, 0, stream>>>(
        W1, W2, whi1, wlo1, whi2, wlo2, bcur);

    gemm1_bappend_kernel<<<NAB + GB1, 256, 0, stream>>>(
        x, whi1, wlo1, a_src1, a_dst1, h1b, als1, ald1, ei, bcur, bstage);

    bsortp1_kernel<<<NBKT, 1024, 0, stream>>>(bcur, bstage, als1, ald1, rowp, epair, p1);

    aggr1g_kernel<<<N_NODES / 16, 256, 0, stream>>>(
        rowp, epair, p1, h1b, b1, whi2, wlo2, a_src2, a_dst2, g, als2, ald2);

    aggr2_kernel<<<N_NODES / 4, 256, 0, stream>>>(rowp, epair, als2, ald2, g, b2, out);
}